// Round 2
// baseline (4998.134 us; speedup 1.0000x reference)
//
#include <hip/hip_runtime.h>

#define D_IN   768
#define NLAT   24576
#define BATCH  4096
#define K_TOP  64
#define MAXEQ  128

// ---------------------------------------------------------------------------
// float -> order-preserving unsigned key (larger key <=> larger float)
// ---------------------------------------------------------------------------
__device__ __forceinline__ unsigned f2key(float f) {
    unsigned u = __float_as_uint(f);
    return (u & 0x80000000u) ? ~u : (u | 0x80000000u);
}

// ---------------------------------------------------------------------------
// Encoder GEMM with f64 accumulation:
//   z_pre[m][n] = (float) sum_k f64(x[m][k] - b_pre[k]) * f64(W_enc[n][k])
// Products of two f32 are exact in f64; accumulation error ~1e-15 -> z_pre is
// the correctly-rounded true value, so top-k selection matches the f64 np ref.
// Tile 128x128, BK=32, 256 threads, 8x8 microtile.
// ---------------------------------------------------------------------------
#define BM 128
#define BN 128
#define BKT 32
#define LDA_PAD 4

__global__ __launch_bounds__(256) void enc_gemm(const float* __restrict__ x,
                                                const float* __restrict__ W,
                                                const float* __restrict__ bpre,
                                                float* __restrict__ z_pre)
{
    __shared__ float As[BKT][BM + LDA_PAD];
    __shared__ float Bs[BKT][BN + LDA_PAD];

    const int tid = threadIdx.x;
    const int bm = blockIdx.y * BM;
    const int bn = blockIdx.x * BN;
    const int tx = tid & 15;
    const int ty = tid >> 4;

    double acc[8][8];
    #pragma unroll
    for (int i = 0; i < 8; ++i)
        #pragma unroll
        for (int j = 0; j < 8; ++j) acc[i][j] = 0.0;

    const int lrow = tid >> 3;        // 0..31
    const int kq   = (tid & 7) * 4;   // 0,4,...,28

    for (int k0 = 0; k0 < D_IN; k0 += BKT) {
        const float4 bp = *(const float4*)(bpre + k0 + kq);
        float4 a0 = *(const float4*)(x + (size_t)(bm + lrow +  0) * D_IN + k0 + kq);
        float4 a1 = *(const float4*)(x + (size_t)(bm + lrow + 32) * D_IN + k0 + kq);
        float4 a2 = *(const float4*)(x + (size_t)(bm + lrow + 64) * D_IN + k0 + kq);
        float4 a3 = *(const float4*)(x + (size_t)(bm + lrow + 96) * D_IN + k0 + kq);
        const float4 b0 = *(const float4*)(W + (size_t)(bn + lrow +  0) * D_IN + k0 + kq);
        const float4 b1 = *(const float4*)(W + (size_t)(bn + lrow + 32) * D_IN + k0 + kq);
        const float4 b2 = *(const float4*)(W + (size_t)(bn + lrow + 64) * D_IN + k0 + kq);
        const float4 b3 = *(const float4*)(W + (size_t)(bn + lrow + 96) * D_IN + k0 + kq);

        __syncthreads();

        // NOTE: b_pre subtraction here is exact in the ref too (f64 centering);
        // (x - b) in f32 could round, but b_pre == 0 in this problem; we still
        // match ref to f64 accuracy because we subtract before the f64 product
        // only via f32 when bp==0 (exact). For generality keep the subtract in
        // f32 (exact when bp==0).
        As[kq+0][lrow+ 0] = a0.x - bp.x; As[kq+1][lrow+ 0] = a0.y - bp.y;
        As[kq+2][lrow+ 0] = a0.z - bp.z; As[kq+3][lrow+ 0] = a0.w - bp.w;
        As[kq+0][lrow+32] = a1.x - bp.x; As[kq+1][lrow+32] = a1.y - bp.y;
        As[kq+2][lrow+32] = a1.z - bp.z; As[kq+3][lrow+32] = a1.w - bp.w;
        As[kq+0][lrow+64] = a2.x - bp.x; As[kq+1][lrow+64] = a2.y - bp.y;
        As[kq+2][lrow+64] = a2.z - bp.z; As[kq+3][lrow+64] = a2.w - bp.w;
        As[kq+0][lrow+96] = a3.x - bp.x; As[kq+1][lrow+96] = a3.y - bp.y;
        As[kq+2][lrow+96] = a3.z - bp.z; As[kq+3][lrow+96] = a3.w - bp.w;

        Bs[kq+0][lrow+ 0] = b0.x; Bs[kq+1][lrow+ 0] = b0.y;
        Bs[kq+2][lrow+ 0] = b0.z; Bs[kq+3][lrow+ 0] = b0.w;
        Bs[kq+0][lrow+32] = b1.x; Bs[kq+1][lrow+32] = b1.y;
        Bs[kq+2][lrow+32] = b1.z; Bs[kq+3][lrow+32] = b1.w;
        Bs[kq+0][lrow+64] = b2.x; Bs[kq+1][lrow+64] = b2.y;
        Bs[kq+2][lrow+64] = b2.z; Bs[kq+3][lrow+64] = b2.w;
        Bs[kq+0][lrow+96] = b3.x; Bs[kq+1][lrow+96] = b3.y;
        Bs[kq+2][lrow+96] = b3.z; Bs[kq+3][lrow+96] = b3.w;

        __syncthreads();

        #pragma unroll
        for (int kk = 0; kk < BKT; ++kk) {
            float a[8], b[8];
            *(float4*)(a + 0) = *(const float4*)&As[kk][ty * 4];
            *(float4*)(a + 4) = *(const float4*)&As[kk][64 + ty * 4];
            *(float4*)(b + 0) = *(const float4*)&Bs[kk][tx * 4];
            *(float4*)(b + 4) = *(const float4*)&Bs[kk][64 + tx * 4];
            double a64[8], b64[8];
            #pragma unroll
            for (int i = 0; i < 8; ++i) { a64[i] = (double)a[i]; b64[i] = (double)b[i]; }
            #pragma unroll
            for (int i = 0; i < 8; ++i)
                #pragma unroll
                for (int j = 0; j < 8; ++j)
                    acc[i][j] = fma(a64[i], b64[j], acc[i][j]);
        }
    }

    #pragma unroll
    for (int i = 0; i < 8; ++i) {
        const int r = bm + ((i < 4) ? (ty * 4 + i) : (64 + ty * 4 + (i - 4)));
        float4 v0 = make_float4((float)acc[i][0], (float)acc[i][1], (float)acc[i][2], (float)acc[i][3]);
        float4 v1 = make_float4((float)acc[i][4], (float)acc[i][5], (float)acc[i][6], (float)acc[i][7]);
        *(float4*)(z_pre + (size_t)r * NLAT + bn + tx * 4)      = v0;
        *(float4*)(z_pre + (size_t)r * NLAT + bn + 64 + tx * 4) = v1;
    }
}

// ---------------------------------------------------------------------------
// Top-k per row on the f32-rounded z_pre.  f32 rounding is monotone, so the
// only ambiguity vs the f64 reference selection is an f32 TIE spanning the
// boundary (#eq > E).  In that rare case, recompute the tied candidates' dots
// in f64 and keep the E largest by f64 value -> selection == f64 truth.
// ---------------------------------------------------------------------------
__global__ __launch_bounds__(1024) void topk_kernel(const float* __restrict__ z_pre,
                                                    float* __restrict__ z,
                                                    const float* __restrict__ x,
                                                    const float* __restrict__ W_enc,
                                                    const float* __restrict__ bpre,
                                                    int* __restrict__ idx_ws,
                                                    float* __restrict__ val_ws)
{
    __shared__ float row[NLAT];            // 96 KB
    __shared__ unsigned hist[256];
    __shared__ unsigned wsum[16];
    __shared__ unsigned wsum2[16];
    __shared__ unsigned sh_prefix;
    __shared__ int sh_rem;
    __shared__ int run_base, run_base2;
    __shared__ int eqidx[MAXEQ];
    __shared__ double dval[MAXEQ];
    __shared__ unsigned char eqflag[MAXEQ];

    const int r = blockIdx.x;
    const int tid = threadIdx.x;
    const int lane = tid & 63;
    const int w = tid >> 6;
    const float* src = z_pre + (size_t)r * NLAT;

    for (int i = tid; i < NLAT / 4; i += 1024)
        ((float4*)row)[i] = ((const float4*)src)[i];

    if (tid == 0) { sh_prefix = 0u; sh_rem = K_TOP; }
    __syncthreads();

    // 4-level MSB-first radix select (8 bits/level) for the K_TOP-th largest key
    for (int lvl = 0; lvl < 4; ++lvl) {
        const int shift = 24 - 8 * lvl;
        if (tid < 256) hist[tid] = 0u;
        __syncthreads();
        const unsigned pfx = sh_prefix;
        for (int i = tid; i < NLAT; i += 1024) {
            const unsigned key = f2key(row[i]);
            const bool match = (lvl == 0) || ((key >> (shift + 8)) == (pfx >> (shift + 8)));
            if (match) atomicAdd(&hist[(key >> shift) & 255u], 1u);
        }
        __syncthreads();
        if (tid == 0) {
            int rem = sh_rem;
            int acc = 0;
            int b = 255;
            for (; b >= 0; --b) {
                const int nb = acc + (int)hist[b];
                if (nb >= rem) { sh_rem = rem - acc; break; }
                acc = nb;
            }
            sh_prefix = pfx | ((unsigned)b << shift);
        }
        __syncthreads();
    }
    const unsigned T = sh_prefix;   // key of the 64th-largest f32 value
    const int E = sh_rem;           // how many ==T belong in the top-64

    // ---- Pass B: collect indices of key==T (leftmost order) ----
    if (tid == 0) run_base = 0;
    __syncthreads();
    for (int c = 0; c < NLAT; c += 1024) {
        const int i = c + tid;
        const bool eq = (f2key(row[i]) == T);
        const unsigned long long m = __ballot(eq);
        if (lane == 0) wsum[w] = (unsigned)__popcll(m);
        __syncthreads();
        int b = run_base;
        for (int j = 0; j < w; ++j) b += (int)wsum[j];
        const int pos = b + __popcll(m & ((1ull << lane) - 1ull));
        if (eq && pos < MAXEQ) eqidx[pos] = i;
        __syncthreads();
        if (tid == 0) { int s = 0; for (int j = 0; j < 16; ++j) s += (int)wsum[j]; run_base += s; }
        __syncthreads();
    }
    const int cnteq = run_base;

    // ---- Tie handling: if more eq candidates than slots, break by f64 dot ----
    if (cnteq > E && cnteq <= MAXEQ) {
        const float* xr = x + (size_t)r * D_IN;
        for (int q = w; q < cnteq; q += 16) {
            const float* wr = W_enc + (size_t)eqidx[q] * D_IN;
            double acc = 0.0;
            for (int k = lane; k < D_IN; k += 64)
                acc = fma((double)xr[k] - (double)bpre[k], (double)wr[k], acc);
            #pragma unroll
            for (int off = 32; off; off >>= 1) acc += __shfl_down(acc, off, 64);
            if (lane == 0) dval[q] = acc;
        }
        __syncthreads();
        for (int t = tid; t < cnteq; t += 1024) {
            const double v = dval[t];
            int rank = 0;
            for (int q = 0; q < cnteq; ++q)
                rank += (dval[q] > v) || (dval[q] == v && q < t);
            eqflag[t] = (rank < E) ? 1 : 0;
        }
    } else {
        for (int t = tid; t < MAXEQ; t += 1024) eqflag[t] = (t < E) ? 1 : 0;
    }
    __syncthreads();

    // ---- Pass C: write z + compact (idx,val) in index order ----
    if (tid == 0) { run_base = 0; run_base2 = 0; }
    __syncthreads();
    float* zdst = z + (size_t)r * NLAT;
    for (int c = 0; c < NLAT; c += 1024) {
        const int i = c + tid;
        const float v = row[i];
        const unsigned key = f2key(v);
        const bool eq = (key == T);
        const bool gt = (key > T);

        const unsigned long long meq = __ballot(eq);
        if (lane == 0) wsum[w] = (unsigned)__popcll(meq);
        __syncthreads();
        int ebase = run_base;
        for (int j = 0; j < w; ++j) ebase += (int)wsum[j];
        const int eqrank = ebase + __popcll(meq & ((1ull << lane) - 1ull));

        const bool keep = gt || (eq && eqrank < MAXEQ && eqflag[eqrank]);
        const unsigned long long mkp = __ballot(keep);
        if (lane == 0) wsum2[w] = (unsigned)__popcll(mkp);
        __syncthreads();
        int kbase = run_base2;
        for (int j = 0; j < w; ++j) kbase += (int)wsum2[j];
        const int pos = kbase + __popcll(mkp & ((1ull << lane) - 1ull));

        zdst[i] = keep ? v : 0.0f;
        if (keep && idx_ws != nullptr && pos < K_TOP) {
            idx_ws[r * K_TOP + pos] = i;
            val_ws[r * K_TOP + pos] = v;
        }
        __syncthreads();
        if (tid == 0) {
            int es = 0, ks = 0;
            for (int j = 0; j < 16; ++j) { es += (int)wsum[j]; ks += (int)wsum2[j]; }
            run_base += es; run_base2 += ks;
        }
        __syncthreads();
    }
}

// ---------------------------------------------------------------------------
// Sparse decoder (ws path), f64 accumulation.
// ---------------------------------------------------------------------------
__global__ __launch_bounds__(256) void dec_kernel(const int* __restrict__ idx_ws,
                                                  const float* __restrict__ val_ws,
                                                  const float* __restrict__ W_dec,
                                                  const float* __restrict__ bpre,
                                                  const float* __restrict__ x,
                                                  float* __restrict__ x_hat,
                                                  float* __restrict__ recon)
{
    __shared__ int sidx[K_TOP];
    __shared__ float sval[K_TOP];
    const int r = blockIdx.x;
    const int tid = threadIdx.x;
    if (tid < K_TOP) {
        sidx[tid] = idx_ws[r * K_TOP + tid];
        sval[tid] = val_ws[r * K_TOP + tid];
    }
    __syncthreads();

    double a0 = (double)bpre[tid], a1 = (double)bpre[tid + 256], a2 = (double)bpre[tid + 512];
    #pragma unroll 4
    for (int j = 0; j < K_TOP; ++j) {
        const double v = (double)sval[j];
        const float* wr = W_dec + (size_t)sidx[j] * D_IN;
        a0 = fma(v, (double)wr[tid],       a0);
        a1 = fma(v, (double)wr[tid + 256], a1);
        a2 = fma(v, (double)wr[tid + 512], a2);
    }
    const size_t o = (size_t)r * D_IN + tid;
    const float f0 = (float)a0, f1 = (float)a1, f2 = (float)a2;
    x_hat[o]       = f0;
    x_hat[o + 256] = f1;
    x_hat[o + 512] = f2;
    recon[o]       = x[o]       - f0;
    recon[o + 256] = x[o + 256] - f1;
    recon[o + 512] = x[o + 512] - f2;
}

// ---------------------------------------------------------------------------
// Fallback decoder (no ws): re-derive (idx,val) by scanning the z row.
// ---------------------------------------------------------------------------
__global__ __launch_bounds__(256) void dec_scan_kernel(const float* __restrict__ z,
                                                       const float* __restrict__ W_dec,
                                                       const float* __restrict__ bpre,
                                                       const float* __restrict__ x,
                                                       float* __restrict__ x_hat,
                                                       float* __restrict__ recon)
{
    __shared__ int sidx[K_TOP];
    __shared__ float sval[K_TOP];
    __shared__ int wcnt[4];
    __shared__ int base;
    const int r = blockIdx.x;
    const int tid = threadIdx.x;
    const int lane = tid & 63, w = tid >> 6;
    if (tid == 0) base = 0;
    __syncthreads();
    const float* zrow = z + (size_t)r * NLAT;
    for (int c = 0; c < NLAT; c += 256) {
        const float v = zrow[c + tid];
        const bool nz = (v != 0.0f);
        const unsigned long long m = __ballot(nz);
        if (lane == 0) wcnt[w] = __popcll(m);
        __syncthreads();
        int b = base;
        for (int j = 0; j < w; ++j) b += wcnt[j];
        const int pos = b + __popcll(m & ((1ull << lane) - 1ull));
        if (nz && pos < K_TOP) { sidx[pos] = c + tid; sval[pos] = v; }
        __syncthreads();
        if (tid == 0) { int s = 0; for (int j = 0; j < 4; ++j) s += wcnt[j]; base += s; }
        __syncthreads();
    }
    const int n = base > K_TOP ? K_TOP : base;

    double a0 = (double)bpre[tid], a1 = (double)bpre[tid + 256], a2 = (double)bpre[tid + 512];
    for (int j = 0; j < n; ++j) {
        const double v = (double)sval[j];
        const float* wr = W_dec + (size_t)sidx[j] * D_IN;
        a0 = fma(v, (double)wr[tid],       a0);
        a1 = fma(v, (double)wr[tid + 256], a1);
        a2 = fma(v, (double)wr[tid + 512], a2);
    }
    const size_t o = (size_t)r * D_IN + tid;
    const float f0 = (float)a0, f1 = (float)a1, f2 = (float)a2;
    x_hat[o]       = f0;
    x_hat[o + 256] = f1;
    x_hat[o + 512] = f2;
    recon[o]       = x[o]       - f0;
    recon[o + 256] = x[o + 256] - f1;
    recon[o + 512] = x[o + 512] - f2;
}

// ---------------------------------------------------------------------------
extern "C" void kernel_launch(void* const* d_in, const int* in_sizes, int n_in,
                              void* d_out, int out_size, void* d_ws, size_t ws_size,
                              hipStream_t stream)
{
    const float* x     = (const float*)d_in[0];
    const float* W_enc = (const float*)d_in[1];
    const float* W_dec = (const float*)d_in[2];
    const float* bpre  = (const float*)d_in[3];
    // d_in[4] is k (==64), hard-coded as K_TOP

    float* out   = (float*)d_out;
    float* x_hat = out;                                   // [BATCH, D_IN]
    float* z     = x_hat + (size_t)BATCH * D_IN;          // [BATCH, NLAT]
    float* z_pre = z     + (size_t)BATCH * NLAT;          // [BATCH, NLAT]
    float* recon = z_pre + (size_t)BATCH * NLAT;          // [BATCH, D_IN]

    const size_t ws_need = (size_t)BATCH * K_TOP * (sizeof(int) + sizeof(float));
    const bool have_ws = (d_ws != nullptr) && (ws_size >= ws_need);
    int*   idx_ws = have_ws ? (int*)d_ws : nullptr;
    float* val_ws = have_ws ? (float*)((char*)d_ws + (size_t)BATCH * K_TOP * sizeof(int)) : nullptr;

    dim3 g1(NLAT / BN, BATCH / BM);
    enc_gemm<<<g1, 256, 0, stream>>>(x, W_enc, bpre, z_pre);

    topk_kernel<<<BATCH, 1024, 0, stream>>>(z_pre, z, x, W_enc, bpre, idx_ws, val_ws);

    if (have_ws)
        dec_kernel<<<BATCH, 256, 0, stream>>>(idx_ws, val_ws, W_dec, bpre, x, x_hat, recon);
    else
        dec_scan_kernel<<<BATCH, 256, 0, stream>>>(z, W_dec, bpre, x, x_hat, recon);
}

// Round 3
// 1733.087 us; speedup vs baseline: 2.8839x; 2.8839x over previous
//
#include <hip/hip_runtime.h>

#define D_IN   768
#define NLAT   24576
#define BATCH  4096
#define K_TOP  64
#define MAXA   1024
#define DELTA  2.0e-3f

typedef float f32x4 __attribute__((ext_vector_type(4)));
typedef short short8 __attribute__((ext_vector_type(8)));

// ---------------------------------------------------------------------------
__device__ __forceinline__ unsigned f2key(float f) {
    unsigned u = __float_as_uint(f);
    return (u & 0x80000000u) ? ~u : (u | 0x80000000u);
}
__device__ __forceinline__ float key2f(unsigned k) {
    unsigned u = (k & 0x80000000u) ? (k & 0x7fffffffu) : ~k;
    return __uint_as_float(u);
}
__device__ __forceinline__ unsigned short bf16hi(float f) {   // RNE f32->bf16
    unsigned u = __float_as_uint(f);
    unsigned r = u + 0x7fffu + ((u >> 16) & 1u);
    return (unsigned short)(r >> 16);
}
__device__ __forceinline__ float bf2f(unsigned short h) {
    return __uint_as_float(((unsigned)h) << 16);
}

// ---------------------------------------------------------------------------
// Encoder GEMM via split-2 bf16 MFMA:  v = hi + lo (+ ~2^-16 residual);
// acc += Ah*Bh + Ah*Bl + Al*Bh  (f32 MFMA accumulate).  |err| ~ 1e-5 worst.
// Tile 128x128, BK=32, 4 waves (2x2), each wave 64x64 via 4x4 16x16 frags.
// A/B fragment k-order chosen identically for both operands => any bijective
// k-assignment yields the correct dot product (permutation invariance).
// ---------------------------------------------------------------------------
#define GBM 128
#define GBN 128
#define GBK 32
#define LROW (GBK + 8)   // pad rows to 40 shorts (80 B) -> <=2-way LDS aliasing

__global__ __launch_bounds__(256) void enc_gemm_mfma(const float* __restrict__ x,
                                                     const float* __restrict__ W,
                                                     const float* __restrict__ bpre,
                                                     float* __restrict__ z_pre)
{
    __shared__ unsigned short Ah[GBM][LROW], Al[GBM][LROW];
    __shared__ unsigned short Bh[GBN][LROW], Bl[GBN][LROW];

    const int tid = threadIdx.x;
    const int bm = blockIdx.y * GBM;
    const int bn = blockIdx.x * GBN;
    const int lane = tid & 63;
    const int wv = tid >> 6;
    const int wr = (wv >> 1) * 64;
    const int wc = (wv & 1) * 64;
    const int fr = lane & 15;     // fragment row/col within 16x16
    const int fg = lane >> 4;     // k-group 0..3

    const int srow = tid >> 3;        // staging: 8 lanes cover one row's 32 floats
    const int sk   = (tid & 7) * 4;

    f32x4 acc[4][4];
    #pragma unroll
    for (int i = 0; i < 4; ++i)
        #pragma unroll
        for (int j = 0; j < 4; ++j)
            #pragma unroll
            for (int e = 0; e < 4; ++e) acc[i][j][e] = 0.0f;

    for (int k0 = 0; k0 < D_IN; k0 += GBK) {
        float4 xa[4], wb[4];
        const float4 bp = *(const float4*)(bpre + k0 + sk);
        #pragma unroll
        for (int p = 0; p < 4; ++p) {
            xa[p] = *(const float4*)(x + (size_t)(bm + srow + 32*p) * D_IN + k0 + sk);
            wb[p] = *(const float4*)(W + (size_t)(bn + srow + 32*p) * D_IN + k0 + sk);
        }
        __syncthreads();   // previous tile's LDS reads done
        #pragma unroll
        for (int p = 0; p < 4; ++p) {
            const float a0 = xa[p].x - bp.x, a1 = xa[p].y - bp.y,
                        a2 = xa[p].z - bp.z, a3 = xa[p].w - bp.w;
            const unsigned short h0 = bf16hi(a0), h1 = bf16hi(a1),
                                 h2 = bf16hi(a2), h3 = bf16hi(a3);
            *(ushort4*)&Ah[srow + 32*p][sk] = make_ushort4(h0, h1, h2, h3);
            *(ushort4*)&Al[srow + 32*p][sk] = make_ushort4(
                bf16hi(a0 - bf2f(h0)), bf16hi(a1 - bf2f(h1)),
                bf16hi(a2 - bf2f(h2)), bf16hi(a3 - bf2f(h3)));
            const float b0 = wb[p].x, b1 = wb[p].y, b2 = wb[p].z, b3 = wb[p].w;
            const unsigned short g0 = bf16hi(b0), g1 = bf16hi(b1),
                                 g2 = bf16hi(b2), g3 = bf16hi(b3);
            *(ushort4*)&Bh[srow + 32*p][sk] = make_ushort4(g0, g1, g2, g3);
            *(ushort4*)&Bl[srow + 32*p][sk] = make_ushort4(
                bf16hi(b0 - bf2f(g0)), bf16hi(b1 - bf2f(g1)),
                bf16hi(b2 - bf2f(g2)), bf16hi(b3 - bf2f(g3)));
        }
        __syncthreads();

        short8 ah[4], al[4], bh[4], bl[4];
        #pragma unroll
        for (int t = 0; t < 4; ++t) {
            ah[t] = *(const short8*)&Ah[wr + t*16 + fr][fg * 8];
            al[t] = *(const short8*)&Al[wr + t*16 + fr][fg * 8];
            bh[t] = *(const short8*)&Bh[wc + t*16 + fr][fg * 8];
            bl[t] = *(const short8*)&Bl[wc + t*16 + fr][fg * 8];
        }
        #pragma unroll
        for (int mt = 0; mt < 4; ++mt)
            #pragma unroll
            for (int nt = 0; nt < 4; ++nt) {
                acc[mt][nt] = __builtin_amdgcn_mfma_f32_16x16x32_bf16(ah[mt], bh[nt], acc[mt][nt], 0, 0, 0);
                acc[mt][nt] = __builtin_amdgcn_mfma_f32_16x16x32_bf16(ah[mt], bl[nt], acc[mt][nt], 0, 0, 0);
                acc[mt][nt] = __builtin_amdgcn_mfma_f32_16x16x32_bf16(al[mt], bh[nt], acc[mt][nt], 0, 0, 0);
            }
    }

    // C/D layout (m89-verified): col = lane&15, row = (lane>>4)*4 + reg
    #pragma unroll
    for (int mt = 0; mt < 4; ++mt)
        #pragma unroll
        for (int j = 0; j < 4; ++j) {
            const int r = bm + wr + mt*16 + fg*4 + j;
            float* dst = z_pre + (size_t)r * NLAT + bn + wc;
            #pragma unroll
            for (int nt = 0; nt < 4; ++nt)
                dst[nt*16 + fr] = acc[mt][nt][j];
        }
}

// ---------------------------------------------------------------------------
// Top-k per row on approx z_pre.  Entries > v64+DELTA are surely selected;
// entries within [v64-DELTA, v64+DELTA] get exact f64 dots recomputed and are
// ranked (f64 desc, idx asc) -> selection == f64 reference selection, since
// |approx - true| << DELTA/2.  Row lives in 24 regs/thread; per-wave radix
// histograms; 4-sync ballot compaction.
// ---------------------------------------------------------------------------
__global__ __launch_bounds__(1024) void topk_kernel(const float* __restrict__ z_pre,
                                                    float* __restrict__ z,
                                                    const float* __restrict__ x,
                                                    const float* __restrict__ W_enc,
                                                    const float* __restrict__ bpre,
                                                    int* __restrict__ idx_ws,
                                                    float* __restrict__ val_ws)
{
    __shared__ unsigned hist_w[16][257];
    __shared__ unsigned hist[256];
    __shared__ unsigned sh_prefix;
    __shared__ int sh_rem;
    __shared__ int cntA;
    __shared__ int nsure_sh;
    __shared__ int idxA[MAXA];
    __shared__ double dvalA[MAXA];
    __shared__ unsigned char keepA[MAXA];
    __shared__ int wcnt[16][24];

    const int r = blockIdx.x;
    const int tid = threadIdx.x;
    const int lane = tid & 63;
    const int w = tid >> 6;
    const unsigned long long lt = (1ull << lane) - 1ull;

    const float* src = z_pre + (size_t)r * NLAT;
    float v[24];
    #pragma unroll
    for (int c = 0; c < 24; ++c) v[c] = src[c*1024 + tid];

    if (tid == 0) { sh_prefix = 0u; sh_rem = K_TOP; cntA = 0; nsure_sh = 0; }
    if (idx_ws != nullptr && tid < K_TOP) {   // clear ws slots (determinism)
        idx_ws[r*K_TOP + tid] = 0; val_ws[r*K_TOP + tid] = 0.0f;
    }

    // ---- 4-level radix select of the 64th-largest approx value ----
    for (int lvl = 0; lvl < 4; ++lvl) {
        const int shift = 24 - 8*lvl;
        for (int i = tid; i < 16*257; i += 1024) ((unsigned*)hist_w)[i] = 0u;
        __syncthreads();
        const unsigned pfx = sh_prefix;
        #pragma unroll
        for (int c = 0; c < 24; ++c) {
            const unsigned key = f2key(v[c]);
            const bool match = (lvl == 0) || ((key >> (shift + 8)) == (pfx >> (shift + 8)));
            if (match) atomicAdd(&hist_w[w][(key >> shift) & 255u], 1u);
        }
        __syncthreads();
        if (tid < 256) {
            unsigned s = 0;
            #pragma unroll
            for (int q = 0; q < 16; ++q) s += hist_w[q][tid];
            hist[tid] = s;
        }
        __syncthreads();
        if (tid == 0) {
            int rem = sh_rem, acc = 0, b = 255;
            for (; b >= 0; --b) {
                const int nb = acc + (int)hist[b];
                if (nb >= rem) { sh_rem = rem - acc; break; }
                acc = nb;
            }
            sh_prefix = pfx | ((unsigned)b << shift);
        }
        __syncthreads();
    }

    const float vT = key2f(sh_prefix);
    const float thr_lo = vT - DELTA, thr_hi = vT + DELTA;

    // ---- count sure-keeps; collect ambiguous window into idxA ----
    int wsure = 0;
    #pragma unroll
    for (int c = 0; c < 24; ++c) {
        const float val = v[c];
        const unsigned long long m = __ballot(val > thr_hi);
        if (lane == 0) wsure += (int)__popcll(m);
        if (val <= thr_hi && val >= thr_lo) {
            const int p = atomicAdd(&cntA, 1);
            if (p < MAXA) idxA[p] = c*1024 + tid;
        }
    }
    if (lane == 0 && wsure) atomicAdd(&nsure_sh, (unsigned)wsure);
    __syncthreads();

    const int nA = cntA < MAXA ? cntA : MAXA;
    const int nkeepA = K_TOP - nsure_sh;

    // ---- exact f64 dots for ambiguous candidates (one wave each) ----
    for (int q = w; q < nA; q += 16) {
        const int j = idxA[q];
        const float* wrow = W_enc + (size_t)j * D_IN;
        const float* xrow = x + (size_t)r * D_IN;
        double a = 0.0;
        for (int k = lane; k < D_IN; k += 64)
            a = fma((double)xrow[k] - (double)bpre[k], (double)wrow[k], a);
        #pragma unroll
        for (int off = 32; off; off >>= 1) a += __shfl_down(a, off, 64);
        if (lane == 0) dvalA[q] = a;
    }
    __syncthreads();

    for (int t = tid; t < nA; t += 1024) {
        const double dv = dvalA[t];
        const int ix = idxA[t];
        int rank = 0;
        for (int q = 0; q < nA; ++q)
            rank += (dvalA[q] > dv) || (dvalA[q] == dv && idxA[q] < ix);
        keepA[t] = (rank < nkeepA) ? 1 : 0;
    }
    __syncthreads();

    // ---- keep flags + 2-sync stable compaction; write z ----
    bool kp[24];
    #pragma unroll
    for (int c = 0; c < 24; ++c) {
        const float val = v[c];
        bool k = (val > thr_hi);
        if (!k && val >= thr_lo) {
            const int i = c*1024 + tid;
            for (int q = 0; q < nA; ++q)
                if (idxA[q] == i) { k = (keepA[q] != 0); break; }
        }
        kp[c] = k;
        const unsigned long long m = __ballot(k);
        if (lane == 0) wcnt[w][c] = (int)__popcll(m);
    }
    __syncthreads();
    if (tid == 0) {
        int run = 0;
        for (int c = 0; c < 24; ++c)
            #pragma unroll
            for (int q = 0; q < 16; ++q) { const int t = wcnt[q][c]; wcnt[q][c] = run; run += t; }
    }
    __syncthreads();

    float* zdst = z + (size_t)r * NLAT;
    #pragma unroll
    for (int c = 0; c < 24; ++c) {
        const unsigned long long m = __ballot(kp[c]);
        const int pos = wcnt[w][c] + (int)__popcll(m & lt);
        const int i = c*1024 + tid;
        zdst[i] = kp[c] ? v[c] : 0.0f;
        if (kp[c] && idx_ws != nullptr && pos < K_TOP) {
            idx_ws[r*K_TOP + pos] = i;
            val_ws[r*K_TOP + pos] = v[c];
        }
    }
}

// ---------------------------------------------------------------------------
// Sparse decoder (ws path), f32 accumulation.
// ---------------------------------------------------------------------------
__global__ __launch_bounds__(256) void dec_kernel(const int* __restrict__ idx_ws,
                                                  const float* __restrict__ val_ws,
                                                  const float* __restrict__ W_dec,
                                                  const float* __restrict__ bpre,
                                                  const float* __restrict__ x,
                                                  float* __restrict__ x_hat,
                                                  float* __restrict__ recon)
{
    __shared__ int sidx[K_TOP];
    __shared__ float sval[K_TOP];
    const int r = blockIdx.x;
    const int tid = threadIdx.x;
    if (tid < K_TOP) {
        sidx[tid] = idx_ws[r*K_TOP + tid];
        sval[tid] = val_ws[r*K_TOP + tid];
    }
    __syncthreads();

    float a0 = bpre[tid], a1 = bpre[tid + 256], a2 = bpre[tid + 512];
    #pragma unroll 4
    for (int j = 0; j < K_TOP; ++j) {
        const float vv = sval[j];
        const float* wr_ = W_dec + (size_t)sidx[j] * D_IN;
        a0 = fmaf(vv, wr_[tid],       a0);
        a1 = fmaf(vv, wr_[tid + 256], a1);
        a2 = fmaf(vv, wr_[tid + 512], a2);
    }
    const size_t o = (size_t)r * D_IN + tid;
    x_hat[o]       = a0;
    x_hat[o + 256] = a1;
    x_hat[o + 512] = a2;
    recon[o]       = x[o]       - a0;
    recon[o + 256] = x[o + 256] - a1;
    recon[o + 512] = x[o + 512] - a2;
}

// ---------------------------------------------------------------------------
// Fallback decoder (no ws): re-derive (idx,val) by scanning the z row.
// ---------------------------------------------------------------------------
__global__ __launch_bounds__(256) void dec_scan_kernel(const float* __restrict__ z,
                                                       const float* __restrict__ W_dec,
                                                       const float* __restrict__ bpre,
                                                       const float* __restrict__ x,
                                                       float* __restrict__ x_hat,
                                                       float* __restrict__ recon)
{
    __shared__ int sidx[K_TOP];
    __shared__ float sval[K_TOP];
    __shared__ int wcnt[4];
    __shared__ int base;
    const int r = blockIdx.x;
    const int tid = threadIdx.x;
    const int lane = tid & 63, w = tid >> 6;
    if (tid == 0) base = 0;
    __syncthreads();
    const float* zrow = z + (size_t)r * NLAT;
    for (int c = 0; c < NLAT; c += 256) {
        const float vv = zrow[c + tid];
        const bool nz = (vv != 0.0f);
        const unsigned long long m = __ballot(nz);
        if (lane == 0) wcnt[w] = __popcll(m);
        __syncthreads();
        int b = base;
        for (int j = 0; j < w; ++j) b += wcnt[j];
        const int pos = b + __popcll(m & ((1ull << lane) - 1ull));
        if (nz && pos < K_TOP) { sidx[pos] = c + tid; sval[pos] = vv; }
        __syncthreads();
        if (tid == 0) { int s = 0; for (int j = 0; j < 4; ++j) s += wcnt[j]; base += s; }
        __syncthreads();
    }
    const int n = base > K_TOP ? K_TOP : base;

    float a0 = bpre[tid], a1 = bpre[tid + 256], a2 = bpre[tid + 512];
    for (int j = 0; j < n; ++j) {
        const float vv = sval[j];
        const float* wr_ = W_dec + (size_t)sidx[j] * D_IN;
        a0 = fmaf(vv, wr_[tid],       a0);
        a1 = fmaf(vv, wr_[tid + 256], a1);
        a2 = fmaf(vv, wr_[tid + 512], a2);
    }
    const size_t o = (size_t)r * D_IN + tid;
    x_hat[o]       = a0;
    x_hat[o + 256] = a1;
    x_hat[o + 512] = a2;
    recon[o]       = x[o]       - a0;
    recon[o + 256] = x[o + 256] - a1;
    recon[o + 512] = x[o + 512] - a2;
}

// ---------------------------------------------------------------------------
extern "C" void kernel_launch(void* const* d_in, const int* in_sizes, int n_in,
                              void* d_out, int out_size, void* d_ws, size_t ws_size,
                              hipStream_t stream)
{
    const float* x     = (const float*)d_in[0];
    const float* W_enc = (const float*)d_in[1];
    const float* W_dec = (const float*)d_in[2];
    const float* bpre  = (const float*)d_in[3];
    // d_in[4] is k (==64), hard-coded as K_TOP

    float* out   = (float*)d_out;
    float* x_hat = out;                                   // [BATCH, D_IN]
    float* z     = x_hat + (size_t)BATCH * D_IN;          // [BATCH, NLAT]
    float* z_pre = z     + (size_t)BATCH * NLAT;          // [BATCH, NLAT]
    float* recon = z_pre + (size_t)BATCH * NLAT;          // [BATCH, D_IN]

    const size_t ws_need = (size_t)BATCH * K_TOP * (sizeof(int) + sizeof(float));
    const bool have_ws = (d_ws != nullptr) && (ws_size >= ws_need);
    int*   idx_ws = have_ws ? (int*)d_ws : nullptr;
    float* val_ws = have_ws ? (float*)((char*)d_ws + (size_t)BATCH * K_TOP * sizeof(int)) : nullptr;

    dim3 g1(NLAT / GBN, BATCH / GBM);
    enc_gemm_mfma<<<g1, 256, 0, stream>>>(x, W_enc, bpre, z_pre);

    topk_kernel<<<BATCH, 1024, 0, stream>>>(z_pre, z, x, W_enc, bpre, idx_ws, val_ws);

    if (have_ws)
        dec_kernel<<<BATCH, 256, 0, stream>>>(idx_ws, val_ws, W_dec, bpre, x, x_hat, recon);
    else
        dec_scan_kernel<<<BATCH, 256, 0, stream>>>(z, W_dec, bpre, x, x_hat, recon);
}

// Round 4
// 1412.301 us; speedup vs baseline: 3.5390x; 1.2271x over previous
//
#include <hip/hip_runtime.h>

#define D_IN   768
#define NLAT   24576
#define BATCH  4096
#define K_TOP  64
#define MAXA   1024
#define DELTA  2.0e-3f
#define THRESH 1.30f
#define CAND_MAX 512
#define MAXAMB 64

typedef float f32x4 __attribute__((ext_vector_type(4)));
typedef short short8 __attribute__((ext_vector_type(8)));

// ---------------------------------------------------------------------------
__device__ __forceinline__ unsigned f2key(float f) {
    unsigned u = __float_as_uint(f);
    return (u & 0x80000000u) ? ~u : (u | 0x80000000u);
}
__device__ __forceinline__ float key2f(unsigned k) {
    unsigned u = (k & 0x80000000u) ? (k & 0x7fffffffu) : ~k;
    return __uint_as_float(u);
}
__device__ __forceinline__ unsigned short bf16hi(float f) {   // RNE f32->bf16
    unsigned u = __float_as_uint(f);
    unsigned r = u + 0x7fffu + ((u >> 16) & 1u);
    return (unsigned short)(r >> 16);
}
__device__ __forceinline__ float bf2f(unsigned short h) {
    return __uint_as_float(((unsigned)h) << 16);
}
// value edge of histogram bin b (positive floats, upper-16-bit binning)
__device__ __forceinline__ float binedge(int b) {
    return __uint_as_float((unsigned)(16288 + b) << 16);   // 16288 = 0x3FA0 -> 1.25f
}

// ---------------------------------------------------------------------------
// Encoder GEMM via split-2 bf16 MFMA + fused top-k candidate extraction.
// ---------------------------------------------------------------------------
#define GBM 128
#define GBN 128
#define GBK 32
#define LROW (GBK + 8)

__global__ __launch_bounds__(256) void enc_gemm_mfma(const float* __restrict__ x,
                                                     const float* __restrict__ W,
                                                     const float* __restrict__ bpre,
                                                     float* __restrict__ z_pre,
                                                     int* __restrict__ cnt_ws,
                                                     int* __restrict__ cand_idx,
                                                     float* __restrict__ cand_val)
{
    __shared__ unsigned short Ah[GBM][LROW], Al[GBM][LROW];
    __shared__ unsigned short Bh[GBN][LROW], Bl[GBN][LROW];

    const int tid = threadIdx.x;
    const int bm = blockIdx.y * GBM;
    const int bn = blockIdx.x * GBN;
    const int lane = tid & 63;
    const int wv = tid >> 6;
    const int wr = (wv >> 1) * 64;
    const int wc = (wv & 1) * 64;
    const int fr = lane & 15;
    const int fg = lane >> 4;

    const int srow = tid >> 3;
    const int sk   = (tid & 7) * 4;

    f32x4 acc[4][4];
    #pragma unroll
    for (int i = 0; i < 4; ++i)
        #pragma unroll
        for (int j = 0; j < 4; ++j)
            #pragma unroll
            for (int e = 0; e < 4; ++e) acc[i][j][e] = 0.0f;

    for (int k0 = 0; k0 < D_IN; k0 += GBK) {
        float4 xa[4], wb[4];
        const float4 bp = *(const float4*)(bpre + k0 + sk);
        #pragma unroll
        for (int p = 0; p < 4; ++p) {
            xa[p] = *(const float4*)(x + (size_t)(bm + srow + 32*p) * D_IN + k0 + sk);
            wb[p] = *(const float4*)(W + (size_t)(bn + srow + 32*p) * D_IN + k0 + sk);
        }
        __syncthreads();
        #pragma unroll
        for (int p = 0; p < 4; ++p) {
            const float a0 = xa[p].x - bp.x, a1 = xa[p].y - bp.y,
                        a2 = xa[p].z - bp.z, a3 = xa[p].w - bp.w;
            const unsigned short h0 = bf16hi(a0), h1 = bf16hi(a1),
                                 h2 = bf16hi(a2), h3 = bf16hi(a3);
            *(ushort4*)&Ah[srow + 32*p][sk] = make_ushort4(h0, h1, h2, h3);
            *(ushort4*)&Al[srow + 32*p][sk] = make_ushort4(
                bf16hi(a0 - bf2f(h0)), bf16hi(a1 - bf2f(h1)),
                bf16hi(a2 - bf2f(h2)), bf16hi(a3 - bf2f(h3)));
            const float b0 = wb[p].x, b1 = wb[p].y, b2 = wb[p].z, b3 = wb[p].w;
            const unsigned short g0 = bf16hi(b0), g1 = bf16hi(b1),
                                 g2 = bf16hi(b2), g3 = bf16hi(b3);
            *(ushort4*)&Bh[srow + 32*p][sk] = make_ushort4(g0, g1, g2, g3);
            *(ushort4*)&Bl[srow + 32*p][sk] = make_ushort4(
                bf16hi(b0 - bf2f(g0)), bf16hi(b1 - bf2f(g1)),
                bf16hi(b2 - bf2f(g2)), bf16hi(b3 - bf2f(g3)));
        }
        __syncthreads();

        short8 ah[4], al[4], bh[4], bl[4];
        #pragma unroll
        for (int t = 0; t < 4; ++t) {
            ah[t] = *(const short8*)&Ah[wr + t*16 + fr][fg * 8];
            al[t] = *(const short8*)&Al[wr + t*16 + fr][fg * 8];
            bh[t] = *(const short8*)&Bh[wc + t*16 + fr][fg * 8];
            bl[t] = *(const short8*)&Bl[wc + t*16 + fr][fg * 8];
        }
        #pragma unroll
        for (int mt = 0; mt < 4; ++mt)
            #pragma unroll
            for (int nt = 0; nt < 4; ++nt) {
                acc[mt][nt] = __builtin_amdgcn_mfma_f32_16x16x32_bf16(ah[mt], bh[nt], acc[mt][nt], 0, 0, 0);
                acc[mt][nt] = __builtin_amdgcn_mfma_f32_16x16x32_bf16(ah[mt], bl[nt], acc[mt][nt], 0, 0, 0);
                acc[mt][nt] = __builtin_amdgcn_mfma_f32_16x16x32_bf16(al[mt], bh[nt], acc[mt][nt], 0, 0, 0);
            }
    }

    // C/D layout: col = lane&15, row = (lane>>4)*4 + reg
    #pragma unroll
    for (int mt = 0; mt < 4; ++mt)
        #pragma unroll
        for (int j = 0; j < 4; ++j) {
            const int r = bm + wr + mt*16 + fg*4 + j;
            float* dst = z_pre + (size_t)r * NLAT + bn + wc;
            #pragma unroll
            for (int nt = 0; nt < 4; ++nt)
                dst[nt*16 + fr] = acc[mt][nt][j];
        }

    // Fused candidate extraction: append values > THRESH to per-row lists.
    if (cnt_ws != nullptr) {
        #pragma unroll
        for (int mt = 0; mt < 4; ++mt)
            #pragma unroll
            for (int j = 0; j < 4; ++j) {
                const int r = bm + wr + mt*16 + fg*4 + j;
                #pragma unroll
                for (int nt = 0; nt < 4; ++nt) {
                    const float vv = acc[mt][nt][j];
                    if (vv > THRESH) {
                        const int col = bn + wc + nt*16 + fr;
                        const int p = atomicAdd(&cnt_ws[r], 1);
                        if (p < CAND_MAX) {
                            cand_idx[(size_t)r * CAND_MAX + p] = col;
                            cand_val[(size_t)r * CAND_MAX + p] = vv;
                        }
                    }
                }
            }
    }
}

// ---------------------------------------------------------------------------
// Per-row top-k over the extracted candidate list (<=512).  256-bin histogram
// on the float's upper 16 bits locates the bin containing v64; candidates
// within [bin_lo-DELTA, bin_hi+DELTA] get exact f64 dots and are ranked
// (f64 desc, idx asc) == f64 reference selection.  Writes the full z row
// (zeros + keepers) and the (idx,val) list in index order.  Rows violating
// any assumption are flagged for the fallback kernel.
// ---------------------------------------------------------------------------
__global__ __launch_bounds__(256) void topk_small(const int* __restrict__ cnt_ws,
                                                  const int* __restrict__ cand_idx,
                                                  const float* __restrict__ cand_val,
                                                  const float* __restrict__ x,
                                                  const float* __restrict__ W_enc,
                                                  const float* __restrict__ bpre,
                                                  float* __restrict__ z,
                                                  int* __restrict__ idx_ws,
                                                  float* __restrict__ val_ws,
                                                  int* __restrict__ flag_ws)
{
    __shared__ float cv[CAND_MAX];
    __shared__ int   ci[CAND_MAX];
    __shared__ unsigned char keep[CAND_MAX];
    __shared__ unsigned hist[256];
    __shared__ int b_sh;
    __shared__ int nsure_sh, namb_sh, nk_sh;
    __shared__ int amb[MAXAMB];
    __shared__ double ambv[MAXAMB];
    __shared__ int   t_idx[K_TOP + 8];
    __shared__ float t_val[K_TOP + 8];
    __shared__ int   kidx[K_TOP];
    __shared__ float kval[K_TOP];
    __shared__ unsigned bitmap[NLAT / 32];   // 3 KB

    const int r = blockIdx.x;
    const int tid = threadIdx.x;
    const int cnt = cnt_ws[r];

    if (cnt < K_TOP || cnt > CAND_MAX) { if (tid == 0) flag_ws[r] = 1; return; }
    if (tid == 0) { flag_ws[r] = 0; nsure_sh = 0; namb_sh = 0; nk_sh = 0; }
    if (tid < 256) hist[tid] = 0u;

    for (int q = tid; q < cnt; q += 256) {
        const float vv = cand_val[(size_t)r * CAND_MAX + q];
        cv[q] = vv;
        ci[q] = cand_idx[(size_t)r * CAND_MAX + q];
        int b = (int)(__float_as_uint(vv) >> 16) - 16288;
        b = b < 0 ? 0 : (b > 255 ? 255 : b);
        atomicAdd(&hist[b], 1u);
    }
    __syncthreads();

    if (tid == 0) {
        int acc = 0, b = 255;
        for (; b >= 0; --b) {
            const int nb = acc + (int)hist[b];
            if (nb >= K_TOP) break;
            acc = nb;
        }
        b_sh = b;
    }
    __syncthreads();

    const int bstar = b_sh;
    const float hi = binedge(bstar + 1) + DELTA;
    const float lo = binedge(bstar) - DELTA;
    if (bstar >= 255 || bstar < 0 || lo <= THRESH + 1e-3f) {
        if (tid == 0) flag_ws[r] = 1;
        return;
    }

    for (int t = tid; t < cnt; t += 256) {
        const float vt = cv[t];
        if (vt > hi) { keep[t] = 1; atomicAdd(&nsure_sh, 1); }
        else if (vt >= lo) {
            const int p = atomicAdd(&namb_sh, 1);
            if (p < MAXAMB) amb[p] = t;
            keep[t] = 0;
        } else keep[t] = 0;
    }
    __syncthreads();

    const int nsure = nsure_sh;
    const int namb = namb_sh;
    if (namb > MAXAMB || nsure >= K_TOP) { if (tid == 0) flag_ws[r] = 1; return; }
    const int nkeep_amb = K_TOP - nsure;

    // exact f64 dots for ambiguous candidates (one wave each)
    const int lane = tid & 63, w = tid >> 6;
    for (int q = w; q < namb; q += 4) {
        const int j = ci[amb[q]];
        const float* wrow = W_enc + (size_t)j * D_IN;
        const float* xrow = x + (size_t)r * D_IN;
        double a = 0.0;
        for (int k = lane; k < D_IN; k += 64)
            a = fma((double)xrow[k] - (double)bpre[k], (double)wrow[k], a);
        #pragma unroll
        for (int off = 32; off; off >>= 1) a += __shfl_down(a, off, 64);
        if (lane == 0) ambv[q] = a;
    }
    __syncthreads();

    for (int t = tid; t < namb; t += 256) {
        const double dv = ambv[t];
        const int it = ci[amb[t]];
        int rk = 0;
        for (int q = 0; q < namb; ++q)
            rk += (ambv[q] > dv) || (ambv[q] == dv && ci[amb[q]] < it);
        if (rk < nkeep_amb) keep[amb[t]] = 1;
    }
    __syncthreads();

    // compact keepers (arbitrary order), then rank by index (deterministic)
    for (int t = tid; t < cnt; t += 256) {
        if (keep[t]) {
            const int p = atomicAdd(&nk_sh, 1);
            if (p < K_TOP + 8) { t_idx[p] = ci[t]; t_val[p] = cv[t]; }
        }
    }
    __syncthreads();
    if (nk_sh != K_TOP) { if (tid == 0) flag_ws[r] = 1; return; }

    if (tid < K_TOP) {
        const int it = t_idx[tid];
        int pos = 0;
        #pragma unroll 8
        for (int s = 0; s < K_TOP; ++s) pos += (t_idx[s] < it);
        kidx[pos] = it; kval[pos] = t_val[tid];
        idx_ws[r * K_TOP + pos] = it;
        val_ws[r * K_TOP + pos] = t_val[tid];
    }
    for (int i = tid; i < NLAT / 32; i += 256) bitmap[i] = 0u;
    __syncthreads();
    if (tid < K_TOP) atomicOr(&bitmap[kidx[tid] >> 5], 1u << (kidx[tid] & 31));
    __syncthreads();

    // write full z row: zeros + keepers, coalesced float4
    float* zrow = z + (size_t)r * NLAT;
    #pragma unroll
    for (int u = 0; u < NLAT / 4 / 256; ++u) {
        const int f4 = u * 256 + tid;
        const unsigned nib = (bitmap[f4 >> 3] >> ((f4 & 7) * 4)) & 0xFu;
        float4 o = make_float4(0.f, 0.f, 0.f, 0.f);
        if (nib) {
            const int base = f4 * 4;
            #pragma unroll
            for (int b = 0; b < 4; ++b) if ((nib >> b) & 1u) {
                const int target = base + b;
                float vv = 0.f;
                for (int s = 0; s < K_TOP; ++s) if (kidx[s] == target) { vv = kval[s]; break; }
                ((float*)&o)[b] = vv;
            }
        }
        ((float4*)zrow)[f4] = o;
    }
}

// ---------------------------------------------------------------------------
// Fallback full-row top-k (r3-verified).  Processes only flagged rows (or all
// rows when flag==nullptr).
// ---------------------------------------------------------------------------
__global__ __launch_bounds__(1024) void topk_fallback(const float* __restrict__ z_pre,
                                                      float* __restrict__ z,
                                                      const float* __restrict__ x,
                                                      const float* __restrict__ W_enc,
                                                      const float* __restrict__ bpre,
                                                      int* __restrict__ idx_ws,
                                                      float* __restrict__ val_ws,
                                                      const int* __restrict__ flag_ws)
{
    if (flag_ws != nullptr && flag_ws[blockIdx.x] == 0) return;

    __shared__ unsigned hist_w[16][257];
    __shared__ unsigned hist[256];
    __shared__ unsigned sh_prefix;
    __shared__ int sh_rem;
    __shared__ int cntA;
    __shared__ int nsure_sh;
    __shared__ int idxA[MAXA];
    __shared__ double dvalA[MAXA];
    __shared__ unsigned char keepA[MAXA];
    __shared__ int wcnt[16][24];

    const int r = blockIdx.x;
    const int tid = threadIdx.x;
    const int lane = tid & 63;
    const int w = tid >> 6;
    const unsigned long long lt = (1ull << lane) - 1ull;

    const float* src = z_pre + (size_t)r * NLAT;
    float v[24];
    #pragma unroll
    for (int c = 0; c < 24; ++c) v[c] = src[c*1024 + tid];

    if (tid == 0) { sh_prefix = 0u; sh_rem = K_TOP; cntA = 0; nsure_sh = 0; }
    if (idx_ws != nullptr && tid < K_TOP) {
        idx_ws[r*K_TOP + tid] = 0; val_ws[r*K_TOP + tid] = 0.0f;
    }

    for (int lvl = 0; lvl < 4; ++lvl) {
        const int shift = 24 - 8*lvl;
        for (int i = tid; i < 16*257; i += 1024) ((unsigned*)hist_w)[i] = 0u;
        __syncthreads();
        const unsigned pfx = sh_prefix;
        #pragma unroll
        for (int c = 0; c < 24; ++c) {
            const unsigned key = f2key(v[c]);
            const bool match = (lvl == 0) || ((key >> (shift + 8)) == (pfx >> (shift + 8)));
            if (match) atomicAdd(&hist_w[w][(key >> shift) & 255u], 1u);
        }
        __syncthreads();
        if (tid < 256) {
            unsigned s = 0;
            #pragma unroll
            for (int q = 0; q < 16; ++q) s += hist_w[q][tid];
            hist[tid] = s;
        }
        __syncthreads();
        if (tid == 0) {
            int rem = sh_rem, acc = 0, b = 255;
            for (; b >= 0; --b) {
                const int nb = acc + (int)hist[b];
                if (nb >= rem) { sh_rem = rem - acc; break; }
                acc = nb;
            }
            sh_prefix = pfx | ((unsigned)b << shift);
        }
        __syncthreads();
    }

    const float vT = key2f(sh_prefix);
    const float thr_lo = vT - DELTA, thr_hi = vT + DELTA;

    int wsure = 0;
    #pragma unroll
    for (int c = 0; c < 24; ++c) {
        const float val = v[c];
        const unsigned long long m = __ballot(val > thr_hi);
        if (lane == 0) wsure += (int)__popcll(m);
        if (val <= thr_hi && val >= thr_lo) {
            const int p = atomicAdd(&cntA, 1);
            if (p < MAXA) idxA[p] = c*1024 + tid;
        }
    }
    if (lane == 0 && wsure) atomicAdd(&nsure_sh, (unsigned)wsure);
    __syncthreads();

    const int nA = cntA < MAXA ? cntA : MAXA;
    const int nkeepA = K_TOP - nsure_sh;

    for (int q = w; q < nA; q += 16) {
        const int j = idxA[q];
        const float* wrow = W_enc + (size_t)j * D_IN;
        const float* xrow = x + (size_t)r * D_IN;
        double a = 0.0;
        for (int k = lane; k < D_IN; k += 64)
            a = fma((double)xrow[k] - (double)bpre[k], (double)wrow[k], a);
        #pragma unroll
        for (int off = 32; off; off >>= 1) a += __shfl_down(a, off, 64);
        if (lane == 0) dvalA[q] = a;
    }
    __syncthreads();

    for (int t = tid; t < nA; t += 1024) {
        const double dv = dvalA[t];
        const int ix = idxA[t];
        int rank = 0;
        for (int q = 0; q < nA; ++q)
            rank += (dvalA[q] > dv) || (dvalA[q] == dv && idxA[q] < ix);
        keepA[t] = (rank < nkeepA) ? 1 : 0;
    }
    __syncthreads();

    bool kp[24];
    #pragma unroll
    for (int c = 0; c < 24; ++c) {
        const float val = v[c];
        bool k = (val > thr_hi);
        if (!k && val >= thr_lo) {
            const int i = c*1024 + tid;
            for (int q = 0; q < nA; ++q)
                if (idxA[q] == i) { k = (keepA[q] != 0); break; }
        }
        kp[c] = k;
        const unsigned long long m = __ballot(k);
        if (lane == 0) wcnt[w][c] = (int)__popcll(m);
    }
    __syncthreads();
    if (tid == 0) {
        int run = 0;
        for (int c = 0; c < 24; ++c)
            #pragma unroll
            for (int q = 0; q < 16; ++q) { const int t = wcnt[q][c]; wcnt[q][c] = run; run += t; }
    }
    __syncthreads();

    float* zdst = z + (size_t)r * NLAT;
    #pragma unroll
    for (int c = 0; c < 24; ++c) {
        const unsigned long long m = __ballot(kp[c]);
        const int pos = wcnt[w][c] + (int)__popcll(m & lt);
        const int i = c*1024 + tid;
        zdst[i] = kp[c] ? v[c] : 0.0f;
        if (kp[c] && idx_ws != nullptr && pos < K_TOP) {
            idx_ws[r*K_TOP + pos] = i;
            val_ws[r*K_TOP + pos] = v[c];
        }
    }
}

// ---------------------------------------------------------------------------
__global__ __launch_bounds__(256) void dec_kernel(const int* __restrict__ idx_ws,
                                                  const float* __restrict__ val_ws,
                                                  const float* __restrict__ W_dec,
                                                  const float* __restrict__ bpre,
                                                  const float* __restrict__ x,
                                                  float* __restrict__ x_hat,
                                                  float* __restrict__ recon)
{
    __shared__ int sidx[K_TOP];
    __shared__ float sval[K_TOP];
    const int r = blockIdx.x;
    const int tid = threadIdx.x;
    if (tid < K_TOP) {
        sidx[tid] = idx_ws[r*K_TOP + tid];
        sval[tid] = val_ws[r*K_TOP + tid];
    }
    __syncthreads();

    float a0 = bpre[tid], a1 = bpre[tid + 256], a2 = bpre[tid + 512];
    #pragma unroll 4
    for (int j = 0; j < K_TOP; ++j) {
        const float vv = sval[j];
        const float* wr_ = W_dec + (size_t)sidx[j] * D_IN;
        a0 = fmaf(vv, wr_[tid],       a0);
        a1 = fmaf(vv, wr_[tid + 256], a1);
        a2 = fmaf(vv, wr_[tid + 512], a2);
    }
    const size_t o = (size_t)r * D_IN + tid;
    x_hat[o]       = a0;
    x_hat[o + 256] = a1;
    x_hat[o + 512] = a2;
    recon[o]       = x[o]       - a0;
    recon[o + 256] = x[o + 256] - a1;
    recon[o + 512] = x[o + 512] - a2;
}

__global__ __launch_bounds__(256) void dec_scan_kernel(const float* __restrict__ z,
                                                       const float* __restrict__ W_dec,
                                                       const float* __restrict__ bpre,
                                                       const float* __restrict__ x,
                                                       float* __restrict__ x_hat,
                                                       float* __restrict__ recon)
{
    __shared__ int sidx[K_TOP];
    __shared__ float sval[K_TOP];
    __shared__ int wcnt[4];
    __shared__ int base;
    const int r = blockIdx.x;
    const int tid = threadIdx.x;
    const int lane = tid & 63, w = tid >> 6;
    if (tid == 0) base = 0;
    __syncthreads();
    const float* zrow = z + (size_t)r * NLAT;
    for (int c = 0; c < NLAT; c += 256) {
        const float vv = zrow[c + tid];
        const bool nz = (vv != 0.0f);
        const unsigned long long m = __ballot(nz);
        if (lane == 0) wcnt[w] = __popcll(m);
        __syncthreads();
        int b = base;
        for (int j = 0; j < w; ++j) b += wcnt[j];
        const int pos = b + __popcll(m & ((1ull << lane) - 1ull));
        if (nz && pos < K_TOP) { sidx[pos] = c + tid; sval[pos] = vv; }
        __syncthreads();
        if (tid == 0) { int s = 0; for (int j = 0; j < 4; ++j) s += wcnt[j]; base += s; }
        __syncthreads();
    }
    const int n = base > K_TOP ? K_TOP : base;

    float a0 = bpre[tid], a1 = bpre[tid + 256], a2 = bpre[tid + 512];
    for (int j = 0; j < n; ++j) {
        const float vv = sval[j];
        const float* wr_ = W_dec + (size_t)sidx[j] * D_IN;
        a0 = fmaf(vv, wr_[tid],       a0);
        a1 = fmaf(vv, wr_[tid + 256], a1);
        a2 = fmaf(vv, wr_[tid + 512], a2);
    }
    const size_t o = (size_t)r * D_IN + tid;
    x_hat[o]       = a0;
    x_hat[o + 256] = a1;
    x_hat[o + 512] = a2;
    recon[o]       = x[o]       - a0;
    recon[o + 256] = x[o + 256] - a1;
    recon[o + 512] = x[o + 512] - a2;
}

// ---------------------------------------------------------------------------
extern "C" void kernel_launch(void* const* d_in, const int* in_sizes, int n_in,
                              void* d_out, int out_size, void* d_ws, size_t ws_size,
                              hipStream_t stream)
{
    const float* x     = (const float*)d_in[0];
    const float* W_enc = (const float*)d_in[1];
    const float* W_dec = (const float*)d_in[2];
    const float* bpre  = (const float*)d_in[3];

    float* out   = (float*)d_out;
    float* x_hat = out;
    float* z     = x_hat + (size_t)BATCH * D_IN;
    float* z_pre = z     + (size_t)BATCH * NLAT;
    float* recon = z_pre + (size_t)BATCH * NLAT;

    // ws layout: cnt | flag | cand_idx | cand_val | idx_ws | val_ws
    char* p = (char*)d_ws;
    int*   cnt_ws   = (int*)p;                       p += (size_t)BATCH * 4;
    int*   flag_ws  = (int*)p;                       p += (size_t)BATCH * 4;
    int*   cand_idx = (int*)p;                       p += (size_t)BATCH * CAND_MAX * 4;
    float* cand_val = (float*)p;                     p += (size_t)BATCH * CAND_MAX * 4;
    int*   idx_ws   = (int*)p;                       p += (size_t)BATCH * K_TOP * 4;
    float* val_ws   = (float*)p;                     p += (size_t)BATCH * K_TOP * 4;
    const size_t ws_need = (size_t)(p - (char*)d_ws);
    const bool have_ws = (d_ws != nullptr) && (ws_size >= ws_need);

    dim3 g1(NLAT / GBN, BATCH / GBM);

    if (have_ws) {
        hipMemsetAsync(cnt_ws, 0, (size_t)BATCH * 4, stream);
        enc_gemm_mfma<<<g1, 256, 0, stream>>>(x, W_enc, bpre, z_pre, cnt_ws, cand_idx, cand_val);
        topk_small<<<BATCH, 256, 0, stream>>>(cnt_ws, cand_idx, cand_val, x, W_enc, bpre,
                                              z, idx_ws, val_ws, flag_ws);
        topk_fallback<<<BATCH, 1024, 0, stream>>>(z_pre, z, x, W_enc, bpre, idx_ws, val_ws, flag_ws);
        dec_kernel<<<BATCH, 256, 0, stream>>>(idx_ws, val_ws, W_dec, bpre, x, x_hat, recon);
    } else {
        enc_gemm_mfma<<<g1, 256, 0, stream>>>(x, W_enc, bpre, z_pre, nullptr, nullptr, nullptr);
        topk_fallback<<<BATCH, 1024, 0, stream>>>(z_pre, z, x, W_enc, bpre, nullptr, nullptr, nullptr);
        dec_scan_kernel<<<BATCH, 256, 0, stream>>>(z, W_dec, bpre, x, x_hat, recon);
    }
}

// Round 5
// 1140.712 us; speedup vs baseline: 4.3816x; 1.2381x over previous
//
#include <hip/hip_runtime.h>

#define D_IN   768
#define NLAT   24576
#define BATCH  4096
#define K_TOP  64
#define MAXA   1024
#define DELTA  2.0e-3f
#define THRESH 1.30f
#define CAND_MAX 512
#define MAXAMB 64

typedef float f32x4 __attribute__((ext_vector_type(4)));
typedef short short8 __attribute__((ext_vector_type(8)));

// ---------------------------------------------------------------------------
__device__ __forceinline__ unsigned f2key(float f) {
    unsigned u = __float_as_uint(f);
    return (u & 0x80000000u) ? ~u : (u | 0x80000000u);
}
__device__ __forceinline__ float key2f(unsigned k) {
    unsigned u = (k & 0x80000000u) ? (k & 0x7fffffffu) : ~k;
    return __uint_as_float(u);
}
__device__ __forceinline__ unsigned short bf16hi(float f) {   // RNE f32->bf16
    unsigned u = __float_as_uint(f);
    unsigned r = u + 0x7fffu + ((u >> 16) & 1u);
    return (unsigned short)(r >> 16);
}
__device__ __forceinline__ float bf2f(unsigned short h) {
    return __uint_as_float(((unsigned)h) << 16);
}
// value edge of histogram bin b (positive floats, upper-16-bit binning)
__device__ __forceinline__ float binedge(int b) {
    return __uint_as_float((unsigned)(16288 + b) << 16);   // 16288 = 0x3FA0 -> 1.25f
}

// ---------------------------------------------------------------------------
// Encoder GEMM via split-2 bf16 MFMA (exact r3 kernel, no extraction).
// ---------------------------------------------------------------------------
#define GBM 128
#define GBN 128
#define GBK 32
#define LROW (GBK + 8)

__global__ __launch_bounds__(256) void enc_gemm_mfma(const float* __restrict__ x,
                                                     const float* __restrict__ W,
                                                     const float* __restrict__ bpre,
                                                     float* __restrict__ z_pre)
{
    __shared__ unsigned short Ah[GBM][LROW], Al[GBM][LROW];
    __shared__ unsigned short Bh[GBN][LROW], Bl[GBN][LROW];

    const int tid = threadIdx.x;
    const int bm = blockIdx.y * GBM;
    const int bn = blockIdx.x * GBN;
    const int lane = tid & 63;
    const int wv = tid >> 6;
    const int wr = (wv >> 1) * 64;
    const int wc = (wv & 1) * 64;
    const int fr = lane & 15;
    const int fg = lane >> 4;

    const int srow = tid >> 3;
    const int sk   = (tid & 7) * 4;

    f32x4 acc[4][4];
    #pragma unroll
    for (int i = 0; i < 4; ++i)
        #pragma unroll
        for (int j = 0; j < 4; ++j)
            #pragma unroll
            for (int e = 0; e < 4; ++e) acc[i][j][e] = 0.0f;

    for (int k0 = 0; k0 < D_IN; k0 += GBK) {
        float4 xa[4], wb[4];
        const float4 bp = *(const float4*)(bpre + k0 + sk);
        #pragma unroll
        for (int p = 0; p < 4; ++p) {
            xa[p] = *(const float4*)(x + (size_t)(bm + srow + 32*p) * D_IN + k0 + sk);
            wb[p] = *(const float4*)(W + (size_t)(bn + srow + 32*p) * D_IN + k0 + sk);
        }
        __syncthreads();
        #pragma unroll
        for (int p = 0; p < 4; ++p) {
            const float a0 = xa[p].x - bp.x, a1 = xa[p].y - bp.y,
                        a2 = xa[p].z - bp.z, a3 = xa[p].w - bp.w;
            const unsigned short h0 = bf16hi(a0), h1 = bf16hi(a1),
                                 h2 = bf16hi(a2), h3 = bf16hi(a3);
            *(ushort4*)&Ah[srow + 32*p][sk] = make_ushort4(h0, h1, h2, h3);
            *(ushort4*)&Al[srow + 32*p][sk] = make_ushort4(
                bf16hi(a0 - bf2f(h0)), bf16hi(a1 - bf2f(h1)),
                bf16hi(a2 - bf2f(h2)), bf16hi(a3 - bf2f(h3)));
            const float b0 = wb[p].x, b1 = wb[p].y, b2 = wb[p].z, b3 = wb[p].w;
            const unsigned short g0 = bf16hi(b0), g1 = bf16hi(b1),
                                 g2 = bf16hi(b2), g3 = bf16hi(b3);
            *(ushort4*)&Bh[srow + 32*p][sk] = make_ushort4(g0, g1, g2, g3);
            *(ushort4*)&Bl[srow + 32*p][sk] = make_ushort4(
                bf16hi(b0 - bf2f(g0)), bf16hi(b1 - bf2f(g1)),
                bf16hi(b2 - bf2f(g2)), bf16hi(b3 - bf2f(g3)));
        }
        __syncthreads();

        short8 ah[4], al[4], bh[4], bl[4];
        #pragma unroll
        for (int t = 0; t < 4; ++t) {
            ah[t] = *(const short8*)&Ah[wr + t*16 + fr][fg * 8];
            al[t] = *(const short8*)&Al[wr + t*16 + fr][fg * 8];
            bh[t] = *(const short8*)&Bh[wc + t*16 + fr][fg * 8];
            bl[t] = *(const short8*)&Bl[wc + t*16 + fr][fg * 8];
        }
        #pragma unroll
        for (int mt = 0; mt < 4; ++mt)
            #pragma unroll
            for (int nt = 0; nt < 4; ++nt) {
                acc[mt][nt] = __builtin_amdgcn_mfma_f32_16x16x32_bf16(ah[mt], bh[nt], acc[mt][nt], 0, 0, 0);
                acc[mt][nt] = __builtin_amdgcn_mfma_f32_16x16x32_bf16(ah[mt], bl[nt], acc[mt][nt], 0, 0, 0);
                acc[mt][nt] = __builtin_amdgcn_mfma_f32_16x16x32_bf16(al[mt], bh[nt], acc[mt][nt], 0, 0, 0);
            }
    }

    // C/D layout: col = lane&15, row = (lane>>4)*4 + reg
    #pragma unroll
    for (int mt = 0; mt < 4; ++mt)
        #pragma unroll
        for (int j = 0; j < 4; ++j) {
            const int r = bm + wr + mt*16 + fg*4 + j;
            float* dst = z_pre + (size_t)r * NLAT + bn + wc;
            #pragma unroll
            for (int nt = 0; nt < 4; ++nt)
                dst[nt*16 + fr] = acc[mt][nt][j];
        }
}

// ---------------------------------------------------------------------------
// Fused filter + top-k + z-write.  One 256-thread block per row:
//  1) float4-scan z_pre row, LDS-append values > THRESH (~300 expected)
//  2) 256-bin histogram on upper-16 float bits -> bin containing v64
//  3) candidates within [bin_lo-DELTA, bin_hi+DELTA] -> exact f64 dots,
//     ranked (f64 desc, idx asc)  == f64 reference selection
//  4) write (idx,val) in index order + full z row from LDS bitmap
// Rows violating any statistical assumption are flagged for the fallback.
// ---------------------------------------------------------------------------
__global__ __launch_bounds__(256) void topk_fused(const float* __restrict__ z_pre,
                                                  float* __restrict__ z,
                                                  const float* __restrict__ x,
                                                  const float* __restrict__ W_enc,
                                                  const float* __restrict__ bpre,
                                                  int* __restrict__ idx_ws,
                                                  float* __restrict__ val_ws,
                                                  int* __restrict__ flag_ws)
{
    __shared__ float cv[CAND_MAX];
    __shared__ int   ci[CAND_MAX];
    __shared__ unsigned char keep[CAND_MAX];
    __shared__ unsigned hist[256];
    __shared__ int cnt_sh, b_sh;
    __shared__ int nsure_sh, namb_sh, nk_sh;
    __shared__ int amb[MAXAMB];
    __shared__ double ambv[MAXAMB];
    __shared__ int   t_idx[K_TOP + 8];
    __shared__ float t_val[K_TOP + 8];
    __shared__ int   kidx[K_TOP];
    __shared__ float kval[K_TOP];
    __shared__ unsigned bitmap[NLAT / 32];   // 3 KB

    const int r = blockIdx.x;
    const int tid = threadIdx.x;

    if (tid == 0) { cnt_sh = 0; nsure_sh = 0; namb_sh = 0; nk_sh = 0; }
    if (tid < 256) hist[tid] = 0u;
    __syncthreads();

    // ---- 1) scan + filter ----
    const float4* src = (const float4*)(z_pre + (size_t)r * NLAT);
    #pragma unroll
    for (int u = 0; u < NLAT / 4 / 256; ++u) {
        const int f4 = u * 256 + tid;
        const float4 v4 = src[f4];
        #pragma unroll
        for (int b = 0; b < 4; ++b) {
            const float vv = ((const float*)&v4)[b];
            if (vv > THRESH) {
                const int p = atomicAdd(&cnt_sh, 1);
                if (p < CAND_MAX) { cv[p] = vv; ci[p] = f4 * 4 + b; }
            }
        }
    }
    __syncthreads();

    const int cnt = cnt_sh;
    if (cnt < K_TOP || cnt > CAND_MAX) { if (tid == 0) flag_ws[r] = 1; return; }
    if (tid == 0) flag_ws[r] = 0;

    // ---- 2) histogram + bin select ----
    for (int q = tid; q < cnt; q += 256) {
        int b = (int)(__float_as_uint(cv[q]) >> 16) - 16288;
        b = b < 0 ? 0 : (b > 255 ? 255 : b);
        atomicAdd(&hist[b], 1u);
    }
    __syncthreads();
    if (tid == 0) {
        int acc = 0, b = 255;
        for (; b >= 0; --b) {
            const int nb = acc + (int)hist[b];
            if (nb >= K_TOP) break;
            acc = nb;
        }
        b_sh = b;
    }
    __syncthreads();

    const int bstar = b_sh;
    const float hi = binedge(bstar + 1) + DELTA;
    const float lo = binedge(bstar) - DELTA;
    if (bstar >= 255 || bstar < 0 || lo <= THRESH + 1e-3f) {
        if (tid == 0) flag_ws[r] = 1;
        return;
    }

    // ---- 3) classify; exact f64 refine on the ambiguous window ----
    for (int t = tid; t < cnt; t += 256) {
        const float vt = cv[t];
        if (vt > hi) { keep[t] = 1; atomicAdd(&nsure_sh, 1); }
        else if (vt >= lo) {
            const int p = atomicAdd(&namb_sh, 1);
            if (p < MAXAMB) amb[p] = t;
            keep[t] = 0;
        } else keep[t] = 0;
    }
    __syncthreads();

    const int nsure = nsure_sh;
    const int namb = namb_sh;
    if (namb > MAXAMB || nsure >= K_TOP) { if (tid == 0) flag_ws[r] = 1; return; }
    const int nkeep_amb = K_TOP - nsure;

    const int lane = tid & 63, w = tid >> 6;
    for (int q = w; q < namb; q += 4) {
        const int j = ci[amb[q]];
        const float* wrow = W_enc + (size_t)j * D_IN;
        const float* xrow = x + (size_t)r * D_IN;
        double a = 0.0;
        for (int k = lane; k < D_IN; k += 64)
            a = fma((double)xrow[k] - (double)bpre[k], (double)wrow[k], a);
        #pragma unroll
        for (int off = 32; off; off >>= 1) a += __shfl_down(a, off, 64);
        if (lane == 0) ambv[q] = a;
    }
    __syncthreads();

    for (int t = tid; t < namb; t += 256) {
        const double dv = ambv[t];
        const int it = ci[amb[t]];
        int rk = 0;
        for (int q = 0; q < namb; ++q)
            rk += (ambv[q] > dv) || (ambv[q] == dv && ci[amb[q]] < it);
        if (rk < nkeep_amb) keep[amb[t]] = 1;
    }
    __syncthreads();

    // ---- 4) compact keepers, rank by index, write ws + z ----
    for (int t = tid; t < cnt; t += 256) {
        if (keep[t]) {
            const int p = atomicAdd(&nk_sh, 1);
            if (p < K_TOP + 8) { t_idx[p] = ci[t]; t_val[p] = cv[t]; }
        }
    }
    __syncthreads();
    if (nk_sh != K_TOP) { if (tid == 0) flag_ws[r] = 1; return; }

    if (tid < K_TOP) {
        const int it = t_idx[tid];
        int pos = 0;
        #pragma unroll 8
        for (int s = 0; s < K_TOP; ++s) pos += (t_idx[s] < it);
        kidx[pos] = it; kval[pos] = t_val[tid];
        idx_ws[r * K_TOP + pos] = it;
        val_ws[r * K_TOP + pos] = t_val[tid];
    }
    for (int i = tid; i < NLAT / 32; i += 256) bitmap[i] = 0u;
    __syncthreads();
    if (tid < K_TOP) atomicOr(&bitmap[kidx[tid] >> 5], 1u << (kidx[tid] & 31));
    __syncthreads();

    float* zrow = z + (size_t)r * NLAT;
    #pragma unroll
    for (int u = 0; u < NLAT / 4 / 256; ++u) {
        const int f4 = u * 256 + tid;
        const unsigned nib = (bitmap[f4 >> 3] >> ((f4 & 7) * 4)) & 0xFu;
        float4 o = make_float4(0.f, 0.f, 0.f, 0.f);
        if (nib) {
            const int base = f4 * 4;
            #pragma unroll
            for (int b = 0; b < 4; ++b) if ((nib >> b) & 1u) {
                const int target = base + b;
                float vv = 0.f;
                for (int s = 0; s < K_TOP; ++s) if (kidx[s] == target) { vv = kval[s]; break; }
                ((float*)&o)[b] = vv;
            }
        }
        ((float4*)zrow)[f4] = o;
    }
}

// ---------------------------------------------------------------------------
// Fallback full-row top-k (r3-verified).  Processes only flagged rows (or all
// rows when flag==nullptr).
// ---------------------------------------------------------------------------
__global__ __launch_bounds__(1024) void topk_fallback(const float* __restrict__ z_pre,
                                                      float* __restrict__ z,
                                                      const float* __restrict__ x,
                                                      const float* __restrict__ W_enc,
                                                      const float* __restrict__ bpre,
                                                      int* __restrict__ idx_ws,
                                                      float* __restrict__ val_ws,
                                                      const int* __restrict__ flag_ws)
{
    if (flag_ws != nullptr && flag_ws[blockIdx.x] == 0) return;

    __shared__ unsigned hist_w[16][257];
    __shared__ unsigned hist[256];
    __shared__ unsigned sh_prefix;
    __shared__ int sh_rem;
    __shared__ int cntA;
    __shared__ int nsure_sh;
    __shared__ int idxA[MAXA];
    __shared__ double dvalA[MAXA];
    __shared__ unsigned char keepA[MAXA];
    __shared__ int wcnt[16][24];

    const int r = blockIdx.x;
    const int tid = threadIdx.x;
    const int lane = tid & 63;
    const int w = tid >> 6;
    const unsigned long long lt = (1ull << lane) - 1ull;

    const float* src = z_pre + (size_t)r * NLAT;
    float v[24];
    #pragma unroll
    for (int c = 0; c < 24; ++c) v[c] = src[c*1024 + tid];

    if (tid == 0) { sh_prefix = 0u; sh_rem = K_TOP; cntA = 0; nsure_sh = 0; }
    if (idx_ws != nullptr && tid < K_TOP) {
        idx_ws[r*K_TOP + tid] = 0; val_ws[r*K_TOP + tid] = 0.0f;
    }

    for (int lvl = 0; lvl < 4; ++lvl) {
        const int shift = 24 - 8*lvl;
        for (int i = tid; i < 16*257; i += 1024) ((unsigned*)hist_w)[i] = 0u;
        __syncthreads();
        const unsigned pfx = sh_prefix;
        #pragma unroll
        for (int c = 0; c < 24; ++c) {
            const unsigned key = f2key(v[c]);
            const bool match = (lvl == 0) || ((key >> (shift + 8)) == (pfx >> (shift + 8)));
            if (match) atomicAdd(&hist_w[w][(key >> shift) & 255u], 1u);
        }
        __syncthreads();
        if (tid < 256) {
            unsigned s = 0;
            #pragma unroll
            for (int q = 0; q < 16; ++q) s += hist_w[q][tid];
            hist[tid] = s;
        }
        __syncthreads();
        if (tid == 0) {
            int rem = sh_rem, acc = 0, b = 255;
            for (; b >= 0; --b) {
                const int nb = acc + (int)hist[b];
                if (nb >= rem) { sh_rem = rem - acc; break; }
                acc = nb;
            }
            sh_prefix = pfx | ((unsigned)b << shift);
        }
        __syncthreads();
    }

    const float vT = key2f(sh_prefix);
    const float thr_lo = vT - DELTA, thr_hi = vT + DELTA;

    int wsure = 0;
    #pragma unroll
    for (int c = 0; c < 24; ++c) {
        const float val = v[c];
        const unsigned long long m = __ballot(val > thr_hi);
        if (lane == 0) wsure += (int)__popcll(m);
        if (val <= thr_hi && val >= thr_lo) {
            const int p = atomicAdd(&cntA, 1);
            if (p < MAXA) idxA[p] = c*1024 + tid;
        }
    }
    if (lane == 0 && wsure) atomicAdd(&nsure_sh, (unsigned)wsure);
    __syncthreads();

    const int nA = cntA < MAXA ? cntA : MAXA;
    const int nkeepA = K_TOP - nsure_sh;

    for (int q = w; q < nA; q += 16) {
        const int j = idxA[q];
        const float* wrow = W_enc + (size_t)j * D_IN;
        const float* xrow = x + (size_t)r * D_IN;
        double a = 0.0;
        for (int k = lane; k < D_IN; k += 64)
            a = fma((double)xrow[k] - (double)bpre[k], (double)wrow[k], a);
        #pragma unroll
        for (int off = 32; off; off >>= 1) a += __shfl_down(a, off, 64);
        if (lane == 0) dvalA[q] = a;
    }
    __syncthreads();

    for (int t = tid; t < nA; t += 1024) {
        const double dv = dvalA[t];
        const int ix = idxA[t];
        int rank = 0;
        for (int q = 0; q < nA; ++q)
            rank += (dvalA[q] > dv) || (dvalA[q] == dv && idxA[q] < ix);
        keepA[t] = (rank < nkeepA) ? 1 : 0;
    }
    __syncthreads();

    bool kp[24];
    #pragma unroll
    for (int c = 0; c < 24; ++c) {
        const float val = v[c];
        bool k = (val > thr_hi);
        if (!k && val >= thr_lo) {
            const int i = c*1024 + tid;
            for (int q = 0; q < nA; ++q)
                if (idxA[q] == i) { k = (keepA[q] != 0); break; }
        }
        kp[c] = k;
        const unsigned long long m = __ballot(k);
        if (lane == 0) wcnt[w][c] = (int)__popcll(m);
    }
    __syncthreads();
    if (tid == 0) {
        int run = 0;
        for (int c = 0; c < 24; ++c)
            #pragma unroll
            for (int q = 0; q < 16; ++q) { const int t = wcnt[q][c]; wcnt[q][c] = run; run += t; }
    }
    __syncthreads();

    float* zdst = z + (size_t)r * NLAT;
    #pragma unroll
    for (int c = 0; c < 24; ++c) {
        const unsigned long long m = __ballot(kp[c]);
        const int pos = wcnt[w][c] + (int)__popcll(m & lt);
        const int i = c*1024 + tid;
        zdst[i] = kp[c] ? v[c] : 0.0f;
        if (kp[c] && idx_ws != nullptr && pos < K_TOP) {
            idx_ws[r*K_TOP + pos] = i;
            val_ws[r*K_TOP + pos] = v[c];
        }
    }
}

// ---------------------------------------------------------------------------
__global__ __launch_bounds__(256) void dec_kernel(const int* __restrict__ idx_ws,
                                                  const float* __restrict__ val_ws,
                                                  const float* __restrict__ W_dec,
                                                  const float* __restrict__ bpre,
                                                  const float* __restrict__ x,
                                                  float* __restrict__ x_hat,
                                                  float* __restrict__ recon)
{
    __shared__ int sidx[K_TOP];
    __shared__ float sval[K_TOP];
    const int r = blockIdx.x;
    const int tid = threadIdx.x;
    if (tid < K_TOP) {
        sidx[tid] = idx_ws[r*K_TOP + tid];
        sval[tid] = val_ws[r*K_TOP + tid];
    }
    __syncthreads();

    float a0 = bpre[tid], a1 = bpre[tid + 256], a2 = bpre[tid + 512];
    #pragma unroll 4
    for (int j = 0; j < K_TOP; ++j) {
        const float vv = sval[j];
        const float* wr_ = W_dec + (size_t)sidx[j] * D_IN;
        a0 = fmaf(vv, wr_[tid],       a0);
        a1 = fmaf(vv, wr_[tid + 256], a1);
        a2 = fmaf(vv, wr_[tid + 512], a2);
    }
    const size_t o = (size_t)r * D_IN + tid;
    x_hat[o]       = a0;
    x_hat[o + 256] = a1;
    x_hat[o + 512] = a2;
    recon[o]       = x[o]       - a0;
    recon[o + 256] = x[o + 256] - a1;
    recon[o + 512] = x[o + 512] - a2;
}

__global__ __launch_bounds__(256) void dec_scan_kernel(const float* __restrict__ z,
                                                       const float* __restrict__ W_dec,
                                                       const float* __restrict__ bpre,
                                                       const float* __restrict__ x,
                                                       float* __restrict__ x_hat,
                                                       float* __restrict__ recon)
{
    __shared__ int sidx[K_TOP];
    __shared__ float sval[K_TOP];
    __shared__ int wcnt[4];
    __shared__ int base;
    const int r = blockIdx.x;
    const int tid = threadIdx.x;
    const int lane = tid & 63, w = tid >> 6;
    if (tid == 0) base = 0;
    __syncthreads();
    const float* zrow = z + (size_t)r * NLAT;
    for (int c = 0; c < NLAT; c += 256) {
        const float vv = zrow[c + tid];
        const bool nz = (vv != 0.0f);
        const unsigned long long m = __ballot(nz);
        if (lane == 0) wcnt[w] = __popcll(m);
        __syncthreads();
        int b = base;
        for (int j = 0; j < w; ++j) b += wcnt[j];
        const int pos = b + __popcll(m & ((1ull << lane) - 1ull));
        if (nz && pos < K_TOP) { sidx[pos] = c + tid; sval[pos] = vv; }
        __syncthreads();
        if (tid == 0) { int s = 0; for (int j = 0; j < 4; ++j) s += wcnt[j]; base += s; }
        __syncthreads();
    }
    const int n = base > K_TOP ? K_TOP : base;

    float a0 = bpre[tid], a1 = bpre[tid + 256], a2 = bpre[tid + 512];
    for (int j = 0; j < n; ++j) {
        const float vv = sval[j];
        const float* wr_ = W_dec + (size_t)sidx[j] * D_IN;
        a0 = fmaf(vv, wr_[tid],       a0);
        a1 = fmaf(vv, wr_[tid + 256], a1);
        a2 = fmaf(vv, wr_[tid + 512], a2);
    }
    const size_t o = (size_t)r * D_IN + tid;
    x_hat[o]       = a0;
    x_hat[o + 256] = a1;
    x_hat[o + 512] = a2;
    recon[o]       = x[o]       - a0;
    recon[o + 256] = x[o + 256] - a1;
    recon[o + 512] = x[o + 512] - a2;
}

// ---------------------------------------------------------------------------
extern "C" void kernel_launch(void* const* d_in, const int* in_sizes, int n_in,
                              void* d_out, int out_size, void* d_ws, size_t ws_size,
                              hipStream_t stream)
{
    const float* x     = (const float*)d_in[0];
    const float* W_enc = (const float*)d_in[1];
    const float* W_dec = (const float*)d_in[2];
    const float* bpre  = (const float*)d_in[3];

    float* out   = (float*)d_out;
    float* x_hat = out;
    float* z     = x_hat + (size_t)BATCH * D_IN;
    float* z_pre = z     + (size_t)BATCH * NLAT;
    float* recon = z_pre + (size_t)BATCH * NLAT;

    // ws layout: flag | idx_ws | val_ws
    char* p = (char*)d_ws;
    int*   flag_ws = (int*)p;                        p += (size_t)BATCH * 4;
    int*   idx_ws  = (int*)p;                        p += (size_t)BATCH * K_TOP * 4;
    float* val_ws  = (float*)p;                      p += (size_t)BATCH * K_TOP * 4;
    const size_t ws_need = (size_t)(p - (char*)d_ws);
    const bool have_ws = (d_ws != nullptr) && (ws_size >= ws_need);

    dim3 g1(NLAT / GBN, BATCH / GBM);
    enc_gemm_mfma<<<g1, 256, 0, stream>>>(x, W_enc, bpre, z_pre);

    if (have_ws) {
        topk_fused<<<BATCH, 256, 0, stream>>>(z_pre, z, x, W_enc, bpre,
                                              idx_ws, val_ws, flag_ws);
        topk_fallback<<<BATCH, 1024, 0, stream>>>(z_pre, z, x, W_enc, bpre, idx_ws, val_ws, flag_ws);
        dec_kernel<<<BATCH, 256, 0, stream>>>(idx_ws, val_ws, W_dec, bpre, x, x_hat, recon);
    } else {
        topk_fallback<<<BATCH, 1024, 0, stream>>>(z_pre, z, x, W_enc, bpre, nullptr, nullptr, nullptr);
        dec_scan_kernel<<<BATCH, 256, 0, stream>>>(z, W_dec, bpre, x, x_hat, recon);
    }
}

// Round 6
// 1081.102 us; speedup vs baseline: 4.6232x; 1.0551x over previous
//
#include <hip/hip_runtime.h>

#define D_IN   768
#define NLAT   24576
#define BATCH  4096
#define K_TOP  64
#define MAXA   1024
#define DELTA  2.0e-3f
#define THRESH 1.30f
#define CAND_MAX 512
#define MAXAMB 64

typedef float f32x4 __attribute__((ext_vector_type(4)));
typedef short short8 __attribute__((ext_vector_type(8)));

// ---------------------------------------------------------------------------
__device__ __forceinline__ unsigned f2key(float f) {
    unsigned u = __float_as_uint(f);
    return (u & 0x80000000u) ? ~u : (u | 0x80000000u);
}
__device__ __forceinline__ float key2f(unsigned k) {
    unsigned u = (k & 0x80000000u) ? (k & 0x7fffffffu) : ~k;
    return __uint_as_float(u);
}
__device__ __forceinline__ unsigned short bf16hi(float f) {   // RNE f32->bf16
    unsigned u = __float_as_uint(f);
    unsigned r = u + 0x7fffu + ((u >> 16) & 1u);
    return (unsigned short)(r >> 16);
}
__device__ __forceinline__ float bf2f(unsigned short h) {
    return __uint_as_float(((unsigned)h) << 16);
}
__device__ __forceinline__ float binedge(int b) {
    return __uint_as_float((unsigned)(16288 + b) << 16);   // bin 0 edge = 1.25f
}

// ---------------------------------------------------------------------------
// One-time split passes: v = hi + lo (bf16 RNE), written to ws.
// ---------------------------------------------------------------------------
__global__ __launch_bounds__(256) void split_x_kernel(const float4* __restrict__ src,
                                                      const float* __restrict__ bpre,
                                                      ushort4* __restrict__ hi,
                                                      ushort4* __restrict__ lo)
{
    const int f = blockIdx.x * 256 + threadIdx.x;   // < BATCH*D_IN/4
    float4 v = src[f];
    const float4 bp = ((const float4*)bpre)[f % (D_IN / 4)];
    v.x -= bp.x; v.y -= bp.y; v.z -= bp.z; v.w -= bp.w;
    ushort4 h, l;
    h.x = bf16hi(v.x); l.x = bf16hi(v.x - bf2f(h.x));
    h.y = bf16hi(v.y); l.y = bf16hi(v.y - bf2f(h.y));
    h.z = bf16hi(v.z); l.z = bf16hi(v.z - bf2f(h.z));
    h.w = bf16hi(v.w); l.w = bf16hi(v.w - bf2f(h.w));
    hi[f] = h; lo[f] = l;
}

__global__ __launch_bounds__(256) void split_w_kernel(const float4* __restrict__ src,
                                                      ushort4* __restrict__ hi,
                                                      ushort4* __restrict__ lo)
{
    const int f = blockIdx.x * 256 + threadIdx.x;   // < NLAT*D_IN/4
    const float4 v = src[f];
    ushort4 h, l;
    h.x = bf16hi(v.x); l.x = bf16hi(v.x - bf2f(h.x));
    h.y = bf16hi(v.y); l.y = bf16hi(v.y - bf2f(h.y));
    h.z = bf16hi(v.z); l.z = bf16hi(v.z - bf2f(h.z));
    h.w = bf16hi(v.w); l.w = bf16hi(v.w - bf2f(h.w));
    hi[f] = h; lo[f] = l;
}

// ---------------------------------------------------------------------------
// Encoder GEMM reading PRE-SPLIT bf16 operands.  Tile 128x128, BK=32,
// 4 waves (2x2), each 64x64 via 4x4 16x16x32 frags, 3 MFMAs (hh, hl, lh).
// Same LDS layout / fragment indexing / MFMA order as the r3-verified kernel
// => bit-identical z_pre.  XCD-bijective block swizzle (6144 % 8 == 0).
// ---------------------------------------------------------------------------
#define GBM 128
#define GBN 128
#define GBK 32
#define LROW (GBK + 8)
#define NWG  ((NLAT / GBN) * (BATCH / GBM))   // 6144

__global__ __launch_bounds__(256) void enc_gemm_pre(const unsigned short* __restrict__ xh,
                                                    const unsigned short* __restrict__ xl,
                                                    const unsigned short* __restrict__ wh,
                                                    const unsigned short* __restrict__ wl,
                                                    float* __restrict__ z_pre)
{
    __shared__ unsigned short Ah[GBM][LROW], Al[GBM][LROW];
    __shared__ unsigned short Bh[GBN][LROW], Bl[GBN][LROW];

    const int tid = threadIdx.x;
    const int bid = blockIdx.x;
    const int swz = (bid & 7) * (NWG / 8) + (bid >> 3);
    const int bn = (swz % (NLAT / GBN)) * GBN;
    const int bm = (swz / (NLAT / GBN)) * GBM;

    const int lane = tid & 63;
    const int wv = tid >> 6;
    const int wr = (wv >> 1) * 64;
    const int wc = (wv & 1) * 64;
    const int fr = lane & 15;
    const int fg = lane >> 4;

    // staging: 2048 16B-chunks per K-step over 4 arrays; 2 chunks/array/thread
    const int row0 = tid >> 2,           ko0 = (tid & 3) * 8;
    const int row1 = (tid + 256) >> 2,   ko1 = ((tid + 256) & 3) * 8;
    const unsigned short* pxh0 = xh + (size_t)(bm + row0) * D_IN + ko0;
    const unsigned short* pxl0 = xl + (size_t)(bm + row0) * D_IN + ko0;
    const unsigned short* pwh0 = wh + (size_t)(bn + row0) * D_IN + ko0;
    const unsigned short* pwl0 = wl + (size_t)(bn + row0) * D_IN + ko0;
    const unsigned short* pxh1 = xh + (size_t)(bm + row1) * D_IN + ko1;
    const unsigned short* pxl1 = xl + (size_t)(bm + row1) * D_IN + ko1;
    const unsigned short* pwh1 = wh + (size_t)(bn + row1) * D_IN + ko1;
    const unsigned short* pwl1 = wl + (size_t)(bn + row1) * D_IN + ko1;

    f32x4 acc[4][4];
    #pragma unroll
    for (int i = 0; i < 4; ++i)
        #pragma unroll
        for (int j = 0; j < 4; ++j)
            #pragma unroll
            for (int e = 0; e < 4; ++e) acc[i][j][e] = 0.0f;

    for (int k0 = 0; k0 < D_IN; k0 += GBK) {
        const short8 vxh0 = *(const short8*)(pxh0 + k0);
        const short8 vxl0 = *(const short8*)(pxl0 + k0);
        const short8 vwh0 = *(const short8*)(pwh0 + k0);
        const short8 vwl0 = *(const short8*)(pwl0 + k0);
        const short8 vxh1 = *(const short8*)(pxh1 + k0);
        const short8 vxl1 = *(const short8*)(pxl1 + k0);
        const short8 vwh1 = *(const short8*)(pwh1 + k0);
        const short8 vwl1 = *(const short8*)(pwl1 + k0);

        __syncthreads();   // previous tile's LDS reads done

        *(short8*)&Ah[row0][ko0] = vxh0;
        *(short8*)&Al[row0][ko0] = vxl0;
        *(short8*)&Bh[row0][ko0] = vwh0;
        *(short8*)&Bl[row0][ko0] = vwl0;
        *(short8*)&Ah[row1][ko1] = vxh1;
        *(short8*)&Al[row1][ko1] = vxl1;
        *(short8*)&Bh[row1][ko1] = vwh1;
        *(short8*)&Bl[row1][ko1] = vwl1;

        __syncthreads();

        short8 ah[4], al[4], bh[4], bl[4];
        #pragma unroll
        for (int t = 0; t < 4; ++t) {
            ah[t] = *(const short8*)&Ah[wr + t*16 + fr][fg * 8];
            al[t] = *(const short8*)&Al[wr + t*16 + fr][fg * 8];
            bh[t] = *(const short8*)&Bh[wc + t*16 + fr][fg * 8];
            bl[t] = *(const short8*)&Bl[wc + t*16 + fr][fg * 8];
        }
        #pragma unroll
        for (int mt = 0; mt < 4; ++mt)
            #pragma unroll
            for (int nt = 0; nt < 4; ++nt) {
                acc[mt][nt] = __builtin_amdgcn_mfma_f32_16x16x32_bf16(ah[mt], bh[nt], acc[mt][nt], 0, 0, 0);
                acc[mt][nt] = __builtin_amdgcn_mfma_f32_16x16x32_bf16(ah[mt], bl[nt], acc[mt][nt], 0, 0, 0);
                acc[mt][nt] = __builtin_amdgcn_mfma_f32_16x16x32_bf16(al[mt], bh[nt], acc[mt][nt], 0, 0, 0);
            }
    }

    // C/D layout: col = lane&15, row = (lane>>4)*4 + reg
    #pragma unroll
    for (int mt = 0; mt < 4; ++mt)
        #pragma unroll
        for (int j = 0; j < 4; ++j) {
            const int r = bm + wr + mt*16 + fg*4 + j;
            float* dst = z_pre + (size_t)r * NLAT + bn + wc;
            #pragma unroll
            for (int nt = 0; nt < 4; ++nt)
                dst[nt*16 + fr] = acc[mt][nt][j];
        }
}

// ---------------------------------------------------------------------------
// Fallback GEMM with in-kernel split (r5-verified) for small ws.
// ---------------------------------------------------------------------------
__global__ __launch_bounds__(256) void enc_gemm_mfma(const float* __restrict__ x,
                                                     const float* __restrict__ W,
                                                     const float* __restrict__ bpre,
                                                     float* __restrict__ z_pre)
{
    __shared__ unsigned short Ah[GBM][LROW], Al[GBM][LROW];
    __shared__ unsigned short Bh[GBN][LROW], Bl[GBN][LROW];

    const int tid = threadIdx.x;
    const int bm = blockIdx.y * GBM;
    const int bn = blockIdx.x * GBN;
    const int lane = tid & 63;
    const int wv = tid >> 6;
    const int wr = (wv >> 1) * 64;
    const int wc = (wv & 1) * 64;
    const int fr = lane & 15;
    const int fg = lane >> 4;

    const int srow = tid >> 3;
    const int sk   = (tid & 7) * 4;

    f32x4 acc[4][4];
    #pragma unroll
    for (int i = 0; i < 4; ++i)
        #pragma unroll
        for (int j = 0; j < 4; ++j)
            #pragma unroll
            for (int e = 0; e < 4; ++e) acc[i][j][e] = 0.0f;

    for (int k0 = 0; k0 < D_IN; k0 += GBK) {
        float4 xa[4], wb[4];
        const float4 bp = *(const float4*)(bpre + k0 + sk);
        #pragma unroll
        for (int p = 0; p < 4; ++p) {
            xa[p] = *(const float4*)(x + (size_t)(bm + srow + 32*p) * D_IN + k0 + sk);
            wb[p] = *(const float4*)(W + (size_t)(bn + srow + 32*p) * D_IN + k0 + sk);
        }
        __syncthreads();
        #pragma unroll
        for (int p = 0; p < 4; ++p) {
            const float a0 = xa[p].x - bp.x, a1 = xa[p].y - bp.y,
                        a2 = xa[p].z - bp.z, a3 = xa[p].w - bp.w;
            const unsigned short h0 = bf16hi(a0), h1 = bf16hi(a1),
                                 h2 = bf16hi(a2), h3 = bf16hi(a3);
            *(ushort4*)&Ah[srow + 32*p][sk] = make_ushort4(h0, h1, h2, h3);
            *(ushort4*)&Al[srow + 32*p][sk] = make_ushort4(
                bf16hi(a0 - bf2f(h0)), bf16hi(a1 - bf2f(h1)),
                bf16hi(a2 - bf2f(h2)), bf16hi(a3 - bf2f(h3)));
            const float b0 = wb[p].x, b1 = wb[p].y, b2 = wb[p].z, b3 = wb[p].w;
            const unsigned short g0 = bf16hi(b0), g1 = bf16hi(b1),
                                 g2 = bf16hi(b2), g3 = bf16hi(b3);
            *(ushort4*)&Bh[srow + 32*p][sk] = make_ushort4(g0, g1, g2, g3);
            *(ushort4*)&Bl[srow + 32*p][sk] = make_ushort4(
                bf16hi(b0 - bf2f(g0)), bf16hi(b1 - bf2f(g1)),
                bf16hi(b2 - bf2f(g2)), bf16hi(b3 - bf2f(g3)));
        }
        __syncthreads();

        short8 ah[4], al[4], bh[4], bl[4];
        #pragma unroll
        for (int t = 0; t < 4; ++t) {
            ah[t] = *(const short8*)&Ah[wr + t*16 + fr][fg * 8];
            al[t] = *(const short8*)&Al[wr + t*16 + fr][fg * 8];
            bh[t] = *(const short8*)&Bh[wc + t*16 + fr][fg * 8];
            bl[t] = *(const short8*)&Bl[wc + t*16 + fr][fg * 8];
        }
        #pragma unroll
        for (int mt = 0; mt < 4; ++mt)
            #pragma unroll
            for (int nt = 0; nt < 4; ++nt) {
                acc[mt][nt] = __builtin_amdgcn_mfma_f32_16x16x32_bf16(ah[mt], bh[nt], acc[mt][nt], 0, 0, 0);
                acc[mt][nt] = __builtin_amdgcn_mfma_f32_16x16x32_bf16(ah[mt], bl[nt], acc[mt][nt], 0, 0, 0);
                acc[mt][nt] = __builtin_amdgcn_mfma_f32_16x16x32_bf16(al[mt], bh[nt], acc[mt][nt], 0, 0, 0);
            }
    }

    #pragma unroll
    for (int mt = 0; mt < 4; ++mt)
        #pragma unroll
        for (int j = 0; j < 4; ++j) {
            const int r = bm + wr + mt*16 + fg*4 + j;
            float* dst = z_pre + (size_t)r * NLAT + bn + wc;
            #pragma unroll
            for (int nt = 0; nt < 4; ++nt)
                dst[nt*16 + fr] = acc[mt][nt][j];
        }
}

// ---------------------------------------------------------------------------
// Fused filter + top-k + z-write (r5-verified, unchanged).
// ---------------------------------------------------------------------------
__global__ __launch_bounds__(256) void topk_fused(const float* __restrict__ z_pre,
                                                  float* __restrict__ z,
                                                  const float* __restrict__ x,
                                                  const float* __restrict__ W_enc,
                                                  const float* __restrict__ bpre,
                                                  int* __restrict__ idx_ws,
                                                  float* __restrict__ val_ws,
                                                  int* __restrict__ flag_ws)
{
    __shared__ float cv[CAND_MAX];
    __shared__ int   ci[CAND_MAX];
    __shared__ unsigned char keep[CAND_MAX];
    __shared__ unsigned hist[256];
    __shared__ int cnt_sh, b_sh;
    __shared__ int nsure_sh, namb_sh, nk_sh;
    __shared__ int amb[MAXAMB];
    __shared__ double ambv[MAXAMB];
    __shared__ int   t_idx[K_TOP + 8];
    __shared__ float t_val[K_TOP + 8];
    __shared__ int   kidx[K_TOP];
    __shared__ float kval[K_TOP];
    __shared__ unsigned bitmap[NLAT / 32];

    const int r = blockIdx.x;
    const int tid = threadIdx.x;

    if (tid == 0) { cnt_sh = 0; nsure_sh = 0; namb_sh = 0; nk_sh = 0; }
    if (tid < 256) hist[tid] = 0u;
    __syncthreads();

    const float4* src = (const float4*)(z_pre + (size_t)r * NLAT);
    #pragma unroll
    for (int u = 0; u < NLAT / 4 / 256; ++u) {
        const int f4 = u * 256 + tid;
        const float4 v4 = src[f4];
        #pragma unroll
        for (int b = 0; b < 4; ++b) {
            const float vv = ((const float*)&v4)[b];
            if (vv > THRESH) {
                const int p = atomicAdd(&cnt_sh, 1);
                if (p < CAND_MAX) { cv[p] = vv; ci[p] = f4 * 4 + b; }
            }
        }
    }
    __syncthreads();

    const int cnt = cnt_sh;
    if (cnt < K_TOP || cnt > CAND_MAX) { if (tid == 0) flag_ws[r] = 1; return; }
    if (tid == 0) flag_ws[r] = 0;

    for (int q = tid; q < cnt; q += 256) {
        int b = (int)(__float_as_uint(cv[q]) >> 16) - 16288;
        b = b < 0 ? 0 : (b > 255 ? 255 : b);
        atomicAdd(&hist[b], 1u);
    }
    __syncthreads();
    if (tid == 0) {
        int acc = 0, b = 255;
        for (; b >= 0; --b) {
            const int nb = acc + (int)hist[b];
            if (nb >= K_TOP) break;
            acc = nb;
        }
        b_sh = b;
    }
    __syncthreads();

    const int bstar = b_sh;
    const float hi = binedge(bstar + 1) + DELTA;
    const float lo = binedge(bstar) - DELTA;
    if (bstar >= 255 || bstar < 0 || lo <= THRESH + 1e-3f) {
        if (tid == 0) flag_ws[r] = 1;
        return;
    }

    for (int t = tid; t < cnt; t += 256) {
        const float vt = cv[t];
        if (vt > hi) { keep[t] = 1; atomicAdd(&nsure_sh, 1); }
        else if (vt >= lo) {
            const int p = atomicAdd(&namb_sh, 1);
            if (p < MAXAMB) amb[p] = t;
            keep[t] = 0;
        } else keep[t] = 0;
    }
    __syncthreads();

    const int nsure = nsure_sh;
    const int namb = namb_sh;
    if (namb > MAXAMB || nsure >= K_TOP) { if (tid == 0) flag_ws[r] = 1; return; }
    const int nkeep_amb = K_TOP - nsure;

    const int lane = tid & 63, w = tid >> 6;
    for (int q = w; q < namb; q += 4) {
        const int j = ci[amb[q]];
        const float* wrow = W_enc + (size_t)j * D_IN;
        const float* xrow = x + (size_t)r * D_IN;
        double a = 0.0;
        for (int k = lane; k < D_IN; k += 64)
            a = fma((double)xrow[k] - (double)bpre[k], (double)wrow[k], a);
        #pragma unroll
        for (int off = 32; off; off >>= 1) a += __shfl_down(a, off, 64);
        if (lane == 0) ambv[q] = a;
    }
    __syncthreads();

    for (int t = tid; t < namb; t += 256) {
        const double dv = ambv[t];
        const int it = ci[amb[t]];
        int rk = 0;
        for (int q = 0; q < namb; ++q)
            rk += (ambv[q] > dv) || (ambv[q] == dv && ci[amb[q]] < it);
        if (rk < nkeep_amb) keep[amb[t]] = 1;
    }
    __syncthreads();

    for (int t = tid; t < cnt; t += 256) {
        if (keep[t]) {
            const int p = atomicAdd(&nk_sh, 1);
            if (p < K_TOP + 8) { t_idx[p] = ci[t]; t_val[p] = cv[t]; }
        }
    }
    __syncthreads();
    if (nk_sh != K_TOP) { if (tid == 0) flag_ws[r] = 1; return; }

    if (tid < K_TOP) {
        const int it = t_idx[tid];
        int pos = 0;
        #pragma unroll 8
        for (int s = 0; s < K_TOP; ++s) pos += (t_idx[s] < it);
        kidx[pos] = it; kval[pos] = t_val[tid];
        idx_ws[r * K_TOP + pos] = it;
        val_ws[r * K_TOP + pos] = t_val[tid];
    }
    for (int i = tid; i < NLAT / 32; i += 256) bitmap[i] = 0u;
    __syncthreads();
    if (tid < K_TOP) atomicOr(&bitmap[kidx[tid] >> 5], 1u << (kidx[tid] & 31));
    __syncthreads();

    float* zrow = z + (size_t)r * NLAT;
    #pragma unroll
    for (int u = 0; u < NLAT / 4 / 256; ++u) {
        const int f4 = u * 256 + tid;
        const unsigned nib = (bitmap[f4 >> 3] >> ((f4 & 7) * 4)) & 0xFu;
        float4 o = make_float4(0.f, 0.f, 0.f, 0.f);
        if (nib) {
            const int base = f4 * 4;
            #pragma unroll
            for (int b = 0; b < 4; ++b) if ((nib >> b) & 1u) {
                const int target = base + b;
                float vv = 0.f;
                for (int s = 0; s < K_TOP; ++s) if (kidx[s] == target) { vv = kval[s]; break; }
                ((float*)&o)[b] = vv;
            }
        }
        ((float4*)zrow)[f4] = o;
    }
}

// ---------------------------------------------------------------------------
// Fallback full-row top-k (r3-verified, unchanged).
// ---------------------------------------------------------------------------
__global__ __launch_bounds__(1024) void topk_fallback(const float* __restrict__ z_pre,
                                                      float* __restrict__ z,
                                                      const float* __restrict__ x,
                                                      const float* __restrict__ W_enc,
                                                      const float* __restrict__ bpre,
                                                      int* __restrict__ idx_ws,
                                                      float* __restrict__ val_ws,
                                                      const int* __restrict__ flag_ws)
{
    if (flag_ws != nullptr && flag_ws[blockIdx.x] == 0) return;

    __shared__ unsigned hist_w[16][257];
    __shared__ unsigned hist[256];
    __shared__ unsigned sh_prefix;
    __shared__ int sh_rem;
    __shared__ int cntA;
    __shared__ int nsure_sh;
    __shared__ int idxA[MAXA];
    __shared__ double dvalA[MAXA];
    __shared__ unsigned char keepA[MAXA];
    __shared__ int wcnt[16][24];

    const int r = blockIdx.x;
    const int tid = threadIdx.x;
    const int lane = tid & 63;
    const int w = tid >> 6;
    const unsigned long long lt = (1ull << lane) - 1ull;

    const float* src = z_pre + (size_t)r * NLAT;
    float v[24];
    #pragma unroll
    for (int c = 0; c < 24; ++c) v[c] = src[c*1024 + tid];

    if (tid == 0) { sh_prefix = 0u; sh_rem = K_TOP; cntA = 0; nsure_sh = 0; }
    if (idx_ws != nullptr && tid < K_TOP) {
        idx_ws[r*K_TOP + tid] = 0; val_ws[r*K_TOP + tid] = 0.0f;
    }

    for (int lvl = 0; lvl < 4; ++lvl) {
        const int shift = 24 - 8*lvl;
        for (int i = tid; i < 16*257; i += 1024) ((unsigned*)hist_w)[i] = 0u;
        __syncthreads();
        const unsigned pfx = sh_prefix;
        #pragma unroll
        for (int c = 0; c < 24; ++c) {
            const unsigned key = f2key(v[c]);
            const bool match = (lvl == 0) || ((key >> (shift + 8)) == (pfx >> (shift + 8)));
            if (match) atomicAdd(&hist_w[w][(key >> shift) & 255u], 1u);
        }
        __syncthreads();
        if (tid < 256) {
            unsigned s = 0;
            #pragma unroll
            for (int q = 0; q < 16; ++q) s += hist_w[q][tid];
            hist[tid] = s;
        }
        __syncthreads();
        if (tid == 0) {
            int rem = sh_rem, acc = 0, b = 255;
            for (; b >= 0; --b) {
                const int nb = acc + (int)hist[b];
                if (nb >= rem) { sh_rem = rem - acc; break; }
                acc = nb;
            }
            sh_prefix = pfx | ((unsigned)b << shift);
        }
        __syncthreads();
    }

    const float vT = key2f(sh_prefix);
    const float thr_lo = vT - DELTA, thr_hi = vT + DELTA;

    int wsure = 0;
    #pragma unroll
    for (int c = 0; c < 24; ++c) {
        const float val = v[c];
        const unsigned long long m = __ballot(val > thr_hi);
        if (lane == 0) wsure += (int)__popcll(m);
        if (val <= thr_hi && val >= thr_lo) {
            const int p = atomicAdd(&cntA, 1);
            if (p < MAXA) idxA[p] = c*1024 + tid;
        }
    }
    if (lane == 0 && wsure) atomicAdd(&nsure_sh, (unsigned)wsure);
    __syncthreads();

    const int nA = cntA < MAXA ? cntA : MAXA;
    const int nkeepA = K_TOP - nsure_sh;

    for (int q = w; q < nA; q += 16) {
        const int j = idxA[q];
        const float* wrow = W_enc + (size_t)j * D_IN;
        const float* xrow = x + (size_t)r * D_IN;
        double a = 0.0;
        for (int k = lane; k < D_IN; k += 64)
            a = fma((double)xrow[k] - (double)bpre[k], (double)wrow[k], a);
        #pragma unroll
        for (int off = 32; off; off >>= 1) a += __shfl_down(a, off, 64);
        if (lane == 0) dvalA[q] = a;
    }
    __syncthreads();

    for (int t = tid; t < nA; t += 1024) {
        const double dv = dvalA[t];
        const int ix = idxA[t];
        int rank = 0;
        for (int q = 0; q < nA; ++q)
            rank += (dvalA[q] > dv) || (dvalA[q] == dv && idxA[q] < ix);
        keepA[t] = (rank < nkeepA) ? 1 : 0;
    }
    __syncthreads();

    bool kp[24];
    #pragma unroll
    for (int c = 0; c < 24; ++c) {
        const float val = v[c];
        bool k = (val > thr_hi);
        if (!k && val >= thr_lo) {
            const int i = c*1024 + tid;
            for (int q = 0; q < nA; ++q)
                if (idxA[q] == i) { k = (keepA[q] != 0); break; }
        }
        kp[c] = k;
        const unsigned long long m = __ballot(k);
        if (lane == 0) wcnt[w][c] = (int)__popcll(m);
    }
    __syncthreads();
    if (tid == 0) {
        int run = 0;
        for (int c = 0; c < 24; ++c)
            #pragma unroll
            for (int q = 0; q < 16; ++q) { const int t = wcnt[q][c]; wcnt[q][c] = run; run += t; }
    }
    __syncthreads();

    float* zdst = z + (size_t)r * NLAT;
    #pragma unroll
    for (int c = 0; c < 24; ++c) {
        const unsigned long long m = __ballot(kp[c]);
        const int pos = wcnt[w][c] + (int)__popcll(m & lt);
        const int i = c*1024 + tid;
        zdst[i] = kp[c] ? v[c] : 0.0f;
        if (kp[c] && idx_ws != nullptr && pos < K_TOP) {
            idx_ws[r*K_TOP + pos] = i;
            val_ws[r*K_TOP + pos] = v[c];
        }
    }
}

// ---------------------------------------------------------------------------
__global__ __launch_bounds__(256) void dec_kernel(const int* __restrict__ idx_ws,
                                                  const float* __restrict__ val_ws,
                                                  const float* __restrict__ W_dec,
                                                  const float* __restrict__ bpre,
                                                  const float* __restrict__ x,
                                                  float* __restrict__ x_hat,
                                                  float* __restrict__ recon)
{
    __shared__ int sidx[K_TOP];
    __shared__ float sval[K_TOP];
    const int r = blockIdx.x;
    const int tid = threadIdx.x;
    if (tid < K_TOP) {
        sidx[tid] = idx_ws[r*K_TOP + tid];
        sval[tid] = val_ws[r*K_TOP + tid];
    }
    __syncthreads();

    float a0 = bpre[tid], a1 = bpre[tid + 256], a2 = bpre[tid + 512];
    #pragma unroll 4
    for (int j = 0; j < K_TOP; ++j) {
        const float vv = sval[j];
        const float* wr_ = W_dec + (size_t)sidx[j] * D_IN;
        a0 = fmaf(vv, wr_[tid],       a0);
        a1 = fmaf(vv, wr_[tid + 256], a1);
        a2 = fmaf(vv, wr_[tid + 512], a2);
    }
    const size_t o = (size_t)r * D_IN + tid;
    x_hat[o]       = a0;
    x_hat[o + 256] = a1;
    x_hat[o + 512] = a2;
    recon[o]       = x[o]       - a0;
    recon[o + 256] = x[o + 256] - a1;
    recon[o + 512] = x[o + 512] - a2;
}

__global__ __launch_bounds__(256) void dec_scan_kernel(const float* __restrict__ z,
                                                       const float* __restrict__ W_dec,
                                                       const float* __restrict__ bpre,
                                                       const float* __restrict__ x,
                                                       float* __restrict__ x_hat,
                                                       float* __restrict__ recon)
{
    __shared__ int sidx[K_TOP];
    __shared__ float sval[K_TOP];
    __shared__ int wcnt[4];
    __shared__ int base;
    const int r = blockIdx.x;
    const int tid = threadIdx.x;
    const int lane = tid & 63, w = tid >> 6;
    if (tid == 0) base = 0;
    __syncthreads();
    const float* zrow = z + (size_t)r * NLAT;
    for (int c = 0; c < NLAT; c += 256) {
        const float vv = zrow[c + tid];
        const bool nz = (vv != 0.0f);
        const unsigned long long m = __ballot(nz);
        if (lane == 0) wcnt[w] = __popcll(m);
        __syncthreads();
        int b = base;
        for (int j = 0; j < w; ++j) b += wcnt[j];
        const int pos = b + __popcll(m & ((1ull << lane) - 1ull));
        if (nz && pos < K_TOP) { sidx[pos] = c + tid; sval[pos] = vv; }
        __syncthreads();
        if (tid == 0) { int s = 0; for (int j = 0; j < 4; ++j) s += wcnt[j]; base += s; }
        __syncthreads();
    }
    const int n = base > K_TOP ? K_TOP : base;

    float a0 = bpre[tid], a1 = bpre[tid + 256], a2 = bpre[tid + 512];
    for (int j = 0; j < n; ++j) {
        const float vv = sval[j];
        const float* wr_ = W_dec + (size_t)sidx[j] * D_IN;
        a0 = fmaf(vv, wr_[tid],       a0);
        a1 = fmaf(vv, wr_[tid + 256], a1);
        a2 = fmaf(vv, wr_[tid + 512], a2);
    }
    const size_t o = (size_t)r * D_IN + tid;
    x_hat[o]       = a0;
    x_hat[o + 256] = a1;
    x_hat[o + 512] = a2;
    recon[o]       = x[o]       - a0;
    recon[o + 256] = x[o + 256] - a1;
    recon[o + 512] = x[o + 512] - a2;
}

// ---------------------------------------------------------------------------
extern "C" void kernel_launch(void* const* d_in, const int* in_sizes, int n_in,
                              void* d_out, int out_size, void* d_ws, size_t ws_size,
                              hipStream_t stream)
{
    const float* x     = (const float*)d_in[0];
    const float* W_enc = (const float*)d_in[1];
    const float* W_dec = (const float*)d_in[2];
    const float* bpre  = (const float*)d_in[3];

    float* out   = (float*)d_out;
    float* x_hat = out;
    float* z     = x_hat + (size_t)BATCH * D_IN;
    float* z_pre = z     + (size_t)BATCH * NLAT;
    float* recon = z_pre + (size_t)BATCH * NLAT;

    // ws layout: flag | idx_ws | val_ws | xh | xl | wh | wl
    char* p = (char*)d_ws;
    int*   flag_ws = (int*)p;                        p += (size_t)BATCH * 4;
    int*   idx_ws  = (int*)p;                        p += (size_t)BATCH * K_TOP * 4;
    float* val_ws  = (float*)p;                      p += (size_t)BATCH * K_TOP * 4;
    const size_t ws_small = (size_t)(p - (char*)d_ws);
    unsigned short* xh = (unsigned short*)p;         p += (size_t)BATCH * D_IN * 2;
    unsigned short* xl = (unsigned short*)p;         p += (size_t)BATCH * D_IN * 2;
    unsigned short* wh = (unsigned short*)p;         p += (size_t)NLAT * D_IN * 2;
    unsigned short* wl = (unsigned short*)p;         p += (size_t)NLAT * D_IN * 2;
    const size_t ws_full = (size_t)(p - (char*)d_ws);

    const bool have_ws   = (d_ws != nullptr) && (ws_size >= ws_small);
    const bool have_full = (d_ws != nullptr) && (ws_size >= ws_full);

    if (have_full) {
        split_x_kernel<<<(BATCH * D_IN / 4) / 256, 256, 0, stream>>>(
            (const float4*)x, bpre, (ushort4*)xh, (ushort4*)xl);
        split_w_kernel<<<(NLAT * D_IN / 4) / 256, 256, 0, stream>>>(
            (const float4*)W_enc, (ushort4*)wh, (ushort4*)wl);
        enc_gemm_pre<<<NWG, 256, 0, stream>>>(xh, xl, wh, wl, z_pre);
    } else {
        dim3 g1(NLAT / GBN, BATCH / GBM);
        enc_gemm_mfma<<<g1, 256, 0, stream>>>(x, W_enc, bpre, z_pre);
    }

    if (have_ws) {
        topk_fused<<<BATCH, 256, 0, stream>>>(z_pre, z, x, W_enc, bpre,
                                              idx_ws, val_ws, flag_ws);
        topk_fallback<<<BATCH, 1024, 0, stream>>>(z_pre, z, x, W_enc, bpre, idx_ws, val_ws, flag_ws);
        dec_kernel<<<BATCH, 256, 0, stream>>>(idx_ws, val_ws, W_dec, bpre, x, x_hat, recon);
    } else {
        topk_fallback<<<BATCH, 1024, 0, stream>>>(z_pre, z, x, W_enc, bpre, nullptr, nullptr, nullptr);
        dec_scan_kernel<<<BATCH, 256, 0, stream>>>(z, W_dec, bpre, x, x_hat, recon);
    }
}

// Round 7
// 1008.917 us; speedup vs baseline: 4.9540x; 1.0715x over previous
//
#include <hip/hip_runtime.h>

#define D_IN   768
#define NLAT   24576
#define BATCH  4096
#define K_TOP  64
#define MAXA   1024
#define DELTA  0.06f
#define THRESH 1.30f
#define CAND_MAX 512
#define MAXAMB 128

typedef float f32x4 __attribute__((ext_vector_type(4)));
typedef short short8 __attribute__((ext_vector_type(8)));

// ---------------------------------------------------------------------------
__device__ __forceinline__ unsigned f2key(float f) {
    unsigned u = __float_as_uint(f);
    return (u & 0x80000000u) ? ~u : (u | 0x80000000u);
}
__device__ __forceinline__ float key2f(unsigned k) {
    unsigned u = (k & 0x80000000u) ? (k & 0x7fffffffu) : ~k;
    return __uint_as_float(u);
}
__device__ __forceinline__ unsigned short bf16hi(float f) {   // RNE f32->bf16
    unsigned u = __float_as_uint(f);
    unsigned r = u + 0x7fffu + ((u >> 16) & 1u);
    return (unsigned short)(r >> 16);
}
__device__ __forceinline__ float bf2f(unsigned short h) {
    return __uint_as_float(((unsigned)h) << 16);
}
__device__ __forceinline__ float binedge(int b) {
    return __uint_as_float((unsigned)(16288 + b) << 16);   // bin 0 edge = 1.25f
}

// ---------------------------------------------------------------------------
// One-time bf16 convert passes (hi only).
// ---------------------------------------------------------------------------
__global__ __launch_bounds__(256) void conv_x_kernel(const float4* __restrict__ src,
                                                     const float* __restrict__ bpre,
                                                     ushort4* __restrict__ hi)
{
    const int f = blockIdx.x * 256 + threadIdx.x;   // < BATCH*D_IN/4
    float4 v = src[f];
    const float4 bp = ((const float4*)bpre)[f % (D_IN / 4)];
    ushort4 h;
    h.x = bf16hi(v.x - bp.x);
    h.y = bf16hi(v.y - bp.y);
    h.z = bf16hi(v.z - bp.z);
    h.w = bf16hi(v.w - bp.w);
    hi[f] = h;
}

__global__ __launch_bounds__(256) void conv_w_kernel(const float4* __restrict__ src,
                                                     ushort4* __restrict__ hi)
{
    const int f = blockIdx.x * 256 + threadIdx.x;   // < NLAT*D_IN/4
    const float4 v = src[f];
    ushort4 h;
    h.x = bf16hi(v.x); h.y = bf16hi(v.y); h.z = bf16hi(v.z); h.w = bf16hi(v.w);
    hi[f] = h;
}

// ---------------------------------------------------------------------------
// Single-bf16 encoder GEMM.  Tile 128x128, BK=64, 4 waves (2x2), each 64x64
// via 4x4 16x16x32 frags, 1 MFMA per fragment pair.  z_pre error ~4.5e-3 rms,
// absorbed by the DELTA=0.06 exact-f64 refinement window in top-k.
// XCD-bijective block swizzle (6144 % 8 == 0).
// ---------------------------------------------------------------------------
#define GBM 128
#define GBN 128
#define GBK 64
#define LROW (GBK + 8)   // 72 shorts = 144 B row stride -> ~2-way LDS aliasing
#define NWG  ((NLAT / GBN) * (BATCH / GBM))   // 6144

__global__ __launch_bounds__(256) void enc_gemm_bf16(const unsigned short* __restrict__ xh,
                                                     const unsigned short* __restrict__ wh,
                                                     float* __restrict__ z_pre)
{
    __shared__ unsigned short Ah[GBM][LROW];
    __shared__ unsigned short Bh[GBN][LROW];

    const int tid = threadIdx.x;
    const int bid = blockIdx.x;
    const int swz = (bid & 7) * (NWG / 8) + (bid >> 3);
    const int bn = (swz % (NLAT / GBN)) * GBN;
    const int bm = (swz / (NLAT / GBN)) * GBM;

    const int lane = tid & 63;
    const int wv = tid >> 6;
    const int wr = (wv >> 1) * 64;
    const int wc = (wv & 1) * 64;
    const int fr = lane & 15;
    const int fg = lane >> 4;

    // staging: per array 128 rows x 64 shorts = 1024 16B-chunks; 4 per thread
    int srow[4], sko[4];
    const unsigned short* pxa[4];
    const unsigned short* pwb[4];
    #pragma unroll
    for (int q = 0; q < 4; ++q) {
        const int c = q * 256 + tid;
        srow[q] = c >> 3;
        sko[q]  = (c & 7) * 8;
        pxa[q] = xh + (size_t)(bm + srow[q]) * D_IN + sko[q];
        pwb[q] = wh + (size_t)(bn + srow[q]) * D_IN + sko[q];
    }

    f32x4 acc[4][4];
    #pragma unroll
    for (int i = 0; i < 4; ++i)
        #pragma unroll
        for (int j = 0; j < 4; ++j)
            #pragma unroll
            for (int e = 0; e < 4; ++e) acc[i][j][e] = 0.0f;

    for (int k0 = 0; k0 < D_IN; k0 += GBK) {
        short8 va[4], vb[4];
        #pragma unroll
        for (int q = 0; q < 4; ++q) {
            va[q] = *(const short8*)(pxa[q] + k0);
            vb[q] = *(const short8*)(pwb[q] + k0);
        }

        __syncthreads();   // previous tile's LDS reads done

        #pragma unroll
        for (int q = 0; q < 4; ++q) {
            *(short8*)&Ah[srow[q]][sko[q]] = va[q];
            *(short8*)&Bh[srow[q]][sko[q]] = vb[q];
        }

        __syncthreads();

        #pragma unroll
        for (int ks = 0; ks < 2; ++ks) {
            short8 ah[4], bh[4];
            #pragma unroll
            for (int t = 0; t < 4; ++t) {
                ah[t] = *(const short8*)&Ah[wr + t*16 + fr][ks*32 + fg*8];
                bh[t] = *(const short8*)&Bh[wc + t*16 + fr][ks*32 + fg*8];
            }
            #pragma unroll
            for (int mt = 0; mt < 4; ++mt)
                #pragma unroll
                for (int nt = 0; nt < 4; ++nt)
                    acc[mt][nt] = __builtin_amdgcn_mfma_f32_16x16x32_bf16(ah[mt], bh[nt], acc[mt][nt], 0, 0, 0);
        }
    }

    // C/D layout: col = lane&15, row = (lane>>4)*4 + reg
    #pragma unroll
    for (int mt = 0; mt < 4; ++mt)
        #pragma unroll
        for (int j = 0; j < 4; ++j) {
            const int r = bm + wr + mt*16 + fg*4 + j;
            float* dst = z_pre + (size_t)r * NLAT + bn + wc;
            #pragma unroll
            for (int nt = 0; nt < 4; ++nt)
                dst[nt*16 + fr] = acc[mt][nt][j];
        }
}

// ---------------------------------------------------------------------------
// Fallback GEMM with in-kernel split-2 (r5-verified) for small ws.
// ---------------------------------------------------------------------------
#define FBK 32
#define FLROW (FBK + 8)

__global__ __launch_bounds__(256) void enc_gemm_mfma(const float* __restrict__ x,
                                                     const float* __restrict__ W,
                                                     const float* __restrict__ bpre,
                                                     float* __restrict__ z_pre)
{
    __shared__ unsigned short Ah[GBM][FLROW], Al[GBM][FLROW];
    __shared__ unsigned short Bh[GBN][FLROW], Bl[GBN][FLROW];

    const int tid = threadIdx.x;
    const int bm = blockIdx.y * GBM;
    const int bn = blockIdx.x * GBN;
    const int lane = tid & 63;
    const int wv = tid >> 6;
    const int wr = (wv >> 1) * 64;
    const int wc = (wv & 1) * 64;
    const int fr = lane & 15;
    const int fg = lane >> 4;

    const int srow = tid >> 3;
    const int sk   = (tid & 7) * 4;

    f32x4 acc[4][4];
    #pragma unroll
    for (int i = 0; i < 4; ++i)
        #pragma unroll
        for (int j = 0; j < 4; ++j)
            #pragma unroll
            for (int e = 0; e < 4; ++e) acc[i][j][e] = 0.0f;

    for (int k0 = 0; k0 < D_IN; k0 += FBK) {
        float4 xa[4], wb[4];
        const float4 bp = *(const float4*)(bpre + k0 + sk);
        #pragma unroll
        for (int p = 0; p < 4; ++p) {
            xa[p] = *(const float4*)(x + (size_t)(bm + srow + 32*p) * D_IN + k0 + sk);
            wb[p] = *(const float4*)(W + (size_t)(bn + srow + 32*p) * D_IN + k0 + sk);
        }
        __syncthreads();
        #pragma unroll
        for (int p = 0; p < 4; ++p) {
            const float a0 = xa[p].x - bp.x, a1 = xa[p].y - bp.y,
                        a2 = xa[p].z - bp.z, a3 = xa[p].w - bp.w;
            const unsigned short h0 = bf16hi(a0), h1 = bf16hi(a1),
                                 h2 = bf16hi(a2), h3 = bf16hi(a3);
            *(ushort4*)&Ah[srow + 32*p][sk] = make_ushort4(h0, h1, h2, h3);
            *(ushort4*)&Al[srow + 32*p][sk] = make_ushort4(
                bf16hi(a0 - bf2f(h0)), bf16hi(a1 - bf2f(h1)),
                bf16hi(a2 - bf2f(h2)), bf16hi(a3 - bf2f(h3)));
            const float b0 = wb[p].x, b1 = wb[p].y, b2 = wb[p].z, b3 = wb[p].w;
            const unsigned short g0 = bf16hi(b0), g1 = bf16hi(b1),
                                 g2 = bf16hi(b2), g3 = bf16hi(b3);
            *(ushort4*)&Bh[srow + 32*p][sk] = make_ushort4(g0, g1, g2, g3);
            *(ushort4*)&Bl[srow + 32*p][sk] = make_ushort4(
                bf16hi(b0 - bf2f(g0)), bf16hi(b1 - bf2f(g1)),
                bf16hi(b2 - bf2f(g2)), bf16hi(b3 - bf2f(g3)));
        }
        __syncthreads();

        short8 ah[4], al[4], bh[4], bl[4];
        #pragma unroll
        for (int t = 0; t < 4; ++t) {
            ah[t] = *(const short8*)&Ah[wr + t*16 + fr][fg * 8];
            al[t] = *(const short8*)&Al[wr + t*16 + fr][fg * 8];
            bh[t] = *(const short8*)&Bh[wc + t*16 + fr][fg * 8];
            bl[t] = *(const short8*)&Bl[wc + t*16 + fr][fg * 8];
        }
        #pragma unroll
        for (int mt = 0; mt < 4; ++mt)
            #pragma unroll
            for (int nt = 0; nt < 4; ++nt) {
                acc[mt][nt] = __builtin_amdgcn_mfma_f32_16x16x32_bf16(ah[mt], bh[nt], acc[mt][nt], 0, 0, 0);
                acc[mt][nt] = __builtin_amdgcn_mfma_f32_16x16x32_bf16(ah[mt], bl[nt], acc[mt][nt], 0, 0, 0);
                acc[mt][nt] = __builtin_amdgcn_mfma_f32_16x16x32_bf16(al[mt], bh[nt], acc[mt][nt], 0, 0, 0);
            }
    }

    #pragma unroll
    for (int mt = 0; mt < 4; ++mt)
        #pragma unroll
        for (int j = 0; j < 4; ++j) {
            const int r = bm + wr + mt*16 + fg*4 + j;
            float* dst = z_pre + (size_t)r * NLAT + bn + wc;
            #pragma unroll
            for (int nt = 0; nt < 4; ++nt)
                dst[nt*16 + fr] = acc[mt][nt][j];
        }
}

// ---------------------------------------------------------------------------
// Fused filter + top-k + z-write.  DELTA-window exact-f64 refinement makes the
// selection identical to the f64 reference despite approximate z_pre.
// ---------------------------------------------------------------------------
__global__ __launch_bounds__(256) void topk_fused(const float* __restrict__ z_pre,
                                                  float* __restrict__ z,
                                                  const float* __restrict__ x,
                                                  const float* __restrict__ W_enc,
                                                  const float* __restrict__ bpre,
                                                  int* __restrict__ idx_ws,
                                                  float* __restrict__ val_ws,
                                                  int* __restrict__ flag_ws)
{
    __shared__ float cv[CAND_MAX];
    __shared__ int   ci[CAND_MAX];
    __shared__ unsigned char keep[CAND_MAX];
    __shared__ unsigned hist[256];
    __shared__ int cnt_sh, b_sh;
    __shared__ int nsure_sh, namb_sh, nk_sh;
    __shared__ int amb[MAXAMB];
    __shared__ double ambv[MAXAMB];
    __shared__ int   t_idx[K_TOP + 8];
    __shared__ float t_val[K_TOP + 8];
    __shared__ int   kidx[K_TOP];
    __shared__ float kval[K_TOP];
    __shared__ unsigned bitmap[NLAT / 32];

    const int r = blockIdx.x;
    const int tid = threadIdx.x;

    if (tid == 0) { cnt_sh = 0; nsure_sh = 0; namb_sh = 0; nk_sh = 0; }
    if (tid < 256) hist[tid] = 0u;
    __syncthreads();

    const float4* src = (const float4*)(z_pre + (size_t)r * NLAT);
    #pragma unroll
    for (int u = 0; u < NLAT / 4 / 256; ++u) {
        const int f4 = u * 256 + tid;
        const float4 v4 = src[f4];
        #pragma unroll
        for (int b = 0; b < 4; ++b) {
            const float vv = ((const float*)&v4)[b];
            if (vv > THRESH) {
                const int p = atomicAdd(&cnt_sh, 1);
                if (p < CAND_MAX) { cv[p] = vv; ci[p] = f4 * 4 + b; }
            }
        }
    }
    __syncthreads();

    const int cnt = cnt_sh;
    if (cnt < K_TOP || cnt > CAND_MAX) { if (tid == 0) flag_ws[r] = 1; return; }
    if (tid == 0) flag_ws[r] = 0;

    for (int q = tid; q < cnt; q += 256) {
        int b = (int)(__float_as_uint(cv[q]) >> 16) - 16288;
        b = b < 0 ? 0 : (b > 255 ? 255 : b);
        atomicAdd(&hist[b], 1u);
    }
    __syncthreads();
    if (tid == 0) {
        int acc = 0, b = 255;
        for (; b >= 0; --b) {
            const int nb = acc + (int)hist[b];
            if (nb >= K_TOP) break;
            acc = nb;
        }
        b_sh = b;
    }
    __syncthreads();

    const int bstar = b_sh;
    const float hi = binedge(bstar + 1) + DELTA;
    const float lo = binedge(bstar) - DELTA;
    if (bstar >= 255 || bstar < 0 || lo <= THRESH + 1e-3f) {
        if (tid == 0) flag_ws[r] = 1;
        return;
    }

    for (int t = tid; t < cnt; t += 256) {
        const float vt = cv[t];
        if (vt > hi) { keep[t] = 1; atomicAdd(&nsure_sh, 1); }
        else if (vt >= lo) {
            const int p = atomicAdd(&namb_sh, 1);
            if (p < MAXAMB) amb[p] = t;
            keep[t] = 0;
        } else keep[t] = 0;
    }
    __syncthreads();

    const int nsure = nsure_sh;
    const int namb = namb_sh;
    if (namb > MAXAMB || nsure >= K_TOP) { if (tid == 0) flag_ws[r] = 1; return; }
    const int nkeep_amb = K_TOP - nsure;

    const int lane = tid & 63, w = tid >> 6;
    for (int q = w; q < namb; q += 4) {
        const int j = ci[amb[q]];
        const float* wrow = W_enc + (size_t)j * D_IN;
        const float* xrow = x + (size_t)r * D_IN;
        double a = 0.0;
        for (int k = lane; k < D_IN; k += 64)
            a = fma((double)xrow[k] - (double)bpre[k], (double)wrow[k], a);
        #pragma unroll
        for (int off = 32; off; off >>= 1) a += __shfl_down(a, off, 64);
        if (lane == 0) ambv[q] = a;
    }
    __syncthreads();

    for (int t = tid; t < namb; t += 256) {
        const double dv = ambv[t];
        const int it = ci[amb[t]];
        int rk = 0;
        for (int q = 0; q < namb; ++q)
            rk += (ambv[q] > dv) || (ambv[q] == dv && ci[amb[q]] < it);
        if (rk < nkeep_amb) keep[amb[t]] = 1;
    }
    __syncthreads();

    for (int t = tid; t < cnt; t += 256) {
        if (keep[t]) {
            const int p = atomicAdd(&nk_sh, 1);
            if (p < K_TOP + 8) { t_idx[p] = ci[t]; t_val[p] = cv[t]; }
        }
    }
    __syncthreads();
    if (nk_sh != K_TOP) { if (tid == 0) flag_ws[r] = 1; return; }

    if (tid < K_TOP) {
        const int it = t_idx[tid];
        int pos = 0;
        #pragma unroll 8
        for (int s = 0; s < K_TOP; ++s) pos += (t_idx[s] < it);
        kidx[pos] = it; kval[pos] = t_val[tid];
        idx_ws[r * K_TOP + pos] = it;
        val_ws[r * K_TOP + pos] = t_val[tid];
    }
    for (int i = tid; i < NLAT / 32; i += 256) bitmap[i] = 0u;
    __syncthreads();
    if (tid < K_TOP) atomicOr(&bitmap[kidx[tid] >> 5], 1u << (kidx[tid] & 31));
    __syncthreads();

    float* zrow = z + (size_t)r * NLAT;
    #pragma unroll
    for (int u = 0; u < NLAT / 4 / 256; ++u) {
        const int f4 = u * 256 + tid;
        const unsigned nib = (bitmap[f4 >> 3] >> ((f4 & 7) * 4)) & 0xFu;
        float4 o = make_float4(0.f, 0.f, 0.f, 0.f);
        if (nib) {
            const int base = f4 * 4;
            #pragma unroll
            for (int b = 0; b < 4; ++b) if ((nib >> b) & 1u) {
                const int target = base + b;
                float vv = 0.f;
                for (int s = 0; s < K_TOP; ++s) if (kidx[s] == target) { vv = kval[s]; break; }
                ((float*)&o)[b] = vv;
            }
        }
        ((float4*)zrow)[f4] = o;
    }
}

// ---------------------------------------------------------------------------
// Fallback full-row top-k (r3-verified).  Only flagged rows (or all if null).
// ---------------------------------------------------------------------------
__global__ __launch_bounds__(1024) void topk_fallback(const float* __restrict__ z_pre,
                                                      float* __restrict__ z,
                                                      const float* __restrict__ x,
                                                      const float* __restrict__ W_enc,
                                                      const float* __restrict__ bpre,
                                                      int* __restrict__ idx_ws,
                                                      float* __restrict__ val_ws,
                                                      const int* __restrict__ flag_ws)
{
    if (flag_ws != nullptr && flag_ws[blockIdx.x] == 0) return;

    __shared__ unsigned hist_w[16][257];
    __shared__ unsigned hist[256];
    __shared__ unsigned sh_prefix;
    __shared__ int sh_rem;
    __shared__ int cntA;
    __shared__ int nsure_sh;
    __shared__ int idxA[MAXA];
    __shared__ double dvalA[MAXA];
    __shared__ unsigned char keepA[MAXA];
    __shared__ int wcnt[16][24];

    const int r = blockIdx.x;
    const int tid = threadIdx.x;
    const int lane = tid & 63;
    const int w = tid >> 6;
    const unsigned long long lt = (1ull << lane) - 1ull;

    const float* src = z_pre + (size_t)r * NLAT;
    float v[24];
    #pragma unroll
    for (int c = 0; c < 24; ++c) v[c] = src[c*1024 + tid];

    if (tid == 0) { sh_prefix = 0u; sh_rem = K_TOP; cntA = 0; nsure_sh = 0; }
    if (idx_ws != nullptr && tid < K_TOP) {
        idx_ws[r*K_TOP + tid] = 0; val_ws[r*K_TOP + tid] = 0.0f;
    }

    for (int lvl = 0; lvl < 4; ++lvl) {
        const int shift = 24 - 8*lvl;
        for (int i = tid; i < 16*257; i += 1024) ((unsigned*)hist_w)[i] = 0u;
        __syncthreads();
        const unsigned pfx = sh_prefix;
        #pragma unroll
        for (int c = 0; c < 24; ++c) {
            const unsigned key = f2key(v[c]);
            const bool match = (lvl == 0) || ((key >> (shift + 8)) == (pfx >> (shift + 8)));
            if (match) atomicAdd(&hist_w[w][(key >> shift) & 255u], 1u);
        }
        __syncthreads();
        if (tid < 256) {
            unsigned s = 0;
            #pragma unroll
            for (int q = 0; q < 16; ++q) s += hist_w[q][tid];
            hist[tid] = s;
        }
        __syncthreads();
        if (tid == 0) {
            int rem = sh_rem, acc = 0, b = 255;
            for (; b >= 0; --b) {
                const int nb = acc + (int)hist[b];
                if (nb >= rem) { sh_rem = rem - acc; break; }
                acc = nb;
            }
            sh_prefix = pfx | ((unsigned)b << shift);
        }
        __syncthreads();
    }

    const float vT = key2f(sh_prefix);
    const float thr_lo = vT - DELTA, thr_hi = vT + DELTA;

    int wsure = 0;
    #pragma unroll
    for (int c = 0; c < 24; ++c) {
        const float val = v[c];
        const unsigned long long m = __ballot(val > thr_hi);
        if (lane == 0) wsure += (int)__popcll(m);
        if (val <= thr_hi && val >= thr_lo) {
            const int p = atomicAdd(&cntA, 1);
            if (p < MAXA) idxA[p] = c*1024 + tid;
        }
    }
    if (lane == 0 && wsure) atomicAdd(&nsure_sh, (unsigned)wsure);
    __syncthreads();

    const int nA = cntA < MAXA ? cntA : MAXA;
    const int nkeepA = K_TOP - nsure_sh;

    for (int q = w; q < nA; q += 16) {
        const int j = idxA[q];
        const float* wrow = W_enc + (size_t)j * D_IN;
        const float* xrow = x + (size_t)r * D_IN;
        double a = 0.0;
        for (int k = lane; k < D_IN; k += 64)
            a = fma((double)xrow[k] - (double)bpre[k], (double)wrow[k], a);
        #pragma unroll
        for (int off = 32; off; off >>= 1) a += __shfl_down(a, off, 64);
        if (lane == 0) dvalA[q] = a;
    }
    __syncthreads();

    for (int t = tid; t < nA; t += 1024) {
        const double dv = dvalA[t];
        const int ix = idxA[t];
        int rank = 0;
        for (int q = 0; q < nA; ++q)
            rank += (dvalA[q] > dv) || (dvalA[q] == dv && idxA[q] < ix);
        keepA[t] = (rank < nkeepA) ? 1 : 0;
    }
    __syncthreads();

    bool kp[24];
    #pragma unroll
    for (int c = 0; c < 24; ++c) {
        const float val = v[c];
        bool k = (val > thr_hi);
        if (!k && val >= thr_lo) {
            const int i = c*1024 + tid;
            for (int q = 0; q < nA; ++q)
                if (idxA[q] == i) { k = (keepA[q] != 0); break; }
        }
        kp[c] = k;
        const unsigned long long m = __ballot(k);
        if (lane == 0) wcnt[w][c] = (int)__popcll(m);
    }
    __syncthreads();
    if (tid == 0) {
        int run = 0;
        for (int c = 0; c < 24; ++c)
            #pragma unroll
            for (int q = 0; q < 16; ++q) { const int t = wcnt[q][c]; wcnt[q][c] = run; run += t; }
    }
    __syncthreads();

    float* zdst = z + (size_t)r * NLAT;
    #pragma unroll
    for (int c = 0; c < 24; ++c) {
        const unsigned long long m = __ballot(kp[c]);
        const int pos = wcnt[w][c] + (int)__popcll(m & lt);
        const int i = c*1024 + tid;
        zdst[i] = kp[c] ? v[c] : 0.0f;
        if (kp[c] && idx_ws != nullptr && pos < K_TOP) {
            idx_ws[r*K_TOP + pos] = i;
            val_ws[r*K_TOP + pos] = v[c];
        }
    }
}

// ---------------------------------------------------------------------------
__global__ __launch_bounds__(256) void dec_kernel(const int* __restrict__ idx_ws,
                                                  const float* __restrict__ val_ws,
                                                  const float* __restrict__ W_dec,
                                                  const float* __restrict__ bpre,
                                                  const float* __restrict__ x,
                                                  float* __restrict__ x_hat,
                                                  float* __restrict__ recon)
{
    __shared__ int sidx[K_TOP];
    __shared__ float sval[K_TOP];
    const int r = blockIdx.x;
    const int tid = threadIdx.x;
    if (tid < K_TOP) {
        sidx[tid] = idx_ws[r*K_TOP + tid];
        sval[tid] = val_ws[r*K_TOP + tid];
    }
    __syncthreads();

    float a0 = bpre[tid], a1 = bpre[tid + 256], a2 = bpre[tid + 512];
    #pragma unroll 4
    for (int j = 0; j < K_TOP; ++j) {
        const float vv = sval[j];
        const float* wr_ = W_dec + (size_t)sidx[j] * D_IN;
        a0 = fmaf(vv, wr_[tid],       a0);
        a1 = fmaf(vv, wr_[tid + 256], a1);
        a2 = fmaf(vv, wr_[tid + 512], a2);
    }
    const size_t o = (size_t)r * D_IN + tid;
    x_hat[o]       = a0;
    x_hat[o + 256] = a1;
    x_hat[o + 512] = a2;
    recon[o]       = x[o]       - a0;
    recon[o + 256] = x[o + 256] - a1;
    recon[o + 512] = x[o + 512] - a2;
}

__global__ __launch_bounds__(256) void dec_scan_kernel(const float* __restrict__ z,
                                                       const float* __restrict__ W_dec,
                                                       const float* __restrict__ bpre,
                                                       const float* __restrict__ x,
                                                       float* __restrict__ x_hat,
                                                       float* __restrict__ recon)
{
    __shared__ int sidx[K_TOP];
    __shared__ float sval[K_TOP];
    __shared__ int wcnt[4];
    __shared__ int base;
    const int r = blockIdx.x;
    const int tid = threadIdx.x;
    const int lane = tid & 63, w = tid >> 6;
    if (tid == 0) base = 0;
    __syncthreads();
    const float* zrow = z + (size_t)r * NLAT;
    for (int c = 0; c < NLAT; c += 256) {
        const float vv = zrow[c + tid];
        const bool nz = (vv != 0.0f);
        const unsigned long long m = __ballot(nz);
        if (lane == 0) wcnt[w] = __popcll(m);
        __syncthreads();
        int b = base;
        for (int j = 0; j < w; ++j) b += wcnt[j];
        const int pos = b + __popcll(m & ((1ull << lane) - 1ull));
        if (nz && pos < K_TOP) { sidx[pos] = c + tid; sval[pos] = vv; }
        __syncthreads();
        if (tid == 0) { int s = 0; for (int j = 0; j < 4; ++j) s += wcnt[j]; base += s; }
        __syncthreads();
    }
    const int n = base > K_TOP ? K_TOP : base;

    float a0 = bpre[tid], a1 = bpre[tid + 256], a2 = bpre[tid + 512];
    for (int j = 0; j < n; ++j) {
        const float vv = sval[j];
        const float* wr_ = W_dec + (size_t)sidx[j] * D_IN;
        a0 = fmaf(vv, wr_[tid],       a0);
        a1 = fmaf(vv, wr_[tid + 256], a1);
        a2 = fmaf(vv, wr_[tid + 512], a2);
    }
    const size_t o = (size_t)r * D_IN + tid;
    x_hat[o]       = a0;
    x_hat[o + 256] = a1;
    x_hat[o + 512] = a2;
    recon[o]       = x[o]       - a0;
    recon[o + 256] = x[o + 256] - a1;
    recon[o + 512] = x[o + 512] - a2;
}

// ---------------------------------------------------------------------------
extern "C" void kernel_launch(void* const* d_in, const int* in_sizes, int n_in,
                              void* d_out, int out_size, void* d_ws, size_t ws_size,
                              hipStream_t stream)
{
    const float* x     = (const float*)d_in[0];
    const float* W_enc = (const float*)d_in[1];
    const float* W_dec = (const float*)d_in[2];
    const float* bpre  = (const float*)d_in[3];

    float* out   = (float*)d_out;
    float* x_hat = out;
    float* z     = x_hat + (size_t)BATCH * D_IN;
    float* z_pre = z     + (size_t)BATCH * NLAT;
    float* recon = z_pre + (size_t)BATCH * NLAT;

    // ws layout: flag | idx_ws | val_ws | xh | wh
    char* p = (char*)d_ws;
    int*   flag_ws = (int*)p;                        p += (size_t)BATCH * 4;
    int*   idx_ws  = (int*)p;                        p += (size_t)BATCH * K_TOP * 4;
    float* val_ws  = (float*)p;                      p += (size_t)BATCH * K_TOP * 4;
    const size_t ws_small = (size_t)(p - (char*)d_ws);
    unsigned short* xh = (unsigned short*)p;         p += (size_t)BATCH * D_IN * 2;
    unsigned short* wh = (unsigned short*)p;         p += (size_t)NLAT * D_IN * 2;
    const size_t ws_full = (size_t)(p - (char*)d_ws);

    const bool have_ws   = (d_ws != nullptr) && (ws_size >= ws_small);
    const bool have_full = (d_ws != nullptr) && (ws_size >= ws_full);

    if (have_full) {
        conv_x_kernel<<<(BATCH * D_IN / 4) / 256, 256, 0, stream>>>(
            (const float4*)x, bpre, (ushort4*)xh);
        conv_w_kernel<<<(NLAT * D_IN / 4) / 256, 256, 0, stream>>>(
            (const float4*)W_enc, (ushort4*)wh);
        enc_gemm_bf16<<<NWG, 256, 0, stream>>>(xh, wh, z_pre);
    } else {
        dim3 g1(NLAT / GBN, BATCH / GBM);
        enc_gemm_mfma<<<g1, 256, 0, stream>>>(x, W_enc, bpre, z_pre);
    }

    if (have_ws) {
        topk_fused<<<BATCH, 256, 0, stream>>>(z_pre, z, x, W_enc, bpre,
                                              idx_ws, val_ws, flag_ws);
        topk_fallback<<<BATCH, 1024, 0, stream>>>(z_pre, z, x, W_enc, bpre, idx_ws, val_ws, flag_ws);
        dec_kernel<<<BATCH, 256, 0, stream>>>(idx_ws, val_ws, W_dec, bpre, x, x_hat, recon);
    } else {
        topk_fallback<<<BATCH, 1024, 0, stream>>>(z_pre, z, x, W_enc, bpre, nullptr, nullptr, nullptr);
        dec_scan_kernel<<<BATCH, 256, 0, stream>>>(z, W_dec, bpre, x, x_hat, recon);
    }
}

// Round 8
// 846.378 us; speedup vs baseline: 5.9053x; 1.1920x over previous
//
#include <hip/hip_runtime.h>

#define D_IN   768
#define NLAT   24576
#define BATCH  4096
#define K_TOP  64
#define MAXA   1024
#define DELTA  0.06f
#define THRESH 1.30f
#define CAND_MAX 512
#define MAXAMB 128

typedef float f32x4 __attribute__((ext_vector_type(4)));
typedef short short8 __attribute__((ext_vector_type(8)));

// ---------------------------------------------------------------------------
__device__ __forceinline__ unsigned f2key(float f) {
    unsigned u = __float_as_uint(f);
    return (u & 0x80000000u) ? ~u : (u | 0x80000000u);
}
__device__ __forceinline__ float key2f(unsigned k) {
    unsigned u = (k & 0x80000000u) ? (k & 0x7fffffffu) : ~k;
    return __uint_as_float(u);
}
__device__ __forceinline__ unsigned short bf16hi(float f) {   // RNE f32->bf16
    unsigned u = __float_as_uint(f);
    unsigned r = u + 0x7fffu + ((u >> 16) & 1u);
    return (unsigned short)(r >> 16);
}
__device__ __forceinline__ float bf2f(unsigned short h) {
    return __uint_as_float(((unsigned)h) << 16);
}
__device__ __forceinline__ float binedge(int b) {
    return __uint_as_float((unsigned)(16288 + b) << 16);   // bin 0 edge = 1.25f
}

// ---------------------------------------------------------------------------
// One-time bf16 convert passes (hi only).
// ---------------------------------------------------------------------------
__global__ __launch_bounds__(256) void conv_x_kernel(const float4* __restrict__ src,
                                                     const float* __restrict__ bpre,
                                                     ushort4* __restrict__ hi)
{
    const int f = blockIdx.x * 256 + threadIdx.x;
    float4 v = src[f];
    const float4 bp = ((const float4*)bpre)[f % (D_IN / 4)];
    ushort4 h;
    h.x = bf16hi(v.x - bp.x);
    h.y = bf16hi(v.y - bp.y);
    h.z = bf16hi(v.z - bp.z);
    h.w = bf16hi(v.w - bp.w);
    hi[f] = h;
}

__global__ __launch_bounds__(256) void conv_w_kernel(const float4* __restrict__ src,
                                                     ushort4* __restrict__ hi)
{
    const int f = blockIdx.x * 256 + threadIdx.x;
    const float4 v = src[f];
    ushort4 h;
    h.x = bf16hi(v.x); h.y = bf16hi(v.y); h.z = bf16hi(v.z); h.w = bf16hi(v.w);
    hi[f] = h;
}

// ---------------------------------------------------------------------------
// Single-bf16 encoder GEMM (r7-verified).  Tile 128x128, BK=64, XCD swizzle.
// ---------------------------------------------------------------------------
#define GBM 128
#define GBN 128
#define GBK 64
#define LROW (GBK + 8)
#define NWG  ((NLAT / GBN) * (BATCH / GBM))   // 6144

__global__ __launch_bounds__(256) void enc_gemm_bf16(const unsigned short* __restrict__ xh,
                                                     const unsigned short* __restrict__ wh,
                                                     float* __restrict__ z_pre)
{
    __shared__ unsigned short Ah[GBM][LROW];
    __shared__ unsigned short Bh[GBN][LROW];

    const int tid = threadIdx.x;
    const int bid = blockIdx.x;
    const int swz = (bid & 7) * (NWG / 8) + (bid >> 3);
    const int bn = (swz % (NLAT / GBN)) * GBN;
    const int bm = (swz / (NLAT / GBN)) * GBM;

    const int lane = tid & 63;
    const int wv = tid >> 6;
    const int wr = (wv >> 1) * 64;
    const int wc = (wv & 1) * 64;
    const int fr = lane & 15;
    const int fg = lane >> 4;

    int srow[4], sko[4];
    const unsigned short* pxa[4];
    const unsigned short* pwb[4];
    #pragma unroll
    for (int q = 0; q < 4; ++q) {
        const int c = q * 256 + tid;
        srow[q] = c >> 3;
        sko[q]  = (c & 7) * 8;
        pxa[q] = xh + (size_t)(bm + srow[q]) * D_IN + sko[q];
        pwb[q] = wh + (size_t)(bn + srow[q]) * D_IN + sko[q];
    }

    f32x4 acc[4][4];
    #pragma unroll
    for (int i = 0; i < 4; ++i)
        #pragma unroll
        for (int j = 0; j < 4; ++j)
            #pragma unroll
            for (int e = 0; e < 4; ++e) acc[i][j][e] = 0.0f;

    for (int k0 = 0; k0 < D_IN; k0 += GBK) {
        short8 va[4], vb[4];
        #pragma unroll
        for (int q = 0; q < 4; ++q) {
            va[q] = *(const short8*)(pxa[q] + k0);
            vb[q] = *(const short8*)(pwb[q] + k0);
        }

        __syncthreads();

        #pragma unroll
        for (int q = 0; q < 4; ++q) {
            *(short8*)&Ah[srow[q]][sko[q]] = va[q];
            *(short8*)&Bh[srow[q]][sko[q]] = vb[q];
        }

        __syncthreads();

        #pragma unroll
        for (int ks = 0; ks < 2; ++ks) {
            short8 ah[4], bh[4];
            #pragma unroll
            for (int t = 0; t < 4; ++t) {
                ah[t] = *(const short8*)&Ah[wr + t*16 + fr][ks*32 + fg*8];
                bh[t] = *(const short8*)&Bh[wc + t*16 + fr][ks*32 + fg*8];
            }
            #pragma unroll
            for (int mt = 0; mt < 4; ++mt)
                #pragma unroll
                for (int nt = 0; nt < 4; ++nt)
                    acc[mt][nt] = __builtin_amdgcn_mfma_f32_16x16x32_bf16(ah[mt], bh[nt], acc[mt][nt], 0, 0, 0);
        }
    }

    #pragma unroll
    for (int mt = 0; mt < 4; ++mt)
        #pragma unroll
        for (int j = 0; j < 4; ++j) {
            const int r = bm + wr + mt*16 + fg*4 + j;
            float* dst = z_pre + (size_t)r * NLAT + bn + wc;
            #pragma unroll
            for (int nt = 0; nt < 4; ++nt)
                dst[nt*16 + fr] = acc[mt][nt][j];
        }
}

// ---------------------------------------------------------------------------
// Stage 1: streaming scan — read z_pre, write z=0 (full), extract candidates
// (> THRESH) into per-row unordered lists via wave-aggregated atomics.
// 4 blocks per row.
// ---------------------------------------------------------------------------
__global__ __launch_bounds__(256) void scan_extract(const float* __restrict__ z_pre,
                                                    float* __restrict__ z,
                                                    int* __restrict__ cnt_ws,
                                                    int* __restrict__ cand_idx,
                                                    float* __restrict__ cand_val)
{
    const int r   = blockIdx.x >> 2;
    const int seg = blockIdx.x & 3;
    const int tid = threadIdx.x;
    const int lane = tid & 63;
    const unsigned long long lt = (1ull << lane) - 1ull;

    const float4* src = (const float4*)(z_pre + (size_t)r * NLAT) + seg * (NLAT/16);
    float4*       dst = (float4*)(z + (size_t)r * NLAT) + seg * (NLAT/16);
    const int col0 = seg * (NLAT/4);

    #pragma unroll
    for (int u = 0; u < NLAT/16/256; ++u) {
        const int f4 = u * 256 + tid;
        const float4 v = src[f4];
        dst[f4] = make_float4(0.f, 0.f, 0.f, 0.f);

        const bool p0 = v.x > THRESH, p1 = v.y > THRESH,
                   p2 = v.z > THRESH, p3 = v.w > THRESH;
        const unsigned long long m0 = __ballot(p0);
        const unsigned long long m1 = __ballot(p1);
        const unsigned long long m2 = __ballot(p2);
        const unsigned long long m3 = __ballot(p3);
        const int c0 = __popcll(m0), c1 = __popcll(m1),
                  c2 = __popcll(m2), c3 = __popcll(m3);
        const int cw = c0 + c1 + c2 + c3;
        int base = 0;
        if (lane == 0 && cw) base = atomicAdd(&cnt_ws[r], cw);
        base = __shfl(base, 0, 64);
        if (cw) {
            const int i0 = col0 + f4 * 4;
            if (p0) { const int s = base + __popcll(m0 & lt);
                if (s < CAND_MAX) { cand_idx[(size_t)r*CAND_MAX+s] = i0;   cand_val[(size_t)r*CAND_MAX+s] = v.x; } }
            if (p1) { const int s = base + c0 + __popcll(m1 & lt);
                if (s < CAND_MAX) { cand_idx[(size_t)r*CAND_MAX+s] = i0+1; cand_val[(size_t)r*CAND_MAX+s] = v.y; } }
            if (p2) { const int s = base + c0 + c1 + __popcll(m2 & lt);
                if (s < CAND_MAX) { cand_idx[(size_t)r*CAND_MAX+s] = i0+2; cand_val[(size_t)r*CAND_MAX+s] = v.z; } }
            if (p3) { const int s = base + c0 + c1 + c2 + __popcll(m3 & lt);
                if (s < CAND_MAX) { cand_idx[(size_t)r*CAND_MAX+s] = i0+3; cand_val[(size_t)r*CAND_MAX+s] = v.w; } }
        }
    }
}

// ---------------------------------------------------------------------------
// Stage 2: per-row classify — histogram, boundary bin, sure/amb split.
// ---------------------------------------------------------------------------
__global__ __launch_bounds__(256) void classify_kernel(const int* __restrict__ cnt_ws,
                                                       const float* __restrict__ cand_val,
                                                       unsigned char* __restrict__ keep_ws,
                                                       int* __restrict__ ambslot_ws,
                                                       int* __restrict__ namb_ws,
                                                       int* __restrict__ nsure_ws,
                                                       int* __restrict__ flag_ws)
{
    __shared__ float cv[CAND_MAX];
    __shared__ unsigned hist[256];
    __shared__ int b_sh, nsure_sh, namb_sh;

    const int r = blockIdx.x;
    const int tid = threadIdx.x;
    const int cnt = cnt_ws[r];

    if (cnt < K_TOP || cnt > CAND_MAX) {
        if (tid == 0) { flag_ws[r] = 1; namb_ws[r] = 0; nsure_ws[r] = 0; }
        return;
    }
    if (tid == 0) { nsure_sh = 0; namb_sh = 0; }
    hist[tid] = 0u;
    __syncthreads();

    for (int q = tid; q < cnt; q += 256) {
        const float vv = cand_val[(size_t)r*CAND_MAX + q];
        cv[q] = vv;
        int b = (int)(__float_as_uint(vv) >> 16) - 16288;
        b = b < 0 ? 0 : (b > 255 ? 255 : b);
        atomicAdd(&hist[b], 1u);
    }
    __syncthreads();
    if (tid == 0) {
        int acc = 0, b = 255;
        for (; b >= 0; --b) {
            const int nb = acc + (int)hist[b];
            if (nb >= K_TOP) break;
            acc = nb;
        }
        b_sh = b;
    }
    __syncthreads();

    const int bstar = b_sh;
    const float hi = binedge(bstar + 1) + DELTA;
    const float lo = binedge(bstar) - DELTA;
    if (bstar >= 255 || bstar < 0 || lo <= THRESH + 1e-3f) {
        if (tid == 0) { flag_ws[r] = 1; namb_ws[r] = 0; nsure_ws[r] = 0; }
        return;
    }

    for (int t = tid; t < cnt; t += 256) {
        const float vt = cv[t];
        unsigned char k = 0;
        if (vt > hi) { k = 1; atomicAdd(&nsure_sh, 1); }
        else if (vt >= lo) {
            const int p = atomicAdd(&namb_sh, 1);
            if (p < MAXAMB) ambslot_ws[(size_t)r*MAXAMB + p] = t;
        }
        keep_ws[(size_t)r*CAND_MAX + t] = k;
    }
    __syncthreads();

    if (tid == 0) {
        const int namb = namb_sh, nsure = nsure_sh;
        namb_ws[r] = namb < MAXAMB ? namb : MAXAMB;
        nsure_ws[r] = nsure;
        flag_ws[r] = (namb > MAXAMB || nsure >= K_TOP) ? 1 : 0;
    }
}

// ---------------------------------------------------------------------------
// Stage 3: flat refine — one block per row (standalone => full-device TLP),
// exact f64 dots for the ambiguous candidates.
// ---------------------------------------------------------------------------
__global__ __launch_bounds__(256) void refine_kernel(const int* __restrict__ flag_ws,
                                                     const int* __restrict__ namb_ws,
                                                     const int* __restrict__ ambslot_ws,
                                                     const int* __restrict__ cand_idx,
                                                     const float* __restrict__ x,
                                                     const float* __restrict__ W_enc,
                                                     const float* __restrict__ bpre,
                                                     double* __restrict__ dval_ws)
{
    const int r = blockIdx.x;
    if (flag_ws[r]) return;
    const int namb = namb_ws[r];
    const int tid = threadIdx.x;
    const int lane = tid & 63, w = tid >> 6;
    const float* xrow = x + (size_t)r * D_IN;

    for (int q = w; q < namb; q += 4) {
        const int t = ambslot_ws[(size_t)r*MAXAMB + q];
        const int j = cand_idx[(size_t)r*CAND_MAX + t];
        const float* wrow = W_enc + (size_t)j * D_IN;
        double a = 0.0;
        #pragma unroll
        for (int k = lane; k < D_IN; k += 64)
            a = fma((double)xrow[k] - (double)bpre[k], (double)wrow[k], a);
        #pragma unroll
        for (int off = 32; off; off >>= 1) a += __shfl_down(a, off, 64);
        if (lane == 0) dval_ws[(size_t)r*MAXAMB + q] = a;
    }
}

// ---------------------------------------------------------------------------
// Stage 4: finalize — rank ambiguous by (f64 desc, idx asc), compact the 64
// keepers, index-order, write ws lists + 64 scattered z values.
// ---------------------------------------------------------------------------
__global__ __launch_bounds__(256) void finalize_kernel(const int* __restrict__ cnt_ws,
                                                       const int* __restrict__ cand_idx,
                                                       const float* __restrict__ cand_val,
                                                       unsigned char* __restrict__ keep_ws,
                                                       const int* __restrict__ ambslot_ws,
                                                       const int* __restrict__ namb_ws,
                                                       const int* __restrict__ nsure_ws,
                                                       const double* __restrict__ dval_ws,
                                                       float* __restrict__ z,
                                                       int* __restrict__ idx_ws,
                                                       float* __restrict__ val_ws,
                                                       int* __restrict__ flag_ws)
{
    __shared__ unsigned char keep[CAND_MAX];
    __shared__ double dv_sh[MAXAMB];
    __shared__ int    as_sh[MAXAMB];
    __shared__ int    ai_sh[MAXAMB];
    __shared__ int    t_idx[K_TOP + 8];
    __shared__ float  t_val[K_TOP + 8];
    __shared__ int nk_sh;

    const int r = blockIdx.x;
    if (flag_ws[r]) return;
    const int tid = threadIdx.x;
    const int cnt = cnt_ws[r];
    const int namb = namb_ws[r];
    const int nkeep_amb = K_TOP - nsure_ws[r];

    if (tid == 0) nk_sh = 0;
    for (int t = tid; t < cnt; t += 256) keep[t] = keep_ws[(size_t)r*CAND_MAX + t];
    for (int q = tid; q < namb; q += 256) {
        const int t = ambslot_ws[(size_t)r*MAXAMB + q];
        as_sh[q] = t;
        ai_sh[q] = cand_idx[(size_t)r*CAND_MAX + t];
        dv_sh[q] = dval_ws[(size_t)r*MAXAMB + q];
    }
    __syncthreads();

    for (int t = tid; t < namb; t += 256) {
        const double dv = dv_sh[t];
        const int it = ai_sh[t];
        int rk = 0;
        for (int q = 0; q < namb; ++q)
            rk += (dv_sh[q] > dv) || (dv_sh[q] == dv && ai_sh[q] < it);
        if (rk < nkeep_amb) keep[as_sh[t]] = 1;
    }
    __syncthreads();

    for (int t = tid; t < cnt; t += 256) {
        if (keep[t]) {
            const int p = atomicAdd(&nk_sh, 1);
            if (p < K_TOP + 8) {
                t_idx[p] = cand_idx[(size_t)r*CAND_MAX + t];
                t_val[p] = cand_val[(size_t)r*CAND_MAX + t];
            }
        }
    }
    __syncthreads();
    if (nk_sh != K_TOP) { if (tid == 0) flag_ws[r] = 1; return; }

    if (tid < K_TOP) {
        const int it = t_idx[tid];
        int pos = 0;
        #pragma unroll 8
        for (int s = 0; s < K_TOP; ++s) pos += (t_idx[s] < it);
        idx_ws[r * K_TOP + pos] = it;
        val_ws[r * K_TOP + pos] = t_val[tid];
        z[(size_t)r * NLAT + it] = t_val[tid];   // scatter over the zeroed row
    }
}

// ---------------------------------------------------------------------------
// Fallback full-row top-k (r3-verified).  Only flagged rows (or all if null).
// ---------------------------------------------------------------------------
__global__ __launch_bounds__(1024) void topk_fallback(const float* __restrict__ z_pre,
                                                      float* __restrict__ z,
                                                      const float* __restrict__ x,
                                                      const float* __restrict__ W_enc,
                                                      const float* __restrict__ bpre,
                                                      int* __restrict__ idx_ws,
                                                      float* __restrict__ val_ws,
                                                      const int* __restrict__ flag_ws)
{
    if (flag_ws != nullptr && flag_ws[blockIdx.x] == 0) return;

    __shared__ unsigned hist_w[16][257];
    __shared__ unsigned hist[256];
    __shared__ unsigned sh_prefix;
    __shared__ int sh_rem;
    __shared__ int cntA;
    __shared__ int nsure_sh;
    __shared__ int idxA[MAXA];
    __shared__ double dvalA[MAXA];
    __shared__ unsigned char keepA[MAXA];
    __shared__ int wcnt[16][24];

    const int r = blockIdx.x;
    const int tid = threadIdx.x;
    const int lane = tid & 63;
    const int w = tid >> 6;
    const unsigned long long lt = (1ull << lane) - 1ull;

    const float* src = z_pre + (size_t)r * NLAT;
    float v[24];
    #pragma unroll
    for (int c = 0; c < 24; ++c) v[c] = src[c*1024 + tid];

    if (tid == 0) { sh_prefix = 0u; sh_rem = K_TOP; cntA = 0; nsure_sh = 0; }
    if (idx_ws != nullptr && tid < K_TOP) {
        idx_ws[r*K_TOP + tid] = 0; val_ws[r*K_TOP + tid] = 0.0f;
    }

    for (int lvl = 0; lvl < 4; ++lvl) {
        const int shift = 24 - 8*lvl;
        for (int i = tid; i < 16*257; i += 1024) ((unsigned*)hist_w)[i] = 0u;
        __syncthreads();
        const unsigned pfx = sh_prefix;
        #pragma unroll
        for (int c = 0; c < 24; ++c) {
            const unsigned key = f2key(v[c]);
            const bool match = (lvl == 0) || ((key >> (shift + 8)) == (pfx >> (shift + 8)));
            if (match) atomicAdd(&hist_w[w][(key >> shift) & 255u], 1u);
        }
        __syncthreads();
        if (tid < 256) {
            unsigned s = 0;
            #pragma unroll
            for (int q = 0; q < 16; ++q) s += hist_w[q][tid];
            hist[tid] = s;
        }
        __syncthreads();
        if (tid == 0) {
            int rem = sh_rem, acc = 0, b = 255;
            for (; b >= 0; --b) {
                const int nb = acc + (int)hist[b];
                if (nb >= rem) { sh_rem = rem - acc; break; }
                acc = nb;
            }
            sh_prefix = pfx | ((unsigned)b << shift);
        }
        __syncthreads();
    }

    const float vT = key2f(sh_prefix);
    const float thr_lo = vT - DELTA, thr_hi = vT + DELTA;

    int wsure = 0;
    #pragma unroll
    for (int c = 0; c < 24; ++c) {
        const float val = v[c];
        const unsigned long long m = __ballot(val > thr_hi);
        if (lane == 0) wsure += (int)__popcll(m);
        if (val <= thr_hi && val >= thr_lo) {
            const int p = atomicAdd(&cntA, 1);
            if (p < MAXA) idxA[p] = c*1024 + tid;
        }
    }
    if (lane == 0 && wsure) atomicAdd(&nsure_sh, (unsigned)wsure);
    __syncthreads();

    const int nA = cntA < MAXA ? cntA : MAXA;
    const int nkeepA = K_TOP - nsure_sh;

    for (int q = w; q < nA; q += 16) {
        const int j = idxA[q];
        const float* wrow = W_enc + (size_t)j * D_IN;
        const float* xrow = x + (size_t)r * D_IN;
        double a = 0.0;
        for (int k = lane; k < D_IN; k += 64)
            a = fma((double)xrow[k] - (double)bpre[k], (double)wrow[k], a);
        #pragma unroll
        for (int off = 32; off; off >>= 1) a += __shfl_down(a, off, 64);
        if (lane == 0) dvalA[q] = a;
    }
    __syncthreads();

    for (int t = tid; t < nA; t += 1024) {
        const double dv = dvalA[t];
        const int ix = idxA[t];
        int rank = 0;
        for (int q = 0; q < nA; ++q)
            rank += (dvalA[q] > dv) || (dvalA[q] == dv && idxA[q] < ix);
        keepA[t] = (rank < nkeepA) ? 1 : 0;
    }
    __syncthreads();

    bool kp[24];
    #pragma unroll
    for (int c = 0; c < 24; ++c) {
        const float val = v[c];
        bool k = (val > thr_hi);
        if (!k && val >= thr_lo) {
            const int i = c*1024 + tid;
            for (int q = 0; q < nA; ++q)
                if (idxA[q] == i) { k = (keepA[q] != 0); break; }
        }
        kp[c] = k;
        const unsigned long long m = __ballot(k);
        if (lane == 0) wcnt[w][c] = (int)__popcll(m);
    }
    __syncthreads();
    if (tid == 0) {
        int run = 0;
        for (int c = 0; c < 24; ++c)
            #pragma unroll
            for (int q = 0; q < 16; ++q) { const int t = wcnt[q][c]; wcnt[q][c] = run; run += t; }
    }
    __syncthreads();

    float* zdst = z + (size_t)r * NLAT;
    #pragma unroll
    for (int c = 0; c < 24; ++c) {
        const unsigned long long m = __ballot(kp[c]);
        const int pos = wcnt[w][c] + (int)__popcll(m & lt);
        const int i = c*1024 + tid;
        zdst[i] = kp[c] ? v[c] : 0.0f;
        if (kp[c] && idx_ws != nullptr && pos < K_TOP) {
            idx_ws[r*K_TOP + pos] = i;
            val_ws[r*K_TOP + pos] = v[c];
        }
    }
}

// ---------------------------------------------------------------------------
// Fallback GEMM with in-kernel split-2 (r5-verified) for small ws.
// ---------------------------------------------------------------------------
#define FBK 32
#define FLROW (FBK + 8)

__global__ __launch_bounds__(256) void enc_gemm_mfma(const float* __restrict__ x,
                                                     const float* __restrict__ W,
                                                     const float* __restrict__ bpre,
                                                     float* __restrict__ z_pre)
{
    __shared__ unsigned short Ah[GBM][FLROW], Al[GBM][FLROW];
    __shared__ unsigned short Bh[GBN][FLROW], Bl[GBN][FLROW];

    const int tid = threadIdx.x;
    const int bm = blockIdx.y * GBM;
    const int bn = blockIdx.x * GBN;
    const int lane = tid & 63;
    const int wv = tid >> 6;
    const int wr = (wv >> 1) * 64;
    const int wc = (wv & 1) * 64;
    const int fr = lane & 15;
    const int fg = lane >> 4;

    const int srow = tid >> 3;
    const int sk   = (tid & 7) * 4;

    f32x4 acc[4][4];
    #pragma unroll
    for (int i = 0; i < 4; ++i)
        #pragma unroll
        for (int j = 0; j < 4; ++j)
            #pragma unroll
            for (int e = 0; e < 4; ++e) acc[i][j][e] = 0.0f;

    for (int k0 = 0; k0 < D_IN; k0 += FBK) {
        float4 xa[4], wb[4];
        const float4 bp = *(const float4*)(bpre + k0 + sk);
        #pragma unroll
        for (int p = 0; p < 4; ++p) {
            xa[p] = *(const float4*)(x + (size_t)(bm + srow + 32*p) * D_IN + k0 + sk);
            wb[p] = *(const float4*)(W + (size_t)(bn + srow + 32*p) * D_IN + k0 + sk);
        }
        __syncthreads();
        #pragma unroll
        for (int p = 0; p < 4; ++p) {
            const float a0 = xa[p].x - bp.x, a1 = xa[p].y - bp.y,
                        a2 = xa[p].z - bp.z, a3 = xa[p].w - bp.w;
            const unsigned short h0 = bf16hi(a0), h1 = bf16hi(a1),
                                 h2 = bf16hi(a2), h3 = bf16hi(a3);
            *(ushort4*)&Ah[srow + 32*p][sk] = make_ushort4(h0, h1, h2, h3);
            *(ushort4*)&Al[srow + 32*p][sk] = make_ushort4(
                bf16hi(a0 - bf2f(h0)), bf16hi(a1 - bf2f(h1)),
                bf16hi(a2 - bf2f(h2)), bf16hi(a3 - bf2f(h3)));
            const float b0 = wb[p].x, b1 = wb[p].y, b2 = wb[p].z, b3 = wb[p].w;
            const unsigned short g0 = bf16hi(b0), g1 = bf16hi(b1),
                                 g2 = bf16hi(b2), g3 = bf16hi(b3);
            *(ushort4*)&Bh[srow + 32*p][sk] = make_ushort4(g0, g1, g2, g3);
            *(ushort4*)&Bl[srow + 32*p][sk] = make_ushort4(
                bf16hi(b0 - bf2f(g0)), bf16hi(b1 - bf2f(g1)),
                bf16hi(b2 - bf2f(g2)), bf16hi(b3 - bf2f(g3)));
        }
        __syncthreads();

        short8 ah[4], al[4], bh[4], bl[4];
        #pragma unroll
        for (int t = 0; t < 4; ++t) {
            ah[t] = *(const short8*)&Ah[wr + t*16 + fr][fg * 8];
            al[t] = *(const short8*)&Al[wr + t*16 + fr][fg * 8];
            bh[t] = *(const short8*)&Bh[wc + t*16 + fr][fg * 8];
            bl[t] = *(const short8*)&Bl[wc + t*16 + fr][fg * 8];
        }
        #pragma unroll
        for (int mt = 0; mt < 4; ++mt)
            #pragma unroll
            for (int nt = 0; nt < 4; ++nt) {
                acc[mt][nt] = __builtin_amdgcn_mfma_f32_16x16x32_bf16(ah[mt], bh[nt], acc[mt][nt], 0, 0, 0);
                acc[mt][nt] = __builtin_amdgcn_mfma_f32_16x16x32_bf16(ah[mt], bl[nt], acc[mt][nt], 0, 0, 0);
                acc[mt][nt] = __builtin_amdgcn_mfma_f32_16x16x32_bf16(al[mt], bh[nt], acc[mt][nt], 0, 0, 0);
            }
    }

    #pragma unroll
    for (int mt = 0; mt < 4; ++mt)
        #pragma unroll
        for (int j = 0; j < 4; ++j) {
            const int r = bm + wr + mt*16 + fg*4 + j;
            float* dst = z_pre + (size_t)r * NLAT + bn + wc;
            #pragma unroll
            for (int nt = 0; nt < 4; ++nt)
                dst[nt*16 + fr] = acc[mt][nt][j];
        }
}

// ---------------------------------------------------------------------------
__global__ __launch_bounds__(256) void dec_kernel(const int* __restrict__ idx_ws,
                                                  const float* __restrict__ val_ws,
                                                  const float* __restrict__ W_dec,
                                                  const float* __restrict__ bpre,
                                                  const float* __restrict__ x,
                                                  float* __restrict__ x_hat,
                                                  float* __restrict__ recon)
{
    __shared__ int sidx[K_TOP];
    __shared__ float sval[K_TOP];
    const int r = blockIdx.x;
    const int tid = threadIdx.x;
    if (tid < K_TOP) {
        sidx[tid] = idx_ws[r*K_TOP + tid];
        sval[tid] = val_ws[r*K_TOP + tid];
    }
    __syncthreads();

    float a0 = bpre[tid], a1 = bpre[tid + 256], a2 = bpre[tid + 512];
    #pragma unroll 4
    for (int j = 0; j < K_TOP; ++j) {
        const float vv = sval[j];
        const float* wr_ = W_dec + (size_t)sidx[j] * D_IN;
        a0 = fmaf(vv, wr_[tid],       a0);
        a1 = fmaf(vv, wr_[tid + 256], a1);
        a2 = fmaf(vv, wr_[tid + 512], a2);
    }
    const size_t o = (size_t)r * D_IN + tid;
    x_hat[o]       = a0;
    x_hat[o + 256] = a1;
    x_hat[o + 512] = a2;
    recon[o]       = x[o]       - a0;
    recon[o + 256] = x[o + 256] - a1;
    recon[o + 512] = x[o + 512] - a2;
}

__global__ __launch_bounds__(256) void dec_scan_kernel(const float* __restrict__ z,
                                                       const float* __restrict__ W_dec,
                                                       const float* __restrict__ bpre,
                                                       const float* __restrict__ x,
                                                       float* __restrict__ x_hat,
                                                       float* __restrict__ recon)
{
    __shared__ int sidx[K_TOP];
    __shared__ float sval[K_TOP];
    __shared__ int wcnt[4];
    __shared__ int base;
    const int r = blockIdx.x;
    const int tid = threadIdx.x;
    const int lane = tid & 63, w = tid >> 6;
    if (tid == 0) base = 0;
    __syncthreads();
    const float* zrow = z + (size_t)r * NLAT;
    for (int c = 0; c < NLAT; c += 256) {
        const float vv = zrow[c + tid];
        const bool nz = (vv != 0.0f);
        const unsigned long long m = __ballot(nz);
        if (lane == 0) wcnt[w] = __popcll(m);
        __syncthreads();
        int b = base;
        for (int j = 0; j < w; ++j) b += wcnt[j];
        const int pos = b + __popcll(m & ((1ull << lane) - 1ull));
        if (nz && pos < K_TOP) { sidx[pos] = c + tid; sval[pos] = vv; }
        __syncthreads();
        if (tid == 0) { int s = 0; for (int j = 0; j < 4; ++j) s += wcnt[j]; base += s; }
        __syncthreads();
    }
    const int n = base > K_TOP ? K_TOP : base;

    float a0 = bpre[tid], a1 = bpre[tid + 256], a2 = bpre[tid + 512];
    for (int j = 0; j < n; ++j) {
        const float vv = sval[j];
        const float* wr_ = W_dec + (size_t)sidx[j] * D_IN;
        a0 = fmaf(vv, wr_[tid],       a0);
        a1 = fmaf(vv, wr_[tid + 256], a1);
        a2 = fmaf(vv, wr_[tid + 512], a2);
    }
    const size_t o = (size_t)r * D_IN + tid;
    x_hat[o]       = a0;
    x_hat[o + 256] = a1;
    x_hat[o + 512] = a2;
    recon[o]       = x[o]       - a0;
    recon[o + 256] = x[o + 256] - a1;
    recon[o + 512] = x[o + 512] - a2;
}

// ---------------------------------------------------------------------------
extern "C" void kernel_launch(void* const* d_in, const int* in_sizes, int n_in,
                              void* d_out, int out_size, void* d_ws, size_t ws_size,
                              hipStream_t stream)
{
    const float* x     = (const float*)d_in[0];
    const float* W_enc = (const float*)d_in[1];
    const float* W_dec = (const float*)d_in[2];
    const float* bpre  = (const float*)d_in[3];

    float* out   = (float*)d_out;
    float* x_hat = out;
    float* z     = x_hat + (size_t)BATCH * D_IN;
    float* z_pre = z     + (size_t)BATCH * NLAT;
    float* recon = z_pre + (size_t)BATCH * NLAT;

    // ws layout (8B-aligned blocks first-ish; all sizes multiples of 16 KB)
    char* p = (char*)d_ws;
    int*    flag_ws  = (int*)p;            p += (size_t)BATCH * 4;
    int*    idx_ws   = (int*)p;            p += (size_t)BATCH * K_TOP * 4;
    float*  val_ws   = (float*)p;          p += (size_t)BATCH * K_TOP * 4;
    int*    cnt_ws   = (int*)p;            p += (size_t)BATCH * 4;
    int*    namb_ws  = (int*)p;            p += (size_t)BATCH * 4;
    int*    nsure_ws = (int*)p;            p += (size_t)BATCH * 4;
    double* dval_ws  = (double*)p;         p += (size_t)BATCH * MAXAMB * 8;
    int*    ambslot  = (int*)p;            p += (size_t)BATCH * MAXAMB * 4;
    int*    cand_idx = (int*)p;            p += (size_t)BATCH * CAND_MAX * 4;
    float*  cand_val = (float*)p;          p += (size_t)BATCH * CAND_MAX * 4;
    unsigned char* keep_ws = (unsigned char*)p;  p += (size_t)BATCH * CAND_MAX;
    unsigned short* xh = (unsigned short*)p;     p += (size_t)BATCH * D_IN * 2;
    unsigned short* wh = (unsigned short*)p;     p += (size_t)NLAT * D_IN * 2;
    const size_t ws_full = (size_t)(p - (char*)d_ws);
    const bool have_full = (d_ws != nullptr) && (ws_size >= ws_full);

    if (have_full) {
        hipMemsetAsync(cnt_ws, 0, (size_t)BATCH * 4, stream);
        conv_x_kernel<<<(BATCH * D_IN / 4) / 256, 256, 0, stream>>>(
            (const float4*)x, bpre, (ushort4*)xh);
        conv_w_kernel<<<(NLAT * D_IN / 4) / 256, 256, 0, stream>>>(
            (const float4*)W_enc, (ushort4*)wh);
        enc_gemm_bf16<<<NWG, 256, 0, stream>>>(xh, wh, z_pre);

        scan_extract<<<BATCH * 4, 256, 0, stream>>>(z_pre, z, cnt_ws, cand_idx, cand_val);
        classify_kernel<<<BATCH, 256, 0, stream>>>(cnt_ws, cand_val, keep_ws, ambslot,
                                                   namb_ws, nsure_ws, flag_ws);
        refine_kernel<<<BATCH, 256, 0, stream>>>(flag_ws, namb_ws, ambslot, cand_idx,
                                                 x, W_enc, bpre, dval_ws);
        finalize_kernel<<<BATCH, 256, 0, stream>>>(cnt_ws, cand_idx, cand_val, keep_ws,
                                                   ambslot, namb_ws, nsure_ws, dval_ws,
                                                   z, idx_ws, val_ws, flag_ws);
        topk_fallback<<<BATCH, 1024, 0, stream>>>(z_pre, z, x, W_enc, bpre,
                                                  idx_ws, val_ws, flag_ws);
        dec_kernel<<<BATCH, 256, 0, stream>>>(idx_ws, val_ws, W_dec, bpre, x, x_hat, recon);
    } else {
        dim3 g1(NLAT / GBN, BATCH / GBM);
        enc_gemm_mfma<<<g1, 256, 0, stream>>>(x, W_enc, bpre, z_pre);
        topk_fallback<<<BATCH, 1024, 0, stream>>>(z_pre, z, x, W_enc, bpre,
                                                  nullptr, nullptr, nullptr);
        dec_scan_kernel<<<BATCH, 256, 0, stream>>>(z, W_dec, bpre, x, x_hat, recon);
    }
}

// Round 9
// 771.189 us; speedup vs baseline: 6.4811x; 1.0975x over previous
//
#include <hip/hip_runtime.h>

#define D_IN   768
#define NLAT   24576
#define BATCH  4096
#define K_TOP  64
#define MAXA   1024
#define DELTA  0.05f
#define THRESH 1.30f
#define CAND_MAX 512
#define MAXAMB 128
#define SLOTS  12

typedef float f32x4 __attribute__((ext_vector_type(4)));
typedef short short8 __attribute__((ext_vector_type(8)));

// ---------------------------------------------------------------------------
__device__ __forceinline__ unsigned f2key(float f) {
    unsigned u = __float_as_uint(f);
    return (u & 0x80000000u) ? ~u : (u | 0x80000000u);
}
__device__ __forceinline__ float key2f(unsigned k) {
    unsigned u = (k & 0x80000000u) ? (k & 0x7fffffffu) : ~k;
    return __uint_as_float(u);
}
__device__ __forceinline__ unsigned short bf16hi(float f) {   // RNE f32->bf16
    unsigned u = __float_as_uint(f);
    unsigned r = u + 0x7fffu + ((u >> 16) & 1u);
    return (unsigned short)(r >> 16);
}
__device__ __forceinline__ float bf2f(unsigned short h) {
    return __uint_as_float(((unsigned)h) << 16);
}
__device__ __forceinline__ float binedge(int b) {
    return __uint_as_float((unsigned)(16288 + b) << 16);   // bin 0 edge = 1.25f
}

// ---------------------------------------------------------------------------
// One-time bf16 convert passes.
// ---------------------------------------------------------------------------
__global__ __launch_bounds__(256) void conv_x_kernel(const float4* __restrict__ src,
                                                     const float* __restrict__ bpre,
                                                     ushort4* __restrict__ hi)
{
    const int f = blockIdx.x * 256 + threadIdx.x;
    float4 v = src[f];
    const float4 bp = ((const float4*)bpre)[f % (D_IN / 4)];
    ushort4 h;
    h.x = bf16hi(v.x - bp.x);
    h.y = bf16hi(v.y - bp.y);
    h.z = bf16hi(v.z - bp.z);
    h.w = bf16hi(v.w - bp.w);
    hi[f] = h;
}

__global__ __launch_bounds__(256) void conv_w_kernel(const float4* __restrict__ src,
                                                     ushort4* __restrict__ hi)
{
    const int f = blockIdx.x * 256 + threadIdx.x;
    const float4 v = src[f];
    ushort4 h;
    h.x = bf16hi(v.x); h.y = bf16hi(v.y); h.z = bf16hi(v.z); h.w = bf16hi(v.w);
    hi[f] = h;
}

// ---------------------------------------------------------------------------
// Single-bf16 encoder GEMM (r7-verified core) + fused z-zeroing + slot-based
// candidate extraction (NO global atomics — r4's failure was 1.2M contended
// cross-XCD atomicAdds; slots are private per (row, block-column)).
// ---------------------------------------------------------------------------
#define GBM 128
#define GBN 128
#define GBK 64
#define LROW (GBK + 8)
#define NWG  ((NLAT / GBN) * (BATCH / GBM))   // 6144
#define NBLKN (NLAT / GBN)                    // 192

__global__ __launch_bounds__(256) void enc_gemm_fused(const unsigned short* __restrict__ xh,
                                                      const unsigned short* __restrict__ wh,
                                                      float* __restrict__ z_pre,
                                                      float* __restrict__ z,
                                                      int* __restrict__ cnt_blk,   // [NBLKN][BATCH]
                                                      int2* __restrict__ slot_iv)  // [BATCH][NBLKN][SLOTS]
{
    __shared__ unsigned short Ah[GBM][LROW];
    __shared__ unsigned short Bh[GBN][LROW];
    __shared__ int rowcnt[GBM];

    const int tid = threadIdx.x;
    const int bid = blockIdx.x;
    const int swz = (bid & 7) * (NWG / 8) + (bid >> 3);
    const int bn = (swz % NBLKN) * GBN;
    const int bm = (swz / NBLKN) * GBM;
    const int blkn = bn / GBN;

    const int lane = tid & 63;
    const int wv = tid >> 6;
    const int wr = (wv >> 1) * 64;
    const int wc = (wv & 1) * 64;
    const int fr = lane & 15;
    const int fg = lane >> 4;

    int srow[4], sko[4];
    const unsigned short* pxa[4];
    const unsigned short* pwb[4];
    #pragma unroll
    for (int q = 0; q < 4; ++q) {
        const int c = q * 256 + tid;
        srow[q] = c >> 3;
        sko[q]  = (c & 7) * 8;
        pxa[q] = xh + (size_t)(bm + srow[q]) * D_IN + sko[q];
        pwb[q] = wh + (size_t)(bn + srow[q]) * D_IN + sko[q];
    }

    f32x4 acc[4][4];
    #pragma unroll
    for (int i = 0; i < 4; ++i)
        #pragma unroll
        for (int j = 0; j < 4; ++j)
            #pragma unroll
            for (int e = 0; e < 4; ++e) acc[i][j][e] = 0.0f;

    for (int k0 = 0; k0 < D_IN; k0 += GBK) {
        short8 va[4], vb[4];
        #pragma unroll
        for (int q = 0; q < 4; ++q) {
            va[q] = *(const short8*)(pxa[q] + k0);
            vb[q] = *(const short8*)(pwb[q] + k0);
        }

        __syncthreads();

        #pragma unroll
        for (int q = 0; q < 4; ++q) {
            *(short8*)&Ah[srow[q]][sko[q]] = va[q];
            *(short8*)&Bh[srow[q]][sko[q]] = vb[q];
        }

        __syncthreads();

        #pragma unroll
        for (int ks = 0; ks < 2; ++ks) {
            short8 ah[4], bh[4];
            #pragma unroll
            for (int t = 0; t < 4; ++t) {
                ah[t] = *(const short8*)&Ah[wr + t*16 + fr][ks*32 + fg*8];
                bh[t] = *(const short8*)&Bh[wc + t*16 + fr][ks*32 + fg*8];
            }
            #pragma unroll
            for (int mt = 0; mt < 4; ++mt)
                #pragma unroll
                for (int nt = 0; nt < 4; ++nt)
                    acc[mt][nt] = __builtin_amdgcn_mfma_f32_16x16x32_bf16(ah[mt], bh[nt], acc[mt][nt], 0, 0, 0);
        }
    }

    // ---- epilogue: z_pre store + extraction + z zero-fill + counts ----
    if (tid < GBM) rowcnt[tid] = 0;
    __syncthreads();

    // C/D layout: col = lane&15, row = (lane>>4)*4 + reg
    #pragma unroll
    for (int mt = 0; mt < 4; ++mt)
        #pragma unroll
        for (int j = 0; j < 4; ++j) {
            const int lr = wr + mt*16 + fg*4 + j;
            const int r  = bm + lr;
            float* dst = z_pre + (size_t)r * NLAT + bn + wc;
            #pragma unroll
            for (int nt = 0; nt < 4; ++nt) {
                const float vv = acc[mt][nt][j];
                dst[nt*16 + fr] = vv;
                if (vv > THRESH) {
                    const int s = atomicAdd(&rowcnt[lr], 1);   // LDS atomic
                    if (s < SLOTS)
                        slot_iv[((size_t)r * NBLKN + blkn) * SLOTS + s] =
                            make_int2(bn + wc + nt*16 + fr, __float_as_int(vv));
                }
            }
        }

    // zero the z tile (coalesced float4: 128 rows x 32 float4)
    #pragma unroll
    for (int u = 0; u < 16; ++u) {
        const int idx = u * 256 + tid;
        const int lr = idx >> 5;
        const int lc = (idx & 31) * 4;
        *(float4*)(z + (size_t)(bm + lr) * NLAT + bn + lc) = make_float4(0.f, 0.f, 0.f, 0.f);
    }

    __syncthreads();
    if (tid < GBM) cnt_blk[(size_t)blkn * BATCH + bm + tid] = rowcnt[tid];
}

// ---------------------------------------------------------------------------
// classify v2: gather candidates from slots (block-column order), histogram,
// boundary bin, sure/amb split; emit compacted cand lists for refine/finalize.
// ---------------------------------------------------------------------------
__global__ __launch_bounds__(256) void classify_kernel(const int* __restrict__ cnt_blk,
                                                       const int2* __restrict__ slot_iv,
                                                       int* __restrict__ cand_idx,
                                                       float* __restrict__ cand_val,
                                                       unsigned char* __restrict__ keep_ws,
                                                       int* __restrict__ ambslot_ws,
                                                       int* __restrict__ namb_ws,
                                                       int* __restrict__ nsure_ws,
                                                       int* __restrict__ flag_ws)
{
    __shared__ int ccnt[NBLKN];
    __shared__ int cofs[NBLKN];
    __shared__ float cv[CAND_MAX];
    __shared__ int   ci[CAND_MAX];
    __shared__ unsigned hist[256];
    __shared__ int b_sh, nsure_sh, namb_sh, of_sh, tot_sh;

    const int r = blockIdx.x;
    const int tid = threadIdx.x;

    if (tid == 0) { nsure_sh = 0; namb_sh = 0; }
    hist[tid] = 0u;
    if (tid < NBLKN) ccnt[tid] = cnt_blk[(size_t)tid * BATCH + r];
    __syncthreads();

    if (tid == 0) {
        int run = 0, of = 0;
        for (int b = 0; b < NBLKN; ++b) {
            if (ccnt[b] > SLOTS) of = 1;
            cofs[b] = run;
            run += ccnt[b];
        }
        tot_sh = run; of_sh = of;
    }
    __syncthreads();

    const int cnt = tot_sh;
    if (of_sh || cnt < K_TOP || cnt > CAND_MAX) {
        if (tid == 0) { flag_ws[r] = 1; namb_ws[r] = 0; nsure_ws[r] = 0; }
        return;
    }

    // gather slots -> compacted LDS lists (index order within each block-col)
    if (tid < NBLKN) {
        const int c = ccnt[tid];
        const int2* sp = slot_iv + ((size_t)r * NBLKN + tid) * SLOTS;
        const int o = cofs[tid];
        for (int e = 0; e < c; ++e) {
            const int2 iv = sp[e];
            ci[o + e] = iv.x;
            cv[o + e] = __int_as_float(iv.y);
        }
    }
    __syncthreads();

    for (int q = tid; q < cnt; q += 256) {
        int b = (int)(__float_as_uint(cv[q]) >> 16) - 16288;
        b = b < 0 ? 0 : (b > 255 ? 255 : b);
        atomicAdd(&hist[b], 1u);
    }
    __syncthreads();
    if (tid == 0) {
        int acc = 0, b = 255;
        for (; b >= 0; --b) {
            const int nb = acc + (int)hist[b];
            if (nb >= K_TOP) break;
            acc = nb;
        }
        b_sh = b;
    }
    __syncthreads();

    const int bstar = b_sh;
    const float hi = binedge(bstar + 1) + DELTA;
    const float lo = binedge(bstar) - DELTA;
    if (bstar >= 255 || bstar < 0 || lo <= THRESH + 1e-3f) {
        if (tid == 0) { flag_ws[r] = 1; namb_ws[r] = 0; nsure_ws[r] = 0; }
        return;
    }

    for (int t = tid; t < cnt; t += 256) {
        const float vt = cv[t];
        unsigned char k = 0;
        if (vt > hi) { k = 1; atomicAdd(&nsure_sh, 1); }
        else if (vt >= lo) {
            const int p = atomicAdd(&namb_sh, 1);
            if (p < MAXAMB) ambslot_ws[(size_t)r*MAXAMB + p] = t;
        }
        keep_ws[(size_t)r*CAND_MAX + t] = k;
        cand_idx[(size_t)r*CAND_MAX + t] = ci[t];
        cand_val[(size_t)r*CAND_MAX + t] = cv[t];
    }
    __syncthreads();

    if (tid == 0) {
        const int namb = namb_sh, nsure = nsure_sh;
        namb_ws[r] = namb < MAXAMB ? namb : MAXAMB;
        nsure_ws[r] = nsure;
        flag_ws[r] = (namb > MAXAMB || nsure >= K_TOP) ? 1 : 0;
    }
}

// ---------------------------------------------------------------------------
// Stage 3: flat refine — exact f64 dots for ambiguous candidates.
// ---------------------------------------------------------------------------
__global__ __launch_bounds__(256) void refine_kernel(const int* __restrict__ flag_ws,
                                                     const int* __restrict__ namb_ws,
                                                     const int* __restrict__ ambslot_ws,
                                                     const int* __restrict__ cand_idx,
                                                     const float* __restrict__ x,
                                                     const float* __restrict__ W_enc,
                                                     const float* __restrict__ bpre,
                                                     double* __restrict__ dval_ws)
{
    const int r = blockIdx.x;
    if (flag_ws[r]) return;
    const int namb = namb_ws[r];
    const int tid = threadIdx.x;
    const int lane = tid & 63, w = tid >> 6;
    const float* xrow = x + (size_t)r * D_IN;

    for (int q = w; q < namb; q += 4) {
        const int t = ambslot_ws[(size_t)r*MAXAMB + q];
        const int j = cand_idx[(size_t)r*CAND_MAX + t];
        const float* wrow = W_enc + (size_t)j * D_IN;
        double a = 0.0;
        #pragma unroll
        for (int k = lane; k < D_IN; k += 64)
            a = fma((double)xrow[k] - (double)bpre[k], (double)wrow[k], a);
        #pragma unroll
        for (int off = 32; off; off >>= 1) a += __shfl_down(a, off, 64);
        if (lane == 0) dval_ws[(size_t)r*MAXAMB + q] = a;
    }
}

// ---------------------------------------------------------------------------
// Stage 4: finalize — rank ambiguous by (f64 desc, idx asc), compact the 64
// keepers, index-order, write ws lists + 64 scattered z values.
// ---------------------------------------------------------------------------
__global__ __launch_bounds__(256) void finalize_kernel(const int* __restrict__ cnt_unused,
                                                       const int* __restrict__ cand_idx,
                                                       const float* __restrict__ cand_val,
                                                       unsigned char* __restrict__ keep_ws,
                                                       const int* __restrict__ ambslot_ws,
                                                       const int* __restrict__ namb_ws,
                                                       const int* __restrict__ nsure_ws,
                                                       const double* __restrict__ dval_ws,
                                                       const int* __restrict__ cntrow_ws,
                                                       float* __restrict__ z,
                                                       int* __restrict__ idx_ws,
                                                       float* __restrict__ val_ws,
                                                       int* __restrict__ flag_ws)
{
    __shared__ unsigned char keep[CAND_MAX];
    __shared__ double dv_sh[MAXAMB];
    __shared__ int    as_sh[MAXAMB];
    __shared__ int    ai_sh[MAXAMB];
    __shared__ int    t_idx[K_TOP + 8];
    __shared__ float  t_val[K_TOP + 8];
    __shared__ int nk_sh;

    const int r = blockIdx.x;
    if (flag_ws[r]) return;
    const int tid = threadIdx.x;
    const int cnt = cntrow_ws[r];
    const int namb = namb_ws[r];
    const int nkeep_amb = K_TOP - nsure_ws[r];

    if (tid == 0) nk_sh = 0;
    for (int t = tid; t < cnt; t += 256) keep[t] = keep_ws[(size_t)r*CAND_MAX + t];
    for (int q = tid; q < namb; q += 256) {
        const int t = ambslot_ws[(size_t)r*MAXAMB + q];
        as_sh[q] = t;
        ai_sh[q] = cand_idx[(size_t)r*CAND_MAX + t];
        dv_sh[q] = dval_ws[(size_t)r*MAXAMB + q];
    }
    __syncthreads();

    for (int t = tid; t < namb; t += 256) {
        const double dv = dv_sh[t];
        const int it = ai_sh[t];
        int rk = 0;
        for (int q = 0; q < namb; ++q)
            rk += (dv_sh[q] > dv) || (dv_sh[q] == dv && ai_sh[q] < it);
        if (rk < nkeep_amb) keep[as_sh[t]] = 1;
    }
    __syncthreads();

    for (int t = tid; t < cnt; t += 256) {
        if (keep[t]) {
            const int p = atomicAdd(&nk_sh, 1);
            if (p < K_TOP + 8) {
                t_idx[p] = cand_idx[(size_t)r*CAND_MAX + t];
                t_val[p] = cand_val[(size_t)r*CAND_MAX + t];
            }
        }
    }
    __syncthreads();
    if (nk_sh != K_TOP) { if (tid == 0) flag_ws[r] = 1; return; }

    if (tid < K_TOP) {
        const int it = t_idx[tid];
        int pos = 0;
        #pragma unroll 8
        for (int s = 0; s < K_TOP; ++s) pos += (t_idx[s] < it);
        idx_ws[r * K_TOP + pos] = it;
        val_ws[r * K_TOP + pos] = t_val[tid];
        z[(size_t)r * NLAT + it] = t_val[tid];   // scatter over zeroed row
    }
}

// ---------------------------------------------------------------------------
// Row total count helper: classify needs per-row totals for finalize; compute
// them once here (tiny kernel, 1 wave per 64 rows).
// ---------------------------------------------------------------------------
__global__ __launch_bounds__(256) void rowtotal_kernel(const int* __restrict__ cnt_blk,
                                                       int* __restrict__ cntrow_ws)
{
    const int r = blockIdx.x * 256 + threadIdx.x;
    if (r >= BATCH) return;
    int s = 0;
    for (int b = 0; b < NBLKN; ++b) s += cnt_blk[(size_t)b * BATCH + r];
    cntrow_ws[r] = s;
}

// ---------------------------------------------------------------------------
// Fallback full-row top-k (r3-verified).  Only flagged rows (or all if null).
// ---------------------------------------------------------------------------
__global__ __launch_bounds__(1024) void topk_fallback(const float* __restrict__ z_pre,
                                                      float* __restrict__ z,
                                                      const float* __restrict__ x,
                                                      const float* __restrict__ W_enc,
                                                      const float* __restrict__ bpre,
                                                      int* __restrict__ idx_ws,
                                                      float* __restrict__ val_ws,
                                                      const int* __restrict__ flag_ws)
{
    if (flag_ws != nullptr && flag_ws[blockIdx.x] == 0) return;

    __shared__ unsigned hist_w[16][257];
    __shared__ unsigned hist[256];
    __shared__ unsigned sh_prefix;
    __shared__ int sh_rem;
    __shared__ int cntA;
    __shared__ int nsure_sh;
    __shared__ int idxA[MAXA];
    __shared__ double dvalA[MAXA];
    __shared__ unsigned char keepA[MAXA];
    __shared__ int wcnt[16][24];

    const int r = blockIdx.x;
    const int tid = threadIdx.x;
    const int lane = tid & 63;
    const int w = tid >> 6;
    const unsigned long long lt = (1ull << lane) - 1ull;

    const float* src = z_pre + (size_t)r * NLAT;
    float v[24];
    #pragma unroll
    for (int c = 0; c < 24; ++c) v[c] = src[c*1024 + tid];

    if (tid == 0) { sh_prefix = 0u; sh_rem = K_TOP; cntA = 0; nsure_sh = 0; }
    if (idx_ws != nullptr && tid < K_TOP) {
        idx_ws[r*K_TOP + tid] = 0; val_ws[r*K_TOP + tid] = 0.0f;
    }

    for (int lvl = 0; lvl < 4; ++lvl) {
        const int shift = 24 - 8*lvl;
        for (int i = tid; i < 16*257; i += 1024) ((unsigned*)hist_w)[i] = 0u;
        __syncthreads();
        const unsigned pfx = sh_prefix;
        #pragma unroll
        for (int c = 0; c < 24; ++c) {
            const unsigned key = f2key(v[c]);
            const bool match = (lvl == 0) || ((key >> (shift + 8)) == (pfx >> (shift + 8)));
            if (match) atomicAdd(&hist_w[w][(key >> shift) & 255u], 1u);
        }
        __syncthreads();
        if (tid < 256) {
            unsigned s = 0;
            #pragma unroll
            for (int q = 0; q < 16; ++q) s += hist_w[q][tid];
            hist[tid] = s;
        }
        __syncthreads();
        if (tid == 0) {
            int rem = sh_rem, acc = 0, b = 255;
            for (; b >= 0; --b) {
                const int nb = acc + (int)hist[b];
                if (nb >= rem) { sh_rem = rem - acc; break; }
                acc = nb;
            }
            sh_prefix = pfx | ((unsigned)b << shift);
        }
        __syncthreads();
    }

    const float vT = key2f(sh_prefix);
    const float thr_lo = vT - DELTA, thr_hi = vT + DELTA;

    int wsure = 0;
    #pragma unroll
    for (int c = 0; c < 24; ++c) {
        const float val = v[c];
        const unsigned long long m = __ballot(val > thr_hi);
        if (lane == 0) wsure += (int)__popcll(m);
        if (val <= thr_hi && val >= thr_lo) {
            const int p = atomicAdd(&cntA, 1);
            if (p < MAXA) idxA[p] = c*1024 + tid;
        }
    }
    if (lane == 0 && wsure) atomicAdd(&nsure_sh, (unsigned)wsure);
    __syncthreads();

    const int nA = cntA < MAXA ? cntA : MAXA;
    const int nkeepA = K_TOP - nsure_sh;

    for (int q = w; q < nA; q += 16) {
        const int j = idxA[q];
        const float* wrow = W_enc + (size_t)j * D_IN;
        const float* xrow = x + (size_t)r * D_IN;
        double a = 0.0;
        for (int k = lane; k < D_IN; k += 64)
            a = fma((double)xrow[k] - (double)bpre[k], (double)wrow[k], a);
        #pragma unroll
        for (int off = 32; off; off >>= 1) a += __shfl_down(a, off, 64);
        if (lane == 0) dvalA[q] = a;
    }
    __syncthreads();

    for (int t = tid; t < nA; t += 1024) {
        const double dv = dvalA[t];
        const int ix = idxA[t];
        int rank = 0;
        for (int q = 0; q < nA; ++q)
            rank += (dvalA[q] > dv) || (dvalA[q] == dv && idxA[q] < ix);
        keepA[t] = (rank < nkeepA) ? 1 : 0;
    }
    __syncthreads();

    bool kp[24];
    #pragma unroll
    for (int c = 0; c < 24; ++c) {
        const float val = v[c];
        bool k = (val > thr_hi);
        if (!k && val >= thr_lo) {
            const int i = c*1024 + tid;
            for (int q = 0; q < nA; ++q)
                if (idxA[q] == i) { k = (keepA[q] != 0); break; }
        }
        kp[c] = k;
        const unsigned long long m = __ballot(k);
        if (lane == 0) wcnt[w][c] = (int)__popcll(m);
    }
    __syncthreads();
    if (tid == 0) {
        int run = 0;
        for (int c = 0; c < 24; ++c)
            #pragma unroll
            for (int q = 0; q < 16; ++q) { const int t = wcnt[q][c]; wcnt[q][c] = run; run += t; }
    }
    __syncthreads();

    float* zdst = z + (size_t)r * NLAT;
    #pragma unroll
    for (int c = 0; c < 24; ++c) {
        const unsigned long long m = __ballot(kp[c]);
        const int pos = wcnt[w][c] + (int)__popcll(m & lt);
        const int i = c*1024 + tid;
        zdst[i] = kp[c] ? v[c] : 0.0f;
        if (kp[c] && idx_ws != nullptr && pos < K_TOP) {
            idx_ws[r*K_TOP + pos] = i;
            val_ws[r*K_TOP + pos] = v[c];
        }
    }
}

// ---------------------------------------------------------------------------
// Fallback GEMM with in-kernel split-2 (r5-verified) for small ws.
// ---------------------------------------------------------------------------
#define FBK 32
#define FLROW (FBK + 8)

__global__ __launch_bounds__(256) void enc_gemm_mfma(const float* __restrict__ x,
                                                     const float* __restrict__ W,
                                                     const float* __restrict__ bpre,
                                                     float* __restrict__ z_pre)
{
    __shared__ unsigned short Ah[GBM][FLROW], Al[GBM][FLROW];
    __shared__ unsigned short Bh[GBN][FLROW], Bl[GBN][FLROW];

    const int tid = threadIdx.x;
    const int bm = blockIdx.y * GBM;
    const int bn = blockIdx.x * GBN;
    const int lane = tid & 63;
    const int wv = tid >> 6;
    const int wr = (wv >> 1) * 64;
    const int wc = (wv & 1) * 64;
    const int fr = lane & 15;
    const int fg = lane >> 4;

    const int srow = tid >> 3;
    const int sk   = (tid & 7) * 4;

    f32x4 acc[4][4];
    #pragma unroll
    for (int i = 0; i < 4; ++i)
        #pragma unroll
        for (int j = 0; j < 4; ++j)
            #pragma unroll
            for (int e = 0; e < 4; ++e) acc[i][j][e] = 0.0f;

    for (int k0 = 0; k0 < D_IN; k0 += FBK) {
        float4 xa[4], wb[4];
        const float4 bp = *(const float4*)(bpre + k0 + sk);
        #pragma unroll
        for (int p = 0; p < 4; ++p) {
            xa[p] = *(const float4*)(x + (size_t)(bm + srow + 32*p) * D_IN + k0 + sk);
            wb[p] = *(const float4*)(W + (size_t)(bn + srow + 32*p) * D_IN + k0 + sk);
        }
        __syncthreads();
        #pragma unroll
        for (int p = 0; p < 4; ++p) {
            const float a0 = xa[p].x - bp.x, a1 = xa[p].y - bp.y,
                        a2 = xa[p].z - bp.z, a3 = xa[p].w - bp.w;
            const unsigned short h0 = bf16hi(a0), h1 = bf16hi(a1),
                                 h2 = bf16hi(a2), h3 = bf16hi(a3);
            *(ushort4*)&Ah[srow + 32*p][sk] = make_ushort4(h0, h1, h2, h3);
            *(ushort4*)&Al[srow + 32*p][sk] = make_ushort4(
                bf16hi(a0 - bf2f(h0)), bf16hi(a1 - bf2f(h1)),
                bf16hi(a2 - bf2f(h2)), bf16hi(a3 - bf2f(h3)));
            const float b0 = wb[p].x, b1 = wb[p].y, b2 = wb[p].z, b3 = wb[p].w;
            const unsigned short g0 = bf16hi(b0), g1 = bf16hi(b1),
                                 g2 = bf16hi(b2), g3 = bf16hi(b3);
            *(ushort4*)&Bh[srow + 32*p][sk] = make_ushort4(g0, g1, g2, g3);
            *(ushort4*)&Bl[srow + 32*p][sk] = make_ushort4(
                bf16hi(b0 - bf2f(g0)), bf16hi(b1 - bf2f(g1)),
                bf16hi(b2 - bf2f(g2)), bf16hi(b3 - bf2f(g3)));
        }
        __syncthreads();

        short8 ah[4], al[4], bh[4], bl[4];
        #pragma unroll
        for (int t = 0; t < 4; ++t) {
            ah[t] = *(const short8*)&Ah[wr + t*16 + fr][fg * 8];
            al[t] = *(const short8*)&Al[wr + t*16 + fr][fg * 8];
            bh[t] = *(const short8*)&Bh[wc + t*16 + fr][fg * 8];
            bl[t] = *(const short8*)&Bl[wc + t*16 + fr][fg * 8];
        }
        #pragma unroll
        for (int mt = 0; mt < 4; ++mt)
            #pragma unroll
            for (int nt = 0; nt < 4; ++nt) {
                acc[mt][nt] = __builtin_amdgcn_mfma_f32_16x16x32_bf16(ah[mt], bh[nt], acc[mt][nt], 0, 0, 0);
                acc[mt][nt] = __builtin_amdgcn_mfma_f32_16x16x32_bf16(ah[mt], bl[nt], acc[mt][nt], 0, 0, 0);
                acc[mt][nt] = __builtin_amdgcn_mfma_f32_16x16x32_bf16(al[mt], bh[nt], acc[mt][nt], 0, 0, 0);
            }
    }

    #pragma unroll
    for (int mt = 0; mt < 4; ++mt)
        #pragma unroll
        for (int j = 0; j < 4; ++j) {
            const int r = bm + wr + mt*16 + fg*4 + j;
            float* dst = z_pre + (size_t)r * NLAT + bn + wc;
            #pragma unroll
            for (int nt = 0; nt < 4; ++nt)
                dst[nt*16 + fr] = acc[mt][nt][j];
        }
}

// ---------------------------------------------------------------------------
// Sparse decoder, bf16 W_dec (error ~2e-3 rms, well within budget).
// ---------------------------------------------------------------------------
__global__ __launch_bounds__(256) void dec_kernel(const int* __restrict__ idx_ws,
                                                  const float* __restrict__ val_ws,
                                                  const unsigned short* __restrict__ wdh,
                                                  const float* __restrict__ bpre,
                                                  const float* __restrict__ x,
                                                  float* __restrict__ x_hat,
                                                  float* __restrict__ recon)
{
    __shared__ int sidx[K_TOP];
    __shared__ float sval[K_TOP];
    const int r = blockIdx.x;
    const int tid = threadIdx.x;
    if (tid < K_TOP) {
        sidx[tid] = idx_ws[r*K_TOP + tid];
        sval[tid] = val_ws[r*K_TOP + tid];
    }
    __syncthreads();

    float a0 = bpre[tid], a1 = bpre[tid + 256], a2 = bpre[tid + 512];
    #pragma unroll 4
    for (int j = 0; j < K_TOP; ++j) {
        const float vv = sval[j];
        const unsigned short* wr_ = wdh + (size_t)sidx[j] * D_IN;
        a0 = fmaf(vv, bf2f(wr_[tid]),       a0);
        a1 = fmaf(vv, bf2f(wr_[tid + 256]), a1);
        a2 = fmaf(vv, bf2f(wr_[tid + 512]), a2);
    }
    const size_t o = (size_t)r * D_IN + tid;
    x_hat[o]       = a0;
    x_hat[o + 256] = a1;
    x_hat[o + 512] = a2;
    recon[o]       = x[o]       - a0;
    recon[o + 256] = x[o + 256] - a1;
    recon[o + 512] = x[o + 512] - a2;
}

__global__ __launch_bounds__(256) void dec_scan_kernel(const float* __restrict__ z,
                                                       const float* __restrict__ W_dec,
                                                       const float* __restrict__ bpre,
                                                       const float* __restrict__ x,
                                                       float* __restrict__ x_hat,
                                                       float* __restrict__ recon)
{
    __shared__ int sidx[K_TOP];
    __shared__ float sval[K_TOP];
    __shared__ int wcnt[4];
    __shared__ int base;
    const int r = blockIdx.x;
    const int tid = threadIdx.x;
    const int lane = tid & 63, w = tid >> 6;
    if (tid == 0) base = 0;
    __syncthreads();
    const float* zrow = z + (size_t)r * NLAT;
    for (int c = 0; c < NLAT; c += 256) {
        const float vv = zrow[c + tid];
        const bool nz = (vv != 0.0f);
        const unsigned long long m = __ballot(nz);
        if (lane == 0) wcnt[w] = __popcll(m);
        __syncthreads();
        int b = base;
        for (int j = 0; j < w; ++j) b += wcnt[j];
        const int pos = b + __popcll(m & ((1ull << lane) - 1ull));
        if (nz && pos < K_TOP) { sidx[pos] = c + tid; sval[pos] = vv; }
        __syncthreads();
        if (tid == 0) { int s = 0; for (int j = 0; j < 4; ++j) s += wcnt[j]; base += s; }
        __syncthreads();
    }
    const int n = base > K_TOP ? K_TOP : base;

    float a0 = bpre[tid], a1 = bpre[tid + 256], a2 = bpre[tid + 512];
    for (int j = 0; j < n; ++j) {
        const float vv = sval[j];
        const float* wr_ = W_dec + (size_t)sidx[j] * D_IN;
        a0 = fmaf(vv, wr_[tid],       a0);
        a1 = fmaf(vv, wr_[tid + 256], a1);
        a2 = fmaf(vv, wr_[tid + 512], a2);
    }
    const size_t o = (size_t)r * D_IN + tid;
    x_hat[o]       = a0;
    x_hat[o + 256] = a1;
    x_hat[o + 512] = a2;
    recon[o]       = x[o]       - a0;
    recon[o + 256] = x[o + 256] - a1;
    recon[o + 512] = x[o + 512] - a2;
}

// ---------------------------------------------------------------------------
extern "C" void kernel_launch(void* const* d_in, const int* in_sizes, int n_in,
                              void* d_out, int out_size, void* d_ws, size_t ws_size,
                              hipStream_t stream)
{
    const float* x     = (const float*)d_in[0];
    const float* W_enc = (const float*)d_in[1];
    const float* W_dec = (const float*)d_in[2];
    const float* bpre  = (const float*)d_in[3];

    float* out   = (float*)d_out;
    float* x_hat = out;
    float* z     = x_hat + (size_t)BATCH * D_IN;
    float* z_pre = z     + (size_t)BATCH * NLAT;
    float* recon = z_pre + (size_t)BATCH * NLAT;

    // ws layout
    char* p = (char*)d_ws;
    int*    flag_ws   = (int*)p;           p += (size_t)BATCH * 4;
    int*    idx_ws    = (int*)p;           p += (size_t)BATCH * K_TOP * 4;
    float*  val_ws    = (float*)p;         p += (size_t)BATCH * K_TOP * 4;
    int*    cntrow_ws = (int*)p;           p += (size_t)BATCH * 4;
    int*    namb_ws   = (int*)p;           p += (size_t)BATCH * 4;
    int*    nsure_ws  = (int*)p;           p += (size_t)BATCH * 4;
    double* dval_ws   = (double*)p;        p += (size_t)BATCH * MAXAMB * 8;
    int*    ambslot   = (int*)p;           p += (size_t)BATCH * MAXAMB * 4;
    int*    cand_idx  = (int*)p;           p += (size_t)BATCH * CAND_MAX * 4;
    float*  cand_val  = (float*)p;         p += (size_t)BATCH * CAND_MAX * 4;
    unsigned char* keep_ws = (unsigned char*)p;  p += (size_t)BATCH * CAND_MAX;
    p = (char*)(((size_t)p + 15) & ~(size_t)15);
    int*    cnt_blk   = (int*)p;           p += (size_t)NBLKN * BATCH * 4;
    int2*   slot_iv   = (int2*)p;          p += (size_t)BATCH * NBLKN * SLOTS * 8;
    unsigned short* xh  = (unsigned short*)p;    p += (size_t)BATCH * D_IN * 2;
    unsigned short* wh  = (unsigned short*)p;    p += (size_t)NLAT * D_IN * 2;
    unsigned short* wdh = (unsigned short*)p;    p += (size_t)NLAT * D_IN * 2;
    const size_t ws_full = (size_t)(p - (char*)d_ws);
    const bool have_full = (d_ws != nullptr) && (ws_size >= ws_full);

    if (have_full) {
        conv_x_kernel<<<(BATCH * D_IN / 4) / 256, 256, 0, stream>>>(
            (const float4*)x, bpre, (ushort4*)xh);
        conv_w_kernel<<<(NLAT * D_IN / 4) / 256, 256, 0, stream>>>(
            (const float4*)W_enc, (ushort4*)wh);
        conv_w_kernel<<<(NLAT * D_IN / 4) / 256, 256, 0, stream>>>(
            (const float4*)W_dec, (ushort4*)wdh);

        enc_gemm_fused<<<NWG, 256, 0, stream>>>(xh, wh, z_pre, z, cnt_blk, slot_iv);

        rowtotal_kernel<<<(BATCH + 255) / 256, 256, 0, stream>>>(cnt_blk, cntrow_ws);
        classify_kernel<<<BATCH, 256, 0, stream>>>(cnt_blk, slot_iv, cand_idx, cand_val,
                                                   keep_ws, ambslot, namb_ws, nsure_ws, flag_ws);
        refine_kernel<<<BATCH, 256, 0, stream>>>(flag_ws, namb_ws, ambslot, cand_idx,
                                                 x, W_enc, bpre, dval_ws);
        finalize_kernel<<<BATCH, 256, 0, stream>>>(nullptr, cand_idx, cand_val, keep_ws,
                                                   ambslot, namb_ws, nsure_ws, dval_ws,
                                                   cntrow_ws, z, idx_ws, val_ws, flag_ws);
        topk_fallback<<<BATCH, 1024, 0, stream>>>(z_pre, z, x, W_enc, bpre,
                                                  idx_ws, val_ws, flag_ws);
        dec_kernel<<<BATCH, 256, 0, stream>>>(idx_ws, val_ws, wdh, bpre, x, x_hat, recon);
    } else {
        dim3 g1(NLAT / GBN, BATCH / GBM);
        enc_gemm_mfma<<<g1, 256, 0, stream>>>(x, W_enc, bpre, z_pre);
        topk_fallback<<<BATCH, 1024, 0, stream>>>(z_pre, z, x, W_enc, bpre,
                                                  nullptr, nullptr, nullptr);
        dec_scan_kernel<<<BATCH, 256, 0, stream>>>(z, W_dec, bpre, x, x_hat, recon);
    }
}

// Round 10
// 768.704 us; speedup vs baseline: 6.5020x; 1.0032x over previous
//
#include <hip/hip_runtime.h>

#define D_IN   768
#define NLAT   24576
#define BATCH  4096
#define K_TOP  64
#define MAXA   1024
#define DELTA  0.05f
#define THRESH 1.30f
#define CAND_MAX 512
#define MAXAMB 128
#define SLOTS  12

typedef float f32x4 __attribute__((ext_vector_type(4)));
typedef short short8 __attribute__((ext_vector_type(8)));

// ---------------------------------------------------------------------------
__device__ __forceinline__ unsigned f2key(float f) {
    unsigned u = __float_as_uint(f);
    return (u & 0x80000000u) ? ~u : (u | 0x80000000u);
}
__device__ __forceinline__ float key2f(unsigned k) {
    unsigned u = (k & 0x80000000u) ? (k & 0x7fffffffu) : ~k;
    return __uint_as_float(u);
}
__device__ __forceinline__ unsigned short bf16hi(float f) {   // RNE f32->bf16
    unsigned u = __float_as_uint(f);
    unsigned r = u + 0x7fffu + ((u >> 16) & 1u);
    return (unsigned short)(r >> 16);
}
__device__ __forceinline__ float bf2f(unsigned short h) {
    return __uint_as_float(((unsigned)h) << 16);
}
__device__ __forceinline__ float binedge(int b) {
    return __uint_as_float((unsigned)(16288 + b) << 16);   // bin 0 edge = 1.25f
}

// ---------------------------------------------------------------------------
// One-time bf16 convert passes.
// ---------------------------------------------------------------------------
__global__ __launch_bounds__(256) void conv_x_kernel(const float4* __restrict__ src,
                                                     const float* __restrict__ bpre,
                                                     ushort4* __restrict__ hi)
{
    const int f = blockIdx.x * 256 + threadIdx.x;
    float4 v = src[f];
    const float4 bp = ((const float4*)bpre)[f % (D_IN / 4)];
    ushort4 h;
    h.x = bf16hi(v.x - bp.x);
    h.y = bf16hi(v.y - bp.y);
    h.z = bf16hi(v.z - bp.z);
    h.w = bf16hi(v.w - bp.w);
    hi[f] = h;
}

__global__ __launch_bounds__(256) void conv_w_kernel(const float4* __restrict__ src,
                                                     ushort4* __restrict__ hi)
{
    const int f = blockIdx.x * 256 + threadIdx.x;
    const float4 v = src[f];
    ushort4 h;
    h.x = bf16hi(v.x); h.y = bf16hi(v.y); h.z = bf16hi(v.z); h.w = bf16hi(v.w);
    hi[f] = h;
}

// ---------------------------------------------------------------------------
// Single-bf16 encoder GEMM + fused z-zeroing + slot-based candidate
// extraction (r9-verified).
// ---------------------------------------------------------------------------
#define GBM 128
#define GBN 128
#define GBK 64
#define LROW (GBK + 8)
#define NWG  ((NLAT / GBN) * (BATCH / GBM))   // 6144
#define NBLKN (NLAT / GBN)                    // 192

__global__ __launch_bounds__(256) void enc_gemm_fused(const unsigned short* __restrict__ xh,
                                                      const unsigned short* __restrict__ wh,
                                                      float* __restrict__ z_pre,
                                                      float* __restrict__ z,
                                                      int* __restrict__ cnt_blk,   // [NBLKN][BATCH]
                                                      int2* __restrict__ slot_iv)  // [BATCH][NBLKN][SLOTS]
{
    __shared__ unsigned short Ah[GBM][LROW];
    __shared__ unsigned short Bh[GBN][LROW];
    __shared__ int rowcnt[GBM];

    const int tid = threadIdx.x;
    const int bid = blockIdx.x;
    const int swz = (bid & 7) * (NWG / 8) + (bid >> 3);
    const int bn = (swz % NBLKN) * GBN;
    const int bm = (swz / NBLKN) * GBM;
    const int blkn = bn / GBN;

    const int lane = tid & 63;
    const int wv = tid >> 6;
    const int wr = (wv >> 1) * 64;
    const int wc = (wv & 1) * 64;
    const int fr = lane & 15;
    const int fg = lane >> 4;

    int srow[4], sko[4];
    const unsigned short* pxa[4];
    const unsigned short* pwb[4];
    #pragma unroll
    for (int q = 0; q < 4; ++q) {
        const int c = q * 256 + tid;
        srow[q] = c >> 3;
        sko[q]  = (c & 7) * 8;
        pxa[q] = xh + (size_t)(bm + srow[q]) * D_IN + sko[q];
        pwb[q] = wh + (size_t)(bn + srow[q]) * D_IN + sko[q];
    }

    f32x4 acc[4][4];
    #pragma unroll
    for (int i = 0; i < 4; ++i)
        #pragma unroll
        for (int j = 0; j < 4; ++j)
            #pragma unroll
            for (int e = 0; e < 4; ++e) acc[i][j][e] = 0.0f;

    for (int k0 = 0; k0 < D_IN; k0 += GBK) {
        short8 va[4], vb[4];
        #pragma unroll
        for (int q = 0; q < 4; ++q) {
            va[q] = *(const short8*)(pxa[q] + k0);
            vb[q] = *(const short8*)(pwb[q] + k0);
        }

        __syncthreads();

        #pragma unroll
        for (int q = 0; q < 4; ++q) {
            *(short8*)&Ah[srow[q]][sko[q]] = va[q];
            *(short8*)&Bh[srow[q]][sko[q]] = vb[q];
        }

        __syncthreads();

        #pragma unroll
        for (int ks = 0; ks < 2; ++ks) {
            short8 ah[4], bh[4];
            #pragma unroll
            for (int t = 0; t < 4; ++t) {
                ah[t] = *(const short8*)&Ah[wr + t*16 + fr][ks*32 + fg*8];
                bh[t] = *(const short8*)&Bh[wc + t*16 + fr][ks*32 + fg*8];
            }
            #pragma unroll
            for (int mt = 0; mt < 4; ++mt)
                #pragma unroll
                for (int nt = 0; nt < 4; ++nt)
                    acc[mt][nt] = __builtin_amdgcn_mfma_f32_16x16x32_bf16(ah[mt], bh[nt], acc[mt][nt], 0, 0, 0);
        }
    }

    if (tid < GBM) rowcnt[tid] = 0;
    __syncthreads();

    // C/D layout: col = lane&15, row = (lane>>4)*4 + reg
    #pragma unroll
    for (int mt = 0; mt < 4; ++mt)
        #pragma unroll
        for (int j = 0; j < 4; ++j) {
            const int lr = wr + mt*16 + fg*4 + j;
            const int r  = bm + lr;
            float* dst = z_pre + (size_t)r * NLAT + bn + wc;
            #pragma unroll
            for (int nt = 0; nt < 4; ++nt) {
                const float vv = acc[mt][nt][j];
                dst[nt*16 + fr] = vv;
                if (vv > THRESH) {
                    const int s = atomicAdd(&rowcnt[lr], 1);   // LDS atomic
                    if (s < SLOTS)
                        slot_iv[((size_t)r * NBLKN + blkn) * SLOTS + s] =
                            make_int2(bn + wc + nt*16 + fr, __float_as_int(vv));
                }
            }
        }

    #pragma unroll
    for (int u = 0; u < 16; ++u) {
        const int idx = u * 256 + tid;
        const int lr = idx >> 5;
        const int lc = (idx & 31) * 4;
        *(float4*)(z + (size_t)(bm + lr) * NLAT + bn + lc) = make_float4(0.f, 0.f, 0.f, 0.f);
    }

    __syncthreads();
    if (tid < GBM) cnt_blk[(size_t)blkn * BATCH + bm + tid] = rowcnt[tid];
}

// ---------------------------------------------------------------------------
// Merged select: classify + f64 refine + finalize, one block per row.
// All candidate state stays in LDS; outputs idx/val lists + scattered z.
// ---------------------------------------------------------------------------
__global__ __launch_bounds__(256) void select_kernel(const int* __restrict__ cnt_blk,
                                                     const int2* __restrict__ slot_iv,
                                                     const float* __restrict__ x,
                                                     const float* __restrict__ W_enc,
                                                     const float* __restrict__ bpre,
                                                     float* __restrict__ z,
                                                     int* __restrict__ idx_ws,
                                                     float* __restrict__ val_ws,
                                                     int* __restrict__ flag_ws)
{
    __shared__ int ccnt[NBLKN];
    __shared__ int cofs[NBLKN];
    __shared__ float cv[CAND_MAX];
    __shared__ int   ci[CAND_MAX];
    __shared__ unsigned char keep[CAND_MAX];
    __shared__ unsigned hist[256];
    __shared__ int b_sh, nsure_sh, namb_sh, of_sh, tot_sh, nk_sh;
    __shared__ int    amb_t[MAXAMB];
    __shared__ int    amb_i[MAXAMB];
    __shared__ double amb_d[MAXAMB];
    __shared__ int   t_idx[K_TOP + 8];
    __shared__ float t_val[K_TOP + 8];

    const int r = blockIdx.x;
    const int tid = threadIdx.x;

    if (tid == 0) { nsure_sh = 0; namb_sh = 0; nk_sh = 0; }
    hist[tid] = 0u;
    if (tid < NBLKN) ccnt[tid] = cnt_blk[(size_t)tid * BATCH + r];
    __syncthreads();

    if (tid == 0) {
        int run = 0, of = 0;
        for (int b = 0; b < NBLKN; ++b) {
            if (ccnt[b] > SLOTS) of = 1;
            cofs[b] = run;
            run += ccnt[b];
        }
        tot_sh = run; of_sh = of;
    }
    __syncthreads();

    const int cnt = tot_sh;
    if (of_sh || cnt < K_TOP || cnt > CAND_MAX) {
        if (tid == 0) flag_ws[r] = 1;
        return;
    }

    if (tid < NBLKN) {
        const int c = ccnt[tid];
        const int2* sp = slot_iv + ((size_t)r * NBLKN + tid) * SLOTS;
        const int o = cofs[tid];
        for (int e = 0; e < c; ++e) {
            const int2 iv = sp[e];
            ci[o + e] = iv.x;
            cv[o + e] = __int_as_float(iv.y);
        }
    }
    __syncthreads();

    for (int q = tid; q < cnt; q += 256) {
        int b = (int)(__float_as_uint(cv[q]) >> 16) - 16288;
        b = b < 0 ? 0 : (b > 255 ? 255 : b);
        atomicAdd(&hist[b], 1u);
    }
    __syncthreads();
    if (tid == 0) {
        int acc = 0, b = 255;
        for (; b >= 0; --b) {
            const int nb = acc + (int)hist[b];
            if (nb >= K_TOP) break;
            acc = nb;
        }
        b_sh = b;
    }
    __syncthreads();

    const int bstar = b_sh;
    const float hi = binedge(bstar + 1) + DELTA;
    const float lo = binedge(bstar) - DELTA;
    if (bstar >= 255 || bstar < 0 || lo <= THRESH + 1e-3f) {
        if (tid == 0) flag_ws[r] = 1;
        return;
    }

    for (int t = tid; t < cnt; t += 256) {
        const float vt = cv[t];
        unsigned char k = 0;
        if (vt > hi) { k = 1; atomicAdd(&nsure_sh, 1); }
        else if (vt >= lo) {
            const int p = atomicAdd(&namb_sh, 1);
            if (p < MAXAMB) { amb_t[p] = t; amb_i[p] = ci[t]; }
        }
        keep[t] = k;
    }
    __syncthreads();

    const int nsure = nsure_sh;
    const int namb = namb_sh;
    if (namb > MAXAMB || nsure >= K_TOP) { if (tid == 0) flag_ws[r] = 1; return; }
    const int nkeep_amb = K_TOP - nsure;

    // f64 refine (one wave per candidate, 4 waves rotating)
    const int lane = tid & 63, w = tid >> 6;
    const float* xrow = x + (size_t)r * D_IN;
    for (int q = w; q < namb; q += 4) {
        const float* wrow = W_enc + (size_t)amb_i[q] * D_IN;
        double a = 0.0;
        #pragma unroll
        for (int k = lane; k < D_IN; k += 64)
            a = fma((double)xrow[k] - (double)bpre[k], (double)wrow[k], a);
        #pragma unroll
        for (int off = 32; off; off >>= 1) a += __shfl_down(a, off, 64);
        if (lane == 0) amb_d[q] = a;
    }
    __syncthreads();

    for (int t = tid; t < namb; t += 256) {
        const double dv = amb_d[t];
        const int it = amb_i[t];
        int rk = 0;
        for (int q = 0; q < namb; ++q)
            rk += (amb_d[q] > dv) || (amb_d[q] == dv && amb_i[q] < it);
        if (rk < nkeep_amb) keep[amb_t[t]] = 1;
    }
    __syncthreads();

    for (int t = tid; t < cnt; t += 256) {
        if (keep[t]) {
            const int p = atomicAdd(&nk_sh, 1);
            if (p < K_TOP + 8) { t_idx[p] = ci[t]; t_val[p] = cv[t]; }
        }
    }
    __syncthreads();
    if (nk_sh != K_TOP) { if (tid == 0) flag_ws[r] = 1; return; }

    if (tid == 0) flag_ws[r] = 0;
    if (tid < K_TOP) {
        const int it = t_idx[tid];
        int pos = 0;
        #pragma unroll 8
        for (int s = 0; s < K_TOP; ++s) pos += (t_idx[s] < it);
        idx_ws[r * K_TOP + pos] = it;
        val_ws[r * K_TOP + pos] = t_val[tid];
        z[(size_t)r * NLAT + it] = t_val[tid];   // scatter over zeroed row
    }
}

// ---------------------------------------------------------------------------
// Fallback full-row top-k (r3-verified).  Only flagged rows (or all if null).
// ---------------------------------------------------------------------------
__global__ __launch_bounds__(1024) void topk_fallback(const float* __restrict__ z_pre,
                                                      float* __restrict__ z,
                                                      const float* __restrict__ x,
                                                      const float* __restrict__ W_enc,
                                                      const float* __restrict__ bpre,
                                                      int* __restrict__ idx_ws,
                                                      float* __restrict__ val_ws,
                                                      const int* __restrict__ flag_ws)
{
    if (flag_ws != nullptr && flag_ws[blockIdx.x] == 0) return;

    __shared__ unsigned hist_w[16][257];
    __shared__ unsigned hist[256];
    __shared__ unsigned sh_prefix;
    __shared__ int sh_rem;
    __shared__ int cntA;
    __shared__ int nsure_sh;
    __shared__ int idxA[MAXA];
    __shared__ double dvalA[MAXA];
    __shared__ unsigned char keepA[MAXA];
    __shared__ int wcnt[16][24];

    const int r = blockIdx.x;
    const int tid = threadIdx.x;
    const int lane = tid & 63;
    const int w = tid >> 6;
    const unsigned long long lt = (1ull << lane) - 1ull;

    const float* src = z_pre + (size_t)r * NLAT;
    float v[24];
    #pragma unroll
    for (int c = 0; c < 24; ++c) v[c] = src[c*1024 + tid];

    if (tid == 0) { sh_prefix = 0u; sh_rem = K_TOP; cntA = 0; nsure_sh = 0; }
    if (idx_ws != nullptr && tid < K_TOP) {
        idx_ws[r*K_TOP + tid] = 0; val_ws[r*K_TOP + tid] = 0.0f;
    }

    for (int lvl = 0; lvl < 4; ++lvl) {
        const int shift = 24 - 8*lvl;
        for (int i = tid; i < 16*257; i += 1024) ((unsigned*)hist_w)[i] = 0u;
        __syncthreads();
        const unsigned pfx = sh_prefix;
        #pragma unroll
        for (int c = 0; c < 24; ++c) {
            const unsigned key = f2key(v[c]);
            const bool match = (lvl == 0) || ((key >> (shift + 8)) == (pfx >> (shift + 8)));
            if (match) atomicAdd(&hist_w[w][(key >> shift) & 255u], 1u);
        }
        __syncthreads();
        if (tid < 256) {
            unsigned s = 0;
            #pragma unroll
            for (int q = 0; q < 16; ++q) s += hist_w[q][tid];
            hist[tid] = s;
        }
        __syncthreads();
        if (tid == 0) {
            int rem = sh_rem, acc = 0, b = 255;
            for (; b >= 0; --b) {
                const int nb = acc + (int)hist[b];
                if (nb >= rem) { sh_rem = rem - acc; break; }
                acc = nb;
            }
            sh_prefix = pfx | ((unsigned)b << shift);
        }
        __syncthreads();
    }

    const float vT = key2f(sh_prefix);
    const float thr_lo = vT - DELTA, thr_hi = vT + DELTA;

    int wsure = 0;
    #pragma unroll
    for (int c = 0; c < 24; ++c) {
        const float val = v[c];
        const unsigned long long m = __ballot(val > thr_hi);
        if (lane == 0) wsure += (int)__popcll(m);
        if (val <= thr_hi && val >= thr_lo) {
            const int p = atomicAdd(&cntA, 1);
            if (p < MAXA) idxA[p] = c*1024 + tid;
        }
    }
    if (lane == 0 && wsure) atomicAdd(&nsure_sh, (unsigned)wsure);
    __syncthreads();

    const int nA = cntA < MAXA ? cntA : MAXA;
    const int nkeepA = K_TOP - nsure_sh;

    for (int q = w; q < nA; q += 16) {
        const int j = idxA[q];
        const float* wrow = W_enc + (size_t)j * D_IN;
        const float* xrow = x + (size_t)r * D_IN;
        double a = 0.0;
        for (int k = lane; k < D_IN; k += 64)
            a = fma((double)xrow[k] - (double)bpre[k], (double)wrow[k], a);
        #pragma unroll
        for (int off = 32; off; off >>= 1) a += __shfl_down(a, off, 64);
        if (lane == 0) dvalA[q] = a;
    }
    __syncthreads();

    for (int t = tid; t < nA; t += 1024) {
        const double dv = dvalA[t];
        const int ix = idxA[t];
        int rank = 0;
        for (int q = 0; q < nA; ++q)
            rank += (dvalA[q] > dv) || (dvalA[q] == dv && idxA[q] < ix);
        keepA[t] = (rank < nkeepA) ? 1 : 0;
    }
    __syncthreads();

    bool kp[24];
    #pragma unroll
    for (int c = 0; c < 24; ++c) {
        const float val = v[c];
        bool k = (val > thr_hi);
        if (!k && val >= thr_lo) {
            const int i = c*1024 + tid;
            for (int q = 0; q < nA; ++q)
                if (idxA[q] == i) { k = (keepA[q] != 0); break; }
        }
        kp[c] = k;
        const unsigned long long m = __ballot(k);
        if (lane == 0) wcnt[w][c] = (int)__popcll(m);
    }
    __syncthreads();
    if (tid == 0) {
        int run = 0;
        for (int c = 0; c < 24; ++c)
            #pragma unroll
            for (int q = 0; q < 16; ++q) { const int t = wcnt[q][c]; wcnt[q][c] = run; run += t; }
    }
    __syncthreads();

    float* zdst = z + (size_t)r * NLAT;
    #pragma unroll
    for (int c = 0; c < 24; ++c) {
        const unsigned long long m = __ballot(kp[c]);
        const int pos = wcnt[w][c] + (int)__popcll(m & lt);
        const int i = c*1024 + tid;
        zdst[i] = kp[c] ? v[c] : 0.0f;
        if (kp[c] && idx_ws != nullptr && pos < K_TOP) {
            idx_ws[r*K_TOP + pos] = i;
            val_ws[r*K_TOP + pos] = v[c];
        }
    }
}

// ---------------------------------------------------------------------------
// Fallback GEMM with in-kernel split-2 (r5-verified) for small ws.
// ---------------------------------------------------------------------------
#define FBK 32
#define FLROW (FBK + 8)

__global__ __launch_bounds__(256) void enc_gemm_mfma(const float* __restrict__ x,
                                                     const float* __restrict__ W,
                                                     const float* __restrict__ bpre,
                                                     float* __restrict__ z_pre)
{
    __shared__ unsigned short Ah[GBM][FLROW], Al[GBM][FLROW];
    __shared__ unsigned short Bh[GBN][FLROW], Bl[GBN][FLROW];

    const int tid = threadIdx.x;
    const int bm = blockIdx.y * GBM;
    const int bn = blockIdx.x * GBN;
    const int lane = tid & 63;
    const int wv = tid >> 6;
    const int wr = (wv >> 1) * 64;
    const int wc = (wv & 1) * 64;
    const int fr = lane & 15;
    const int fg = lane >> 4;

    const int srow = tid >> 3;
    const int sk   = (tid & 7) * 4;

    f32x4 acc[4][4];
    #pragma unroll
    for (int i = 0; i < 4; ++i)
        #pragma unroll
        for (int j = 0; j < 4; ++j)
            #pragma unroll
            for (int e = 0; e < 4; ++e) acc[i][j][e] = 0.0f;

    for (int k0 = 0; k0 < D_IN; k0 += FBK) {
        float4 xa[4], wb[4];
        const float4 bp = *(const float4*)(bpre + k0 + sk);
        #pragma unroll
        for (int p = 0; p < 4; ++p) {
            xa[p] = *(const float4*)(x + (size_t)(bm + srow + 32*p) * D_IN + k0 + sk);
            wb[p] = *(const float4*)(W + (size_t)(bn + srow + 32*p) * D_IN + k0 + sk);
        }
        __syncthreads();
        #pragma unroll
        for (int p = 0; p < 4; ++p) {
            const float a0 = xa[p].x - bp.x, a1 = xa[p].y - bp.y,
                        a2 = xa[p].z - bp.z, a3 = xa[p].w - bp.w;
            const unsigned short h0 = bf16hi(a0), h1 = bf16hi(a1),
                                 h2 = bf16hi(a2), h3 = bf16hi(a3);
            *(ushort4*)&Ah[srow + 32*p][sk] = make_ushort4(h0, h1, h2, h3);
            *(ushort4*)&Al[srow + 32*p][sk] = make_ushort4(
                bf16hi(a0 - bf2f(h0)), bf16hi(a1 - bf2f(h1)),
                bf16hi(a2 - bf2f(h2)), bf16hi(a3 - bf2f(h3)));
            const float b0 = wb[p].x, b1 = wb[p].y, b2 = wb[p].z, b3 = wb[p].w;
            const unsigned short g0 = bf16hi(b0), g1 = bf16hi(b1),
                                 g2 = bf16hi(b2), g3 = bf16hi(b3);
            *(ushort4*)&Bh[srow + 32*p][sk] = make_ushort4(g0, g1, g2, g3);
            *(ushort4*)&Bl[srow + 32*p][sk] = make_ushort4(
                bf16hi(b0 - bf2f(g0)), bf16hi(b1 - bf2f(g1)),
                bf16hi(b2 - bf2f(g2)), bf16hi(b3 - bf2f(g3)));
        }
        __syncthreads();

        short8 ah[4], al[4], bh[4], bl[4];
        #pragma unroll
        for (int t = 0; t < 4; ++t) {
            ah[t] = *(const short8*)&Ah[wr + t*16 + fr][fg * 8];
            al[t] = *(const short8*)&Al[wr + t*16 + fr][fg * 8];
            bh[t] = *(const short8*)&Bh[wc + t*16 + fr][fg * 8];
            bl[t] = *(const short8*)&Bl[wc + t*16 + fr][fg * 8];
        }
        #pragma unroll
        for (int mt = 0; mt < 4; ++mt)
            #pragma unroll
            for (int nt = 0; nt < 4; ++nt) {
                acc[mt][nt] = __builtin_amdgcn_mfma_f32_16x16x32_bf16(ah[mt], bh[nt], acc[mt][nt], 0, 0, 0);
                acc[mt][nt] = __builtin_amdgcn_mfma_f32_16x16x32_bf16(ah[mt], bl[nt], acc[mt][nt], 0, 0, 0);
                acc[mt][nt] = __builtin_amdgcn_mfma_f32_16x16x32_bf16(al[mt], bh[nt], acc[mt][nt], 0, 0, 0);
            }
    }

    #pragma unroll
    for (int mt = 0; mt < 4; ++mt)
        #pragma unroll
        for (int j = 0; j < 4; ++j) {
            const int r = bm + wr + mt*16 + fg*4 + j;
            float* dst = z_pre + (size_t)r * NLAT + bn + wc;
            #pragma unroll
            for (int nt = 0; nt < 4; ++nt)
                dst[nt*16 + fr] = acc[mt][nt][j];
        }
}

// ---------------------------------------------------------------------------
// Sparse decoder v2: bf16 W_dec, thread t<192 owns 4 contiguous dims
// (ushort4 gather = 8B/lane coalesced; float4 stores).
// ---------------------------------------------------------------------------
__global__ __launch_bounds__(256) void dec_kernel(const int* __restrict__ idx_ws,
                                                  const float* __restrict__ val_ws,
                                                  const unsigned short* __restrict__ wdh,
                                                  const float* __restrict__ bpre,
                                                  const float* __restrict__ x,
                                                  float* __restrict__ x_hat,
                                                  float* __restrict__ recon)
{
    __shared__ int sidx[K_TOP];
    __shared__ float sval[K_TOP];
    const int r = blockIdx.x;
    const int tid = threadIdx.x;
    if (tid < K_TOP) {
        sidx[tid] = idx_ws[r*K_TOP + tid];
        sval[tid] = val_ws[r*K_TOP + tid];
    }
    __syncthreads();

    if (tid < D_IN / 4) {
        const int d0 = tid * 4;
        const float4 bp = *(const float4*)(bpre + d0);
        float a0 = bp.x, a1 = bp.y, a2 = bp.z, a3 = bp.w;
        #pragma unroll 8
        for (int j = 0; j < K_TOP; ++j) {
            const float vv = sval[j];
            const ushort4 w4 = *(const ushort4*)(wdh + (size_t)sidx[j] * D_IN + d0);
            a0 = fmaf(vv, bf2f(w4.x), a0);
            a1 = fmaf(vv, bf2f(w4.y), a1);
            a2 = fmaf(vv, bf2f(w4.z), a2);
            a3 = fmaf(vv, bf2f(w4.w), a3);
        }
        const size_t o = (size_t)r * D_IN + d0;
        const float4 xv = *(const float4*)(x + o);
        *(float4*)(x_hat + o) = make_float4(a0, a1, a2, a3);
        *(float4*)(recon + o) = make_float4(xv.x - a0, xv.y - a1, xv.z - a2, xv.w - a3);
    }
}

__global__ __launch_bounds__(256) void dec_scan_kernel(const float* __restrict__ z,
                                                       const float* __restrict__ W_dec,
                                                       const float* __restrict__ bpre,
                                                       const float* __restrict__ x,
                                                       float* __restrict__ x_hat,
                                                       float* __restrict__ recon)
{
    __shared__ int sidx[K_TOP];
    __shared__ float sval[K_TOP];
    __shared__ int wcnt[4];
    __shared__ int base;
    const int r = blockIdx.x;
    const int tid = threadIdx.x;
    const int lane = tid & 63, w = tid >> 6;
    if (tid == 0) base = 0;
    __syncthreads();
    const float* zrow = z + (size_t)r * NLAT;
    for (int c = 0; c < NLAT; c += 256) {
        const float vv = zrow[c + tid];
        const bool nz = (vv != 0.0f);
        const unsigned long long m = __ballot(nz);
        if (lane == 0) wcnt[w] = __popcll(m);
        __syncthreads();
        int b = base;
        for (int j = 0; j < w; ++j) b += wcnt[j];
        const int pos = b + __popcll(m & ((1ull << lane) - 1ull));
        if (nz && pos < K_TOP) { sidx[pos] = c + tid; sval[pos] = vv; }
        __syncthreads();
        if (tid == 0) { int s = 0; for (int j = 0; j < 4; ++j) s += wcnt[j]; base += s; }
        __syncthreads();
    }
    const int n = base > K_TOP ? K_TOP : base;

    float a0 = bpre[tid], a1 = bpre[tid + 256], a2 = bpre[tid + 512];
    for (int j = 0; j < n; ++j) {
        const float vv = sval[j];
        const float* wr_ = W_dec + (size_t)sidx[j] * D_IN;
        a0 = fmaf(vv, wr_[tid],       a0);
        a1 = fmaf(vv, wr_[tid + 256], a1);
        a2 = fmaf(vv, wr_[tid + 512], a2);
    }
    const size_t o = (size_t)r * D_IN + tid;
    x_hat[o]       = a0;
    x_hat[o + 256] = a1;
    x_hat[o + 512] = a2;
    recon[o]       = x[o]       - a0;
    recon[o + 256] = x[o + 256] - a1;
    recon[o + 512] = x[o + 512] - a2;
}

// ---------------------------------------------------------------------------
extern "C" void kernel_launch(void* const* d_in, const int* in_sizes, int n_in,
                              void* d_out, int out_size, void* d_ws, size_t ws_size,
                              hipStream_t stream)
{
    const float* x     = (const float*)d_in[0];
    const float* W_enc = (const float*)d_in[1];
    const float* W_dec = (const float*)d_in[2];
    const float* bpre  = (const float*)d_in[3];

    float* out   = (float*)d_out;
    float* x_hat = out;
    float* z     = x_hat + (size_t)BATCH * D_IN;
    float* z_pre = z     + (size_t)BATCH * NLAT;
    float* recon = z_pre + (size_t)BATCH * NLAT;

    // ws layout
    char* p = (char*)d_ws;
    int*    flag_ws   = (int*)p;           p += (size_t)BATCH * 4;
    int*    idx_ws    = (int*)p;           p += (size_t)BATCH * K_TOP * 4;
    float*  val_ws    = (float*)p;         p += (size_t)BATCH * K_TOP * 4;
    p = (char*)(((size_t)p + 15) & ~(size_t)15);
    int*    cnt_blk   = (int*)p;           p += (size_t)NBLKN * BATCH * 4;
    int2*   slot_iv   = (int2*)p;          p += (size_t)BATCH * NBLKN * SLOTS * 8;
    unsigned short* xh  = (unsigned short*)p;    p += (size_t)BATCH * D_IN * 2;
    unsigned short* wh  = (unsigned short*)p;    p += (size_t)NLAT * D_IN * 2;
    unsigned short* wdh = (unsigned short*)p;    p += (size_t)NLAT * D_IN * 2;
    const size_t ws_full = (size_t)(p - (char*)d_ws);
    const bool have_full = (d_ws != nullptr) && (ws_size >= ws_full);

    if (have_full) {
        conv_x_kernel<<<(BATCH * D_IN / 4) / 256, 256, 0, stream>>>(
            (const float4*)x, bpre, (ushort4*)xh);
        conv_w_kernel<<<(NLAT * D_IN / 4) / 256, 256, 0, stream>>>(
            (const float4*)W_enc, (ushort4*)wh);
        conv_w_kernel<<<(NLAT * D_IN / 4) / 256, 256, 0, stream>>>(
            (const float4*)W_dec, (ushort4*)wdh);

        enc_gemm_fused<<<NWG, 256, 0, stream>>>(xh, wh, z_pre, z, cnt_blk, slot_iv);

        select_kernel<<<BATCH, 256, 0, stream>>>(cnt_blk, slot_iv, x, W_enc, bpre,
                                                 z, idx_ws, val_ws, flag_ws);
        topk_fallback<<<BATCH, 1024, 0, stream>>>(z_pre, z, x, W_enc, bpre,
                                                  idx_ws, val_ws, flag_ws);
        dec_kernel<<<BATCH, 256, 0, stream>>>(idx_ws, val_ws, wdh, bpre, x, x_hat, recon);
    } else {
        dim3 g1(NLAT / GBN, BATCH / GBM);
        enc_gemm_mfma<<<g1, 256, 0, stream>>>(x, W_enc, bpre, z_pre);
        topk_fallback<<<BATCH, 1024, 0, stream>>>(z_pre, z, x, W_enc, bpre,
                                                  nullptr, nullptr, nullptr);
        dec_scan_kernel<<<BATCH, 256, 0, stream>>>(z, W_dec, bpre, x, x_hat, recon);
    }
}

// Round 11
// 692.753 us; speedup vs baseline: 7.2149x; 1.1096x over previous
//
#include <hip/hip_runtime.h>

#define D_IN   768
#define NLAT   24576
#define BATCH  4096
#define K_TOP  64
#define MAXA   1024
#define DELTA  0.05f
#define THRESH 1.30f
#define CAND_MAX 512
#define MAXAMB 128
#define SLOTS  12

typedef float f32x4  __attribute__((ext_vector_type(4)));
typedef float f32x16 __attribute__((ext_vector_type(16)));
typedef short short8 __attribute__((ext_vector_type(8)));

// ---------------------------------------------------------------------------
__device__ __forceinline__ unsigned f2key(float f) {
    unsigned u = __float_as_uint(f);
    return (u & 0x80000000u) ? ~u : (u | 0x80000000u);
}
__device__ __forceinline__ float key2f(unsigned k) {
    unsigned u = (k & 0x80000000u) ? (k & 0x7fffffffu) : ~k;
    return __uint_as_float(u);
}
__device__ __forceinline__ unsigned short bf16hi(float f) {   // RNE f32->bf16
    unsigned u = __float_as_uint(f);
    unsigned r = u + 0x7fffu + ((u >> 16) & 1u);
    return (unsigned short)(r >> 16);
}
__device__ __forceinline__ float bf2f(unsigned short h) {
    return __uint_as_float(((unsigned)h) << 16);
}
__device__ __forceinline__ float binedge(int b) {
    return __uint_as_float((unsigned)(16288 + b) << 16);   // bin 0 edge = 1.25f
}

// ---------------------------------------------------------------------------
// One merged bf16 convert pass: x (with b_pre), W_enc, W_dec.
// ---------------------------------------------------------------------------
#define XCHUNKS (BATCH * D_IN / 4 / 256)   // 3072
#define WCHUNKS (NLAT * D_IN / 4 / 256)    // 18432

__global__ __launch_bounds__(256) void conv_all(const float4* __restrict__ x,
                                                const float* __restrict__ bpre,
                                                const float4* __restrict__ We,
                                                const float4* __restrict__ Wd,
                                                ushort4* __restrict__ xh,
                                                ushort4* __restrict__ wh,
                                                ushort4* __restrict__ wdh)
{
    const int b = blockIdx.x;
    if (b < XCHUNKS) {
        const int f = b * 256 + threadIdx.x;
        float4 v = x[f];
        const float4 bp = ((const float4*)bpre)[f % (D_IN / 4)];
        ushort4 h;
        h.x = bf16hi(v.x - bp.x);
        h.y = bf16hi(v.y - bp.y);
        h.z = bf16hi(v.z - bp.z);
        h.w = bf16hi(v.w - bp.w);
        xh[f] = h;
    } else if (b < XCHUNKS + WCHUNKS) {
        const int f = (b - XCHUNKS) * 256 + threadIdx.x;
        const float4 v = We[f];
        ushort4 h;
        h.x = bf16hi(v.x); h.y = bf16hi(v.y); h.z = bf16hi(v.z); h.w = bf16hi(v.w);
        wh[f] = h;
    } else {
        const int f = (b - XCHUNKS - WCHUNKS) * 256 + threadIdx.x;
        const float4 v = Wd[f];
        ushort4 h;
        h.x = bf16hi(v.x); h.y = bf16hi(v.y); h.z = bf16hi(v.z); h.w = bf16hi(v.w);
        wdh[f] = h;
    }
}

// ---------------------------------------------------------------------------
// bf16 encoder GEMM, 32x32x16 MFMA (higher per-instr FLOP/cy than 16x16x32),
// fused z-zeroing + slot-based candidate extraction.  Tile 128x128, BK=64.
// Wave = 64x64 via 2x2 of 32x32 frags.  C/D layout (m74/m101-verified):
// col = lane&31, row = (reg&3) + 8*(reg>>2) + 4*(lane>>5).
// ---------------------------------------------------------------------------
#define GBM 128
#define GBN 128
#define GBK 64
#define LROW (GBK + 8)
#define NWG  ((NLAT / GBN) * (BATCH / GBM))   // 6144
#define NBLKN (NLAT / GBN)                    // 192

__global__ __launch_bounds__(256) void enc_gemm_fused(const unsigned short* __restrict__ xh,
                                                      const unsigned short* __restrict__ wh,
                                                      float* __restrict__ z_pre,
                                                      float* __restrict__ z,
                                                      int* __restrict__ cnt_blk,   // [NBLKN][BATCH]
                                                      int2* __restrict__ slot_iv)  // [BATCH][NBLKN][SLOTS]
{
    __shared__ unsigned short Ah[GBM][LROW];
    __shared__ unsigned short Bh[GBN][LROW];
    __shared__ int rowcnt[GBM];

    const int tid = threadIdx.x;
    const int bid = blockIdx.x;
    const int swz = (bid & 7) * (NWG / 8) + (bid >> 3);
    const int bn = (swz % NBLKN) * GBN;
    const int bm = (swz / NBLKN) * GBM;
    const int blkn = bn / GBN;

    const int lane = tid & 63;
    const int wv = tid >> 6;
    const int wr = (wv >> 1) * 64;
    const int wc = (wv & 1) * 64;
    const int l31 = lane & 31;
    const int lh  = lane >> 5;     // k-group / row-half selector

    int srow[4], sko[4];
    const unsigned short* pxa[4];
    const unsigned short* pwb[4];
    #pragma unroll
    for (int q = 0; q < 4; ++q) {
        const int c = q * 256 + tid;
        srow[q] = c >> 3;
        sko[q]  = (c & 7) * 8;
        pxa[q] = xh + (size_t)(bm + srow[q]) * D_IN + sko[q];
        pwb[q] = wh + (size_t)(bn + srow[q]) * D_IN + sko[q];
    }

    f32x16 acc[2][2];
    #pragma unroll
    for (int i = 0; i < 2; ++i)
        #pragma unroll
        for (int j = 0; j < 2; ++j)
            #pragma unroll
            for (int e = 0; e < 16; ++e) acc[i][j][e] = 0.0f;

    for (int k0 = 0; k0 < D_IN; k0 += GBK) {
        short8 va[4], vb[4];
        #pragma unroll
        for (int q = 0; q < 4; ++q) {
            va[q] = *(const short8*)(pxa[q] + k0);
            vb[q] = *(const short8*)(pwb[q] + k0);
        }

        __syncthreads();

        #pragma unroll
        for (int q = 0; q < 4; ++q) {
            *(short8*)&Ah[srow[q]][sko[q]] = va[q];
            *(short8*)&Bh[srow[q]][sko[q]] = vb[q];
        }

        __syncthreads();

        #pragma unroll
        for (int ks = 0; ks < 4; ++ks) {
            short8 ah[2], bh[2];
            #pragma unroll
            for (int t = 0; t < 2; ++t) {
                ah[t] = *(const short8*)&Ah[wr + t*32 + l31][ks*16 + lh*8];
                bh[t] = *(const short8*)&Bh[wc + t*32 + l31][ks*16 + lh*8];
            }
            #pragma unroll
            for (int mt = 0; mt < 2; ++mt)
                #pragma unroll
                for (int nt = 0; nt < 2; ++nt)
                    acc[mt][nt] = __builtin_amdgcn_mfma_f32_32x32x16_bf16(ah[mt], bh[nt], acc[mt][nt], 0, 0, 0);
        }
    }

    if (tid < GBM) rowcnt[tid] = 0;
    __syncthreads();

    // C/D: col = lane&31, row = (reg&3) + 8*(reg>>2) + 4*(lane>>5)
    #pragma unroll
    for (int mt = 0; mt < 2; ++mt)
        #pragma unroll
        for (int nt = 0; nt < 2; ++nt) {
            const int colg = bn + wc + nt*32 + l31;
            #pragma unroll
            for (int reg = 0; reg < 16; ++reg) {
                const int lr = wr + mt*32 + (reg & 3) + 8*(reg >> 2) + 4*lh;
                const int r  = bm + lr;
                const float vv = acc[mt][nt][reg];
                z_pre[(size_t)r * NLAT + colg] = vv;
                if (vv > THRESH) {
                    const int s = atomicAdd(&rowcnt[lr], 1);   // LDS atomic
                    if (s < SLOTS)
                        slot_iv[((size_t)r * NBLKN + blkn) * SLOTS + s] =
                            make_int2(colg, __float_as_int(vv));
                }
            }
        }

    #pragma unroll
    for (int u = 0; u < 16; ++u) {
        const int idx = u * 256 + tid;
        const int lr = idx >> 5;
        const int lc = (idx & 31) * 4;
        *(float4*)(z + (size_t)(bm + lr) * NLAT + bn + lc) = make_float4(0.f, 0.f, 0.f, 0.f);
    }

    __syncthreads();
    if (tid < GBM) cnt_blk[(size_t)blkn * BATCH + bm + tid] = rowcnt[tid];
}

// ---------------------------------------------------------------------------
// Merged select: classify + f64 refine + finalize + DECODER, one block/row.
// ---------------------------------------------------------------------------
__global__ __launch_bounds__(256) void select_kernel(const int* __restrict__ cnt_blk,
                                                     const int2* __restrict__ slot_iv,
                                                     const float* __restrict__ x,
                                                     const float* __restrict__ W_enc,
                                                     const float* __restrict__ bpre,
                                                     const unsigned short* __restrict__ wdh,
                                                     float* __restrict__ z,
                                                     float* __restrict__ x_hat,
                                                     float* __restrict__ recon,
                                                     int* __restrict__ idx_ws,
                                                     float* __restrict__ val_ws,
                                                     int* __restrict__ flag_ws)
{
    __shared__ int ccnt[NBLKN];
    __shared__ int cofs[NBLKN];
    __shared__ float cv[CAND_MAX];
    __shared__ int   ci[CAND_MAX];
    __shared__ unsigned char keep[CAND_MAX];
    __shared__ unsigned hist[256];
    __shared__ int b_sh, nsure_sh, namb_sh, of_sh, tot_sh, nk_sh;
    __shared__ int    amb_t[MAXAMB];
    __shared__ int    amb_i[MAXAMB];
    __shared__ double amb_d[MAXAMB];
    __shared__ int   t_idx[K_TOP + 8];
    __shared__ float t_val[K_TOP + 8];
    __shared__ int   kidx[K_TOP];
    __shared__ float kval[K_TOP];

    const int r = blockIdx.x;
    const int tid = threadIdx.x;

    if (tid == 0) { nsure_sh = 0; namb_sh = 0; nk_sh = 0; }
    hist[tid] = 0u;
    if (tid < NBLKN) ccnt[tid] = cnt_blk[(size_t)tid * BATCH + r];
    __syncthreads();

    if (tid == 0) {
        int run = 0, of = 0;
        for (int b = 0; b < NBLKN; ++b) {
            if (ccnt[b] > SLOTS) of = 1;
            cofs[b] = run;
            run += ccnt[b];
        }
        tot_sh = run; of_sh = of;
    }
    __syncthreads();

    const int cnt = tot_sh;
    if (of_sh || cnt < K_TOP || cnt > CAND_MAX) {
        if (tid == 0) flag_ws[r] = 1;
        return;
    }

    if (tid < NBLKN) {
        const int c = ccnt[tid];
        const int2* sp = slot_iv + ((size_t)r * NBLKN + tid) * SLOTS;
        const int o = cofs[tid];
        for (int e = 0; e < c; ++e) {
            const int2 iv = sp[e];
            ci[o + e] = iv.x;
            cv[o + e] = __int_as_float(iv.y);
        }
    }
    __syncthreads();

    for (int q = tid; q < cnt; q += 256) {
        int b = (int)(__float_as_uint(cv[q]) >> 16) - 16288;
        b = b < 0 ? 0 : (b > 255 ? 255 : b);
        atomicAdd(&hist[b], 1u);
    }
    __syncthreads();
    if (tid == 0) {
        int acc = 0, b = 255;
        for (; b >= 0; --b) {
            const int nb = acc + (int)hist[b];
            if (nb >= K_TOP) break;
            acc = nb;
        }
        b_sh = b;
    }
    __syncthreads();

    const int bstar = b_sh;
    const float hi = binedge(bstar + 1) + DELTA;
    const float lo = binedge(bstar) - DELTA;
    if (bstar >= 255 || bstar < 0 || lo <= THRESH + 1e-3f) {
        if (tid == 0) flag_ws[r] = 1;
        return;
    }

    for (int t = tid; t < cnt; t += 256) {
        const float vt = cv[t];
        unsigned char k = 0;
        if (vt > hi) { k = 1; atomicAdd(&nsure_sh, 1); }
        else if (vt >= lo) {
            const int p = atomicAdd(&namb_sh, 1);
            if (p < MAXAMB) { amb_t[p] = t; amb_i[p] = ci[t]; }
        }
        keep[t] = k;
    }
    __syncthreads();

    const int nsure = nsure_sh;
    const int namb = namb_sh;
    if (namb > MAXAMB || nsure >= K_TOP) { if (tid == 0) flag_ws[r] = 1; return; }
    const int nkeep_amb = K_TOP - nsure;

    // f64 refine (one wave per candidate, 4 waves rotating)
    const int lane = tid & 63, w = tid >> 6;
    const float* xrow = x + (size_t)r * D_IN;
    for (int q = w; q < namb; q += 4) {
        const float* wrow = W_enc + (size_t)amb_i[q] * D_IN;
        double a = 0.0;
        #pragma unroll
        for (int k = lane; k < D_IN; k += 64)
            a = fma((double)xrow[k] - (double)bpre[k], (double)wrow[k], a);
        #pragma unroll
        for (int off = 32; off; off >>= 1) a += __shfl_down(a, off, 64);
        if (lane == 0) amb_d[q] = a;
    }
    __syncthreads();

    for (int t = tid; t < namb; t += 256) {
        const double dv = amb_d[t];
        const int it = amb_i[t];
        int rk = 0;
        for (int q = 0; q < namb; ++q)
            rk += (amb_d[q] > dv) || (amb_d[q] == dv && amb_i[q] < it);
        if (rk < nkeep_amb) keep[amb_t[t]] = 1;
    }
    __syncthreads();

    for (int t = tid; t < cnt; t += 256) {
        if (keep[t]) {
            const int p = atomicAdd(&nk_sh, 1);
            if (p < K_TOP + 8) { t_idx[p] = ci[t]; t_val[p] = cv[t]; }
        }
    }
    __syncthreads();
    if (nk_sh != K_TOP) { if (tid == 0) flag_ws[r] = 1; return; }

    if (tid == 0) flag_ws[r] = 0;
    if (tid < K_TOP) {
        const int it = t_idx[tid];
        int pos = 0;
        #pragma unroll 8
        for (int s = 0; s < K_TOP; ++s) pos += (t_idx[s] < it);
        kidx[pos] = it;
        kval[pos] = t_val[tid];
        z[(size_t)r * NLAT + it] = t_val[tid];   // scatter over zeroed row
    }
    __syncthreads();

    // ---- fused decoder (deterministic: index-ascending sum) ----
    if (tid < D_IN / 4) {
        const int d0 = tid * 4;
        const float4 bp = *(const float4*)(bpre + d0);
        float a0 = bp.x, a1 = bp.y, a2 = bp.z, a3 = bp.w;
        #pragma unroll 8
        for (int j = 0; j < K_TOP; ++j) {
            const float vv = kval[j];
            const ushort4 w4 = *(const ushort4*)(wdh + (size_t)kidx[j] * D_IN + d0);
            a0 = fmaf(vv, bf2f(w4.x), a0);
            a1 = fmaf(vv, bf2f(w4.y), a1);
            a2 = fmaf(vv, bf2f(w4.z), a2);
            a3 = fmaf(vv, bf2f(w4.w), a3);
        }
        const size_t o = (size_t)r * D_IN + d0;
        const float4 xv = *(const float4*)(x + o);
        *(float4*)(x_hat + o) = make_float4(a0, a1, a2, a3);
        *(float4*)(recon + o) = make_float4(xv.x - a0, xv.y - a1, xv.z - a2, xv.w - a3);
    }
}

// ---------------------------------------------------------------------------
// Fallback full-row top-k (r3-verified).  Only flagged rows (or all if null).
// ---------------------------------------------------------------------------
__global__ __launch_bounds__(1024) void topk_fallback(const float* __restrict__ z_pre,
                                                      float* __restrict__ z,
                                                      const float* __restrict__ x,
                                                      const float* __restrict__ W_enc,
                                                      const float* __restrict__ bpre,
                                                      int* __restrict__ idx_ws,
                                                      float* __restrict__ val_ws,
                                                      const int* __restrict__ flag_ws)
{
    if (flag_ws != nullptr && flag_ws[blockIdx.x] == 0) return;

    __shared__ unsigned hist_w[16][257];
    __shared__ unsigned hist[256];
    __shared__ unsigned sh_prefix;
    __shared__ int sh_rem;
    __shared__ int cntA;
    __shared__ int nsure_sh;
    __shared__ int idxA[MAXA];
    __shared__ double dvalA[MAXA];
    __shared__ unsigned char keepA[MAXA];
    __shared__ int wcnt[16][24];

    const int r = blockIdx.x;
    const int tid = threadIdx.x;
    const int lane = tid & 63;
    const int w = tid >> 6;
    const unsigned long long lt = (1ull << lane) - 1ull;

    const float* src = z_pre + (size_t)r * NLAT;
    float v[24];
    #pragma unroll
    for (int c = 0; c < 24; ++c) v[c] = src[c*1024 + tid];

    if (tid == 0) { sh_prefix = 0u; sh_rem = K_TOP; cntA = 0; nsure_sh = 0; }
    if (idx_ws != nullptr && tid < K_TOP) {
        idx_ws[r*K_TOP + tid] = 0; val_ws[r*K_TOP + tid] = 0.0f;
    }

    for (int lvl = 0; lvl < 4; ++lvl) {
        const int shift = 24 - 8*lvl;
        for (int i = tid; i < 16*257; i += 1024) ((unsigned*)hist_w)[i] = 0u;
        __syncthreads();
        const unsigned pfx = sh_prefix;
        #pragma unroll
        for (int c = 0; c < 24; ++c) {
            const unsigned key = f2key(v[c]);
            const bool match = (lvl == 0) || ((key >> (shift + 8)) == (pfx >> (shift + 8)));
            if (match) atomicAdd(&hist_w[w][(key >> shift) & 255u], 1u);
        }
        __syncthreads();
        if (tid < 256) {
            unsigned s = 0;
            #pragma unroll
            for (int q = 0; q < 16; ++q) s += hist_w[q][tid];
            hist[tid] = s;
        }
        __syncthreads();
        if (tid == 0) {
            int rem = sh_rem, acc = 0, b = 255;
            for (; b >= 0; --b) {
                const int nb = acc + (int)hist[b];
                if (nb >= rem) { sh_rem = rem - acc; break; }
                acc = nb;
            }
            sh_prefix = pfx | ((unsigned)b << shift);
        }
        __syncthreads();
    }

    const float vT = key2f(sh_prefix);
    const float thr_lo = vT - DELTA, thr_hi = vT + DELTA;

    int wsure = 0;
    #pragma unroll
    for (int c = 0; c < 24; ++c) {
        const float val = v[c];
        const unsigned long long m = __ballot(val > thr_hi);
        if (lane == 0) wsure += (int)__popcll(m);
        if (val <= thr_hi && val >= thr_lo) {
            const int p = atomicAdd(&cntA, 1);
            if (p < MAXA) idxA[p] = c*1024 + tid;
        }
    }
    if (lane == 0 && wsure) atomicAdd(&nsure_sh, (unsigned)wsure);
    __syncthreads();

    const int nA = cntA < MAXA ? cntA : MAXA;
    const int nkeepA = K_TOP - nsure_sh;

    for (int q = w; q < nA; q += 16) {
        const int j = idxA[q];
        const float* wrow = W_enc + (size_t)j * D_IN;
        const float* xrow = x + (size_t)r * D_IN;
        double a = 0.0;
        for (int k = lane; k < D_IN; k += 64)
            a = fma((double)xrow[k] - (double)bpre[k], (double)wrow[k], a);
        #pragma unroll
        for (int off = 32; off; off >>= 1) a += __shfl_down(a, off, 64);
        if (lane == 0) dvalA[q] = a;
    }
    __syncthreads();

    for (int t = tid; t < nA; t += 1024) {
        const double dv = dvalA[t];
        const int ix = idxA[t];
        int rank = 0;
        for (int q = 0; q < nA; ++q)
            rank += (dvalA[q] > dv) || (dvalA[q] == dv && idxA[q] < ix);
        keepA[t] = (rank < nkeepA) ? 1 : 0;
    }
    __syncthreads();

    bool kp[24];
    #pragma unroll
    for (int c = 0; c < 24; ++c) {
        const float val = v[c];
        bool k = (val > thr_hi);
        if (!k && val >= thr_lo) {
            const int i = c*1024 + tid;
            for (int q = 0; q < nA; ++q)
                if (idxA[q] == i) { k = (keepA[q] != 0); break; }
        }
        kp[c] = k;
        const unsigned long long m = __ballot(k);
        if (lane == 0) wcnt[w][c] = (int)__popcll(m);
    }
    __syncthreads();
    if (tid == 0) {
        int run = 0;
        for (int c = 0; c < 24; ++c)
            #pragma unroll
            for (int q = 0; q < 16; ++q) { const int t = wcnt[q][c]; wcnt[q][c] = run; run += t; }
    }
    __syncthreads();

    float* zdst = z + (size_t)r * NLAT;
    #pragma unroll
    for (int c = 0; c < 24; ++c) {
        const unsigned long long m = __ballot(kp[c]);
        const int pos = wcnt[w][c] + (int)__popcll(m & lt);
        const int i = c*1024 + tid;
        zdst[i] = kp[c] ? v[c] : 0.0f;
        if (kp[c] && idx_ws != nullptr && pos < K_TOP) {
            idx_ws[r*K_TOP + pos] = i;
            val_ws[r*K_TOP + pos] = v[c];
        }
    }
}

// ---------------------------------------------------------------------------
// Flag-gated decoder for fallback rows (reads idx/val written by fallback).
// ---------------------------------------------------------------------------
__global__ __launch_bounds__(256) void dec_flagged(const int* __restrict__ flag_ws,
                                                   const int* __restrict__ idx_ws,
                                                   const float* __restrict__ val_ws,
                                                   const unsigned short* __restrict__ wdh,
                                                   const float* __restrict__ bpre,
                                                   const float* __restrict__ x,
                                                   float* __restrict__ x_hat,
                                                   float* __restrict__ recon)
{
    const int r = blockIdx.x;
    if (flag_ws[r] == 0) return;
    __shared__ int sidx[K_TOP];
    __shared__ float sval[K_TOP];
    const int tid = threadIdx.x;
    if (tid < K_TOP) {
        sidx[tid] = idx_ws[r*K_TOP + tid];
        sval[tid] = val_ws[r*K_TOP + tid];
    }
    __syncthreads();

    if (tid < D_IN / 4) {
        const int d0 = tid * 4;
        const float4 bp = *(const float4*)(bpre + d0);
        float a0 = bp.x, a1 = bp.y, a2 = bp.z, a3 = bp.w;
        #pragma unroll 8
        for (int j = 0; j < K_TOP; ++j) {
            const float vv = sval[j];
            const ushort4 w4 = *(const ushort4*)(wdh + (size_t)sidx[j] * D_IN + d0);
            a0 = fmaf(vv, bf2f(w4.x), a0);
            a1 = fmaf(vv, bf2f(w4.y), a1);
            a2 = fmaf(vv, bf2f(w4.z), a2);
            a3 = fmaf(vv, bf2f(w4.w), a3);
        }
        const size_t o = (size_t)r * D_IN + d0;
        const float4 xv = *(const float4*)(x + o);
        *(float4*)(x_hat + o) = make_float4(a0, a1, a2, a3);
        *(float4*)(recon + o) = make_float4(xv.x - a0, xv.y - a1, xv.z - a2, xv.w - a3);
    }
}

// ---------------------------------------------------------------------------
// Fallback GEMM with in-kernel split-2 (r5-verified) for small ws.
// ---------------------------------------------------------------------------
#define FBK 32
#define FLROW (FBK + 8)

__global__ __launch_bounds__(256) void enc_gemm_mfma(const float* __restrict__ x,
                                                     const float* __restrict__ W,
                                                     const float* __restrict__ bpre,
                                                     float* __restrict__ z_pre)
{
    __shared__ unsigned short Ah[GBM][FLROW], Al[GBM][FLROW];
    __shared__ unsigned short Bh[GBN][FLROW], Bl[GBN][FLROW];

    const int tid = threadIdx.x;
    const int bm = blockIdx.y * GBM;
    const int bn = blockIdx.x * GBN;
    const int lane = tid & 63;
    const int wv = tid >> 6;
    const int wr = (wv >> 1) * 64;
    const int wc = (wv & 1) * 64;
    const int fr = lane & 15;
    const int fg = lane >> 4;

    const int srow = tid >> 3;
    const int sk   = (tid & 7) * 4;

    f32x4 acc[4][4];
    #pragma unroll
    for (int i = 0; i < 4; ++i)
        #pragma unroll
        for (int j = 0; j < 4; ++j)
            #pragma unroll
            for (int e = 0; e < 4; ++e) acc[i][j][e] = 0.0f;

    for (int k0 = 0; k0 < D_IN; k0 += FBK) {
        float4 xa[4], wb[4];
        const float4 bp = *(const float4*)(bpre + k0 + sk);
        #pragma unroll
        for (int p = 0; p < 4; ++p) {
            xa[p] = *(const float4*)(x + (size_t)(bm + srow + 32*p) * D_IN + k0 + sk);
            wb[p] = *(const float4*)(W + (size_t)(bn + srow + 32*p) * D_IN + k0 + sk);
        }
        __syncthreads();
        #pragma unroll
        for (int p = 0; p < 4; ++p) {
            const float a0 = xa[p].x - bp.x, a1 = xa[p].y - bp.y,
                        a2 = xa[p].z - bp.z, a3 = xa[p].w - bp.w;
            const unsigned short h0 = bf16hi(a0), h1 = bf16hi(a1),
                                 h2 = bf16hi(a2), h3 = bf16hi(a3);
            *(ushort4*)&Ah[srow + 32*p][sk] = make_ushort4(h0, h1, h2, h3);
            *(ushort4*)&Al[srow + 32*p][sk] = make_ushort4(
                bf16hi(a0 - bf2f(h0)), bf16hi(a1 - bf2f(h1)),
                bf16hi(a2 - bf2f(h2)), bf16hi(a3 - bf2f(h3)));
            const float b0 = wb[p].x, b1 = wb[p].y, b2 = wb[p].z, b3 = wb[p].w;
            const unsigned short g0 = bf16hi(b0), g1 = bf16hi(b1),
                                 g2 = bf16hi(b2), g3 = bf16hi(b3);
            *(ushort4*)&Bh[srow + 32*p][sk] = make_ushort4(g0, g1, g2, g3);
            *(ushort4*)&Bl[srow + 32*p][sk] = make_ushort4(
                bf16hi(b0 - bf2f(g0)), bf16hi(b1 - bf2f(g1)),
                bf16hi(b2 - bf2f(g2)), bf16hi(b3 - bf2f(g3)));
        }
        __syncthreads();

        short8 ah[4], al[4], bh[4], bl[4];
        #pragma unroll
        for (int t = 0; t < 4; ++t) {
            ah[t] = *(const short8*)&Ah[wr + t*16 + fr][fg * 8];
            al[t] = *(const short8*)&Al[wr + t*16 + fr][fg * 8];
            bh[t] = *(const short8*)&Bh[wc + t*16 + fr][fg * 8];
            bl[t] = *(const short8*)&Bl[wc + t*16 + fr][fg * 8];
        }
        #pragma unroll
        for (int mt = 0; mt < 4; ++mt)
            #pragma unroll
            for (int nt = 0; nt < 4; ++nt) {
                acc[mt][nt] = __builtin_amdgcn_mfma_f32_16x16x32_bf16(ah[mt], bh[nt], acc[mt][nt], 0, 0, 0);
                acc[mt][nt] = __builtin_amdgcn_mfma_f32_16x16x32_bf16(ah[mt], bl[nt], acc[mt][nt], 0, 0, 0);
                acc[mt][nt] = __builtin_amdgcn_mfma_f32_16x16x32_bf16(al[mt], bh[nt], acc[mt][nt], 0, 0, 0);
            }
    }

    #pragma unroll
    for (int mt = 0; mt < 4; ++mt)
        #pragma unroll
        for (int j = 0; j < 4; ++j) {
            const int r = bm + wr + mt*16 + fg*4 + j;
            float* dst = z_pre + (size_t)r * NLAT + bn + wc;
            #pragma unroll
            for (int nt = 0; nt < 4; ++nt)
                dst[nt*16 + fr] = acc[mt][nt][j];
        }
}

__global__ __launch_bounds__(256) void dec_scan_kernel(const float* __restrict__ z,
                                                       const float* __restrict__ W_dec,
                                                       const float* __restrict__ bpre,
                                                       const float* __restrict__ x,
                                                       float* __restrict__ x_hat,
                                                       float* __restrict__ recon)
{
    __shared__ int sidx[K_TOP];
    __shared__ float sval[K_TOP];
    __shared__ int wcnt[4];
    __shared__ int base;
    const int r = blockIdx.x;
    const int tid = threadIdx.x;
    const int lane = tid & 63, w = tid >> 6;
    if (tid == 0) base = 0;
    __syncthreads();
    const float* zrow = z + (size_t)r * NLAT;
    for (int c = 0; c < NLAT; c += 256) {
        const float vv = zrow[c + tid];
        const bool nz = (vv != 0.0f);
        const unsigned long long m = __ballot(nz);
        if (lane == 0) wcnt[w] = __popcll(m);
        __syncthreads();
        int b = base;
        for (int j = 0; j < w; ++j) b += wcnt[j];
        const int pos = b + __popcll(m & ((1ull << lane) - 1ull));
        if (nz && pos < K_TOP) { sidx[pos] = c + tid; sval[pos] = vv; }
        __syncthreads();
        if (tid == 0) { int s = 0; for (int j = 0; j < 4; ++j) s += wcnt[j]; base += s; }
        __syncthreads();
    }
    const int n = base > K_TOP ? K_TOP : base;

    float a0 = bpre[tid], a1 = bpre[tid + 256], a2 = bpre[tid + 512];
    for (int j = 0; j < n; ++j) {
        const float vv = sval[j];
        const float* wr_ = W_dec + (size_t)sidx[j] * D_IN;
        a0 = fmaf(vv, wr_[tid],       a0);
        a1 = fmaf(vv, wr_[tid + 256], a1);
        a2 = fmaf(vv, wr_[tid + 512], a2);
    }
    const size_t o = (size_t)r * D_IN + tid;
    x_hat[o]       = a0;
    x_hat[o + 256] = a1;
    x_hat[o + 512] = a2;
    recon[o]       = x[o]       - a0;
    recon[o + 256] = x[o + 256] - a1;
    recon[o + 512] = x[o + 512] - a2;
}

// ---------------------------------------------------------------------------
extern "C" void kernel_launch(void* const* d_in, const int* in_sizes, int n_in,
                              void* d_out, int out_size, void* d_ws, size_t ws_size,
                              hipStream_t stream)
{
    const float* x     = (const float*)d_in[0];
    const float* W_enc = (const float*)d_in[1];
    const float* W_dec = (const float*)d_in[2];
    const float* bpre  = (const float*)d_in[3];

    float* out   = (float*)d_out;
    float* x_hat = out;
    float* z     = x_hat + (size_t)BATCH * D_IN;
    float* z_pre = z     + (size_t)BATCH * NLAT;
    float* recon = z_pre + (size_t)BATCH * NLAT;

    // ws layout
    char* p = (char*)d_ws;
    int*    flag_ws   = (int*)p;           p += (size_t)BATCH * 4;
    int*    idx_ws    = (int*)p;           p += (size_t)BATCH * K_TOP * 4;
    float*  val_ws    = (float*)p;         p += (size_t)BATCH * K_TOP * 4;
    p = (char*)(((size_t)p + 15) & ~(size_t)15);
    int*    cnt_blk   = (int*)p;           p += (size_t)NBLKN * BATCH * 4;
    int2*   slot_iv   = (int2*)p;          p += (size_t)BATCH * NBLKN * SLOTS * 8;
    unsigned short* xh  = (unsigned short*)p;    p += (size_t)BATCH * D_IN * 2;
    unsigned short* wh  = (unsigned short*)p;    p += (size_t)NLAT * D_IN * 2;
    unsigned short* wdh = (unsigned short*)p;    p += (size_t)NLAT * D_IN * 2;
    const size_t ws_full = (size_t)(p - (char*)d_ws);
    const bool have_full = (d_ws != nullptr) && (ws_size >= ws_full);

    if (have_full) {
        conv_all<<<XCHUNKS + 2 * WCHUNKS, 256, 0, stream>>>(
            (const float4*)x, bpre, (const float4*)W_enc, (const float4*)W_dec,
            (ushort4*)xh, (ushort4*)wh, (ushort4*)wdh);

        enc_gemm_fused<<<NWG, 256, 0, stream>>>(xh, wh, z_pre, z, cnt_blk, slot_iv);

        select_kernel<<<BATCH, 256, 0, stream>>>(cnt_blk, slot_iv, x, W_enc, bpre, wdh,
                                                 z, x_hat, recon, idx_ws, val_ws, flag_ws);
        topk_fallback<<<BATCH, 1024, 0, stream>>>(z_pre, z, x, W_enc, bpre,
                                                  idx_ws, val_ws, flag_ws);
        dec_flagged<<<BATCH, 256, 0, stream>>>(flag_ws, idx_ws, val_ws, wdh, bpre,
                                               x, x_hat, recon);
    } else {
        dim3 g1(NLAT / GBN, BATCH / GBM);
        enc_gemm_mfma<<<g1, 256, 0, stream>>>(x, W_enc, bpre, z_pre);
        topk_fallback<<<BATCH, 1024, 0, stream>>>(z_pre, z, x, W_enc, bpre,
                                                  nullptr, nullptr, nullptr);
        dec_scan_kernel<<<BATCH, 256, 0, stream>>>(z, W_dec, bpre, x, x_hat, recon);
    }
}

// Round 13
// 587.674 us; speedup vs baseline: 8.5050x; 1.1788x over previous
//
#include <hip/hip_runtime.h>

#define D_IN   768
#define NLAT   24576
#define BATCH  4096
#define K_TOP  64
#define MAXA   1024
#define DELTA  0.05f
#define THRESH 1.30f
#define CAND_MAX 512
#define MAXAMB 128
#define SLOTS  12

typedef float f32x4  __attribute__((ext_vector_type(4)));
typedef float f32x16 __attribute__((ext_vector_type(16)));
typedef short short8 __attribute__((ext_vector_type(8)));

// ---------------------------------------------------------------------------
__device__ __forceinline__ unsigned f2key(float f) {
    unsigned u = __float_as_uint(f);
    return (u & 0x80000000u) ? ~u : (u | 0x80000000u);
}
__device__ __forceinline__ float key2f(unsigned k) {
    unsigned u = (k & 0x80000000u) ? (k & 0x7fffffffu) : ~k;
    return __uint_as_float(u);
}
__device__ __forceinline__ unsigned short bf16hi(float f) {   // RNE f32->bf16
    unsigned u = __float_as_uint(f);
    unsigned r = u + 0x7fffu + ((u >> 16) & 1u);
    return (unsigned short)(r >> 16);
}
__device__ __forceinline__ float bf2f(unsigned short h) {
    return __uint_as_float(((unsigned)h) << 16);
}
__device__ __forceinline__ float binedge(int b) {
    return __uint_as_float((unsigned)(16288 + b) << 16);   // bin 0 edge = 1.25f
}

// ---------------------------------------------------------------------------
// One merged bf16 convert pass: x (with b_pre), W_enc, W_dec.
// ---------------------------------------------------------------------------
#define XCHUNKS (BATCH * D_IN / 4 / 256)   // 3072
#define WCHUNKS (NLAT * D_IN / 4 / 256)    // 18432

__global__ __launch_bounds__(256) void conv_all(const float4* __restrict__ x,
                                                const float* __restrict__ bpre,
                                                const float4* __restrict__ We,
                                                const float4* __restrict__ Wd,
                                                ushort4* __restrict__ xh,
                                                ushort4* __restrict__ wh,
                                                ushort4* __restrict__ wdh)
{
    const int b = blockIdx.x;
    if (b < XCHUNKS) {
        const int f = b * 256 + threadIdx.x;
        float4 v = x[f];
        const float4 bp = ((const float4*)bpre)[f % (D_IN / 4)];
        ushort4 h;
        h.x = bf16hi(v.x - bp.x);
        h.y = bf16hi(v.y - bp.y);
        h.z = bf16hi(v.z - bp.z);
        h.w = bf16hi(v.w - bp.w);
        xh[f] = h;
    } else if (b < XCHUNKS + WCHUNKS) {
        const int f = (b - XCHUNKS) * 256 + threadIdx.x;
        const float4 v = We[f];
        ushort4 h;
        h.x = bf16hi(v.x); h.y = bf16hi(v.y); h.z = bf16hi(v.z); h.w = bf16hi(v.w);
        wh[f] = h;
    } else {
        const int f = (b - XCHUNKS - WCHUNKS) * 256 + threadIdx.x;
        const float4 v = Wd[f];
        ushort4 h;
        h.x = bf16hi(v.x); h.y = bf16hi(v.y); h.z = bf16hi(v.z); h.w = bf16hi(v.w);
        wdh[f] = h;
    }
}

// ---------------------------------------------------------------------------
// bf16 encoder GEMM, 32x32x16 MFMA, fused z-zeroing + slot extraction
// (r11-verified).  All streaming output stores are NONTEMPORAL (ext-vector
// types — HIP float4 is rejected by the builtin) so the 806 MB of z_pre/z
// writes don't evict the 44 MB L3-resident operand panels.
// ---------------------------------------------------------------------------
#define GBM 128
#define GBN 128
#define GBK 64
#define LROW (GBK + 8)
#define NWG  ((NLAT / GBN) * (BATCH / GBM))   // 6144
#define NBLKN (NLAT / GBN)                    // 192

__global__ __launch_bounds__(256) void enc_gemm_fused(const unsigned short* __restrict__ xh,
                                                      const unsigned short* __restrict__ wh,
                                                      float* __restrict__ z_pre,
                                                      float* __restrict__ z,
                                                      int* __restrict__ cnt_blk,   // [NBLKN][BATCH]
                                                      int2* __restrict__ slot_iv)  // [BATCH][NBLKN][SLOTS]
{
    __shared__ unsigned short Ah[GBM][LROW];
    __shared__ unsigned short Bh[GBN][LROW];
    __shared__ int rowcnt[GBM];

    const int tid = threadIdx.x;
    const int bid = blockIdx.x;
    const int swz = (bid & 7) * (NWG / 8) + (bid >> 3);
    const int bn = (swz % NBLKN) * GBN;
    const int bm = (swz / NBLKN) * GBM;
    const int blkn = bn / GBN;

    const int lane = tid & 63;
    const int wv = tid >> 6;
    const int wr = (wv >> 1) * 64;
    const int wc = (wv & 1) * 64;
    const int l31 = lane & 31;
    const int lh  = lane >> 5;

    int srow[4], sko[4];
    const unsigned short* pxa[4];
    const unsigned short* pwb[4];
    #pragma unroll
    for (int q = 0; q < 4; ++q) {
        const int c = q * 256 + tid;
        srow[q] = c >> 3;
        sko[q]  = (c & 7) * 8;
        pxa[q] = xh + (size_t)(bm + srow[q]) * D_IN + sko[q];
        pwb[q] = wh + (size_t)(bn + srow[q]) * D_IN + sko[q];
    }

    f32x16 acc[2][2];
    #pragma unroll
    for (int i = 0; i < 2; ++i)
        #pragma unroll
        for (int j = 0; j < 2; ++j)
            #pragma unroll
            for (int e = 0; e < 16; ++e) acc[i][j][e] = 0.0f;

    for (int k0 = 0; k0 < D_IN; k0 += GBK) {
        short8 va[4], vb[4];
        #pragma unroll
        for (int q = 0; q < 4; ++q) {
            va[q] = *(const short8*)(pxa[q] + k0);
            vb[q] = *(const short8*)(pwb[q] + k0);
        }

        __syncthreads();

        #pragma unroll
        for (int q = 0; q < 4; ++q) {
            *(short8*)&Ah[srow[q]][sko[q]] = va[q];
            *(short8*)&Bh[srow[q]][sko[q]] = vb[q];
        }

        __syncthreads();

        #pragma unroll
        for (int ks = 0; ks < 4; ++ks) {
            short8 ah[2], bh[2];
            #pragma unroll
            for (int t = 0; t < 2; ++t) {
                ah[t] = *(const short8*)&Ah[wr + t*32 + l31][ks*16 + lh*8];
                bh[t] = *(const short8*)&Bh[wc + t*32 + l31][ks*16 + lh*8];
            }
            #pragma unroll
            for (int mt = 0; mt < 2; ++mt)
                #pragma unroll
                for (int nt = 0; nt < 2; ++nt)
                    acc[mt][nt] = __builtin_amdgcn_mfma_f32_32x32x16_bf16(ah[mt], bh[nt], acc[mt][nt], 0, 0, 0);
        }
    }

    if (tid < GBM) rowcnt[tid] = 0;
    __syncthreads();

    // C/D: col = lane&31, row = (reg&3) + 8*(reg>>2) + 4*(lane>>5)
    #pragma unroll
    for (int mt = 0; mt < 2; ++mt)
        #pragma unroll
        for (int nt = 0; nt < 2; ++nt) {
            const int colg = bn + wc + nt*32 + l31;
            #pragma unroll
            for (int reg = 0; reg < 16; ++reg) {
                const int lr = wr + mt*32 + (reg & 3) + 8*(reg >> 2) + 4*lh;
                const int r  = bm + lr;
                const float vv = acc[mt][nt][reg];
                __builtin_nontemporal_store(vv, &z_pre[(size_t)r * NLAT + colg]);
                if (vv > THRESH) {
                    const int s = atomicAdd(&rowcnt[lr], 1);   // LDS atomic
                    if (s < SLOTS)
                        slot_iv[((size_t)r * NBLKN + blkn) * SLOTS + s] =
                            make_int2(colg, __float_as_int(vv));
                }
            }
        }

    // zero the z tile with nontemporal ext-vector stores
    const f32x4 zero4 = {0.f, 0.f, 0.f, 0.f};
    #pragma unroll
    for (int u = 0; u < 16; ++u) {
        const int idx = u * 256 + tid;
        const int lr = idx >> 5;
        const int lc = (idx & 31) * 4;
        f32x4* dst4 = (f32x4*)(z + (size_t)(bm + lr) * NLAT + bn + lc);
        __builtin_nontemporal_store(zero4, dst4);
    }

    __syncthreads();
    if (tid < GBM) cnt_blk[(size_t)blkn * BATCH + bm + tid] = rowcnt[tid];
}

// ---------------------------------------------------------------------------
// Merged select: classify + f64 refine + finalize + DECODER (r11-verified).
// ---------------------------------------------------------------------------
__global__ __launch_bounds__(256) void select_kernel(const int* __restrict__ cnt_blk,
                                                     const int2* __restrict__ slot_iv,
                                                     const float* __restrict__ x,
                                                     const float* __restrict__ W_enc,
                                                     const float* __restrict__ bpre,
                                                     const unsigned short* __restrict__ wdh,
                                                     float* __restrict__ z,
                                                     float* __restrict__ x_hat,
                                                     float* __restrict__ recon,
                                                     int* __restrict__ idx_ws,
                                                     float* __restrict__ val_ws,
                                                     int* __restrict__ flag_ws)
{
    __shared__ int ccnt[NBLKN];
    __shared__ int cofs[NBLKN];
    __shared__ float cv[CAND_MAX];
    __shared__ int   ci[CAND_MAX];
    __shared__ unsigned char keep[CAND_MAX];
    __shared__ unsigned hist[256];
    __shared__ int b_sh, nsure_sh, namb_sh, of_sh, tot_sh, nk_sh;
    __shared__ int    amb_t[MAXAMB];
    __shared__ int    amb_i[MAXAMB];
    __shared__ double amb_d[MAXAMB];
    __shared__ int   t_idx[K_TOP + 8];
    __shared__ float t_val[K_TOP + 8];
    __shared__ int   kidx[K_TOP];
    __shared__ float kval[K_TOP];

    const int r = blockIdx.x;
    const int tid = threadIdx.x;

    if (tid == 0) { nsure_sh = 0; namb_sh = 0; nk_sh = 0; }
    hist[tid] = 0u;
    if (tid < NBLKN) ccnt[tid] = cnt_blk[(size_t)tid * BATCH + r];
    __syncthreads();

    if (tid == 0) {
        int run = 0, of = 0;
        for (int b = 0; b < NBLKN; ++b) {
            if (ccnt[b] > SLOTS) of = 1;
            cofs[b] = run;
            run += ccnt[b];
        }
        tot_sh = run; of_sh = of;
    }
    __syncthreads();

    const int cnt = tot_sh;
    if (of_sh || cnt < K_TOP || cnt > CAND_MAX) {
        if (tid == 0) flag_ws[r] = 1;
        return;
    }

    if (tid < NBLKN) {
        const int c = ccnt[tid];
        const int2* sp = slot_iv + ((size_t)r * NBLKN + tid) * SLOTS;
        const int o = cofs[tid];
        for (int e = 0; e < c; ++e) {
            const int2 iv = sp[e];
            ci[o + e] = iv.x;
            cv[o + e] = __int_as_float(iv.y);
        }
    }
    __syncthreads();

    for (int q = tid; q < cnt; q += 256) {
        int b = (int)(__float_as_uint(cv[q]) >> 16) - 16288;
        b = b < 0 ? 0 : (b > 255 ? 255 : b);
        atomicAdd(&hist[b], 1u);
    }
    __syncthreads();
    if (tid == 0) {
        int acc = 0, b = 255;
        for (; b >= 0; --b) {
            const int nb = acc + (int)hist[b];
            if (nb >= K_TOP) break;
            acc = nb;
        }
        b_sh = b;
    }
    __syncthreads();

    const int bstar = b_sh;
    const float hi = binedge(bstar + 1) + DELTA;
    const float lo = binedge(bstar) - DELTA;
    if (bstar >= 255 || bstar < 0 || lo <= THRESH + 1e-3f) {
        if (tid == 0) flag_ws[r] = 1;
        return;
    }

    for (int t = tid; t < cnt; t += 256) {
        const float vt = cv[t];
        unsigned char k = 0;
        if (vt > hi) { k = 1; atomicAdd(&nsure_sh, 1); }
        else if (vt >= lo) {
            const int p = atomicAdd(&namb_sh, 1);
            if (p < MAXAMB) { amb_t[p] = t; amb_i[p] = ci[t]; }
        }
        keep[t] = k;
    }
    __syncthreads();

    const int nsure = nsure_sh;
    const int namb = namb_sh;
    if (namb > MAXAMB || nsure >= K_TOP) { if (tid == 0) flag_ws[r] = 1; return; }
    const int nkeep_amb = K_TOP - nsure;

    const int lane = tid & 63, w = tid >> 6;
    const float* xrow = x + (size_t)r * D_IN;
    for (int q = w; q < namb; q += 4) {
        const float* wrow = W_enc + (size_t)amb_i[q] * D_IN;
        double a = 0.0;
        #pragma unroll
        for (int k = lane; k < D_IN; k += 64)
            a = fma((double)xrow[k] - (double)bpre[k], (double)wrow[k], a);
        #pragma unroll
        for (int off = 32; off; off >>= 1) a += __shfl_down(a, off, 64);
        if (lane == 0) amb_d[q] = a;
    }
    __syncthreads();

    for (int t = tid; t < namb; t += 256) {
        const double dv = amb_d[t];
        const int it = amb_i[t];
        int rk = 0;
        for (int q = 0; q < namb; ++q)
            rk += (amb_d[q] > dv) || (amb_d[q] == dv && amb_i[q] < it);
        if (rk < nkeep_amb) keep[amb_t[t]] = 1;
    }
    __syncthreads();

    for (int t = tid; t < cnt; t += 256) {
        if (keep[t]) {
            const int p = atomicAdd(&nk_sh, 1);
            if (p < K_TOP + 8) { t_idx[p] = ci[t]; t_val[p] = cv[t]; }
        }
    }
    __syncthreads();
    if (nk_sh != K_TOP) { if (tid == 0) flag_ws[r] = 1; return; }

    if (tid == 0) flag_ws[r] = 0;
    if (tid < K_TOP) {
        const int it = t_idx[tid];
        int pos = 0;
        #pragma unroll 8
        for (int s = 0; s < K_TOP; ++s) pos += (t_idx[s] < it);
        kidx[pos] = it;
        kval[pos] = t_val[tid];
        z[(size_t)r * NLAT + it] = t_val[tid];   // scatter over zeroed row
    }
    __syncthreads();

    // ---- fused decoder (deterministic: index-ascending sum) ----
    if (tid < D_IN / 4) {
        const int d0 = tid * 4;
        const float4 bp = *(const float4*)(bpre + d0);
        float a0 = bp.x, a1 = bp.y, a2 = bp.z, a3 = bp.w;
        #pragma unroll 8
        for (int j = 0; j < K_TOP; ++j) {
            const float vv = kval[j];
            const ushort4 w4 = *(const ushort4*)(wdh + (size_t)kidx[j] * D_IN + d0);
            a0 = fmaf(vv, bf2f(w4.x), a0);
            a1 = fmaf(vv, bf2f(w4.y), a1);
            a2 = fmaf(vv, bf2f(w4.z), a2);
            a3 = fmaf(vv, bf2f(w4.w), a3);
        }
        const size_t o = (size_t)r * D_IN + d0;
        const float4 xv = *(const float4*)(x + o);
        *(float4*)(x_hat + o) = make_float4(a0, a1, a2, a3);
        *(float4*)(recon + o) = make_float4(xv.x - a0, xv.y - a1, xv.z - a2, xv.w - a3);
    }
}

// ---------------------------------------------------------------------------
// Fallback full-row top-k (r3-verified).  Only flagged rows (or all if null).
// ---------------------------------------------------------------------------
__global__ __launch_bounds__(1024) void topk_fallback(const float* __restrict__ z_pre,
                                                      float* __restrict__ z,
                                                      const float* __restrict__ x,
                                                      const float* __restrict__ W_enc,
                                                      const float* __restrict__ bpre,
                                                      int* __restrict__ idx_ws,
                                                      float* __restrict__ val_ws,
                                                      const int* __restrict__ flag_ws)
{
    if (flag_ws != nullptr && flag_ws[blockIdx.x] == 0) return;

    __shared__ unsigned hist_w[16][257];
    __shared__ unsigned hist[256];
    __shared__ unsigned sh_prefix;
    __shared__ int sh_rem;
    __shared__ int cntA;
    __shared__ int nsure_sh;
    __shared__ int idxA[MAXA];
    __shared__ double dvalA[MAXA];
    __shared__ unsigned char keepA[MAXA];
    __shared__ int wcnt[16][24];

    const int r = blockIdx.x;
    const int tid = threadIdx.x;
    const int lane = tid & 63;
    const int w = tid >> 6;
    const unsigned long long lt = (1ull << lane) - 1ull;

    const float* src = z_pre + (size_t)r * NLAT;
    float v[24];
    #pragma unroll
    for (int c = 0; c < 24; ++c) v[c] = src[c*1024 + tid];

    if (tid == 0) { sh_prefix = 0u; sh_rem = K_TOP; cntA = 0; nsure_sh = 0; }
    if (idx_ws != nullptr && tid < K_TOP) {
        idx_ws[r*K_TOP + tid] = 0; val_ws[r*K_TOP + tid] = 0.0f;
    }

    for (int lvl = 0; lvl < 4; ++lvl) {
        const int shift = 24 - 8*lvl;
        for (int i = tid; i < 16*257; i += 1024) ((unsigned*)hist_w)[i] = 0u;
        __syncthreads();
        const unsigned pfx = sh_prefix;
        #pragma unroll
        for (int c = 0; c < 24; ++c) {
            const unsigned key = f2key(v[c]);
            const bool match = (lvl == 0) || ((key >> (shift + 8)) == (pfx >> (shift + 8)));
            if (match) atomicAdd(&hist_w[w][(key >> shift) & 255u], 1u);
        }
        __syncthreads();
        if (tid < 256) {
            unsigned s = 0;
            #pragma unroll
            for (int q = 0; q < 16; ++q) s += hist_w[q][tid];
            hist[tid] = s;
        }
        __syncthreads();
        if (tid == 0) {
            int rem = sh_rem, acc = 0, b = 255;
            for (; b >= 0; --b) {
                const int nb = acc + (int)hist[b];
                if (nb >= rem) { sh_rem = rem - acc; break; }
                acc = nb;
            }
            sh_prefix = pfx | ((unsigned)b << shift);
        }
        __syncthreads();
    }

    const float vT = key2f(sh_prefix);
    const float thr_lo = vT - DELTA, thr_hi = vT + DELTA;

    int wsure = 0;
    #pragma unroll
    for (int c = 0; c < 24; ++c) {
        const float val = v[c];
        const unsigned long long m = __ballot(val > thr_hi);
        if (lane == 0) wsure += (int)__popcll(m);
        if (val <= thr_hi && val >= thr_lo) {
            const int p = atomicAdd(&cntA, 1);
            if (p < MAXA) idxA[p] = c*1024 + tid;
        }
    }
    if (lane == 0 && wsure) atomicAdd(&nsure_sh, (unsigned)wsure);
    __syncthreads();

    const int nA = cntA < MAXA ? cntA : MAXA;
    const int nkeepA = K_TOP - nsure_sh;

    for (int q = w; q < nA; q += 16) {
        const int j = idxA[q];
        const float* wrow = W_enc + (size_t)j * D_IN;
        const float* xrow = x + (size_t)r * D_IN;
        double a = 0.0;
        for (int k = lane; k < D_IN; k += 64)
            a = fma((double)xrow[k] - (double)bpre[k], (double)wrow[k], a);
        #pragma unroll
        for (int off = 32; off; off >>= 1) a += __shfl_down(a, off, 64);
        if (lane == 0) dvalA[q] = a;
    }
    __syncthreads();

    for (int t = tid; t < nA; t += 1024) {
        const double dv = dvalA[t];
        const int ix = idxA[t];
        int rank = 0;
        for (int q = 0; q < nA; ++q)
            rank += (dvalA[q] > dv) || (dvalA[q] == dv && idxA[q] < ix);
        keepA[t] = (rank < nkeepA) ? 1 : 0;
    }
    __syncthreads();

    bool kp[24];
    #pragma unroll
    for (int c = 0; c < 24; ++c) {
        const float val = v[c];
        bool k = (val > thr_hi);
        if (!k && val >= thr_lo) {
            const int i = c*1024 + tid;
            for (int q = 0; q < nA; ++q)
                if (idxA[q] == i) { k = (keepA[q] != 0); break; }
        }
        kp[c] = k;
        const unsigned long long m = __ballot(k);
        if (lane == 0) wcnt[w][c] = (int)__popcll(m);
    }
    __syncthreads();
    if (tid == 0) {
        int run = 0;
        for (int c = 0; c < 24; ++c)
            #pragma unroll
            for (int q = 0; q < 16; ++q) { const int t = wcnt[q][c]; wcnt[q][c] = run; run += t; }
    }
    __syncthreads();

    float* zdst = z + (size_t)r * NLAT;
    #pragma unroll
    for (int c = 0; c < 24; ++c) {
        const unsigned long long m = __ballot(kp[c]);
        const int pos = wcnt[w][c] + (int)__popcll(m & lt);
        const int i = c*1024 + tid;
        zdst[i] = kp[c] ? v[c] : 0.0f;
        if (kp[c] && idx_ws != nullptr && pos < K_TOP) {
            idx_ws[r*K_TOP + pos] = i;
            val_ws[r*K_TOP + pos] = v[c];
        }
    }
}

// ---------------------------------------------------------------------------
// Flag-gated decoder for fallback rows.
// ---------------------------------------------------------------------------
__global__ __launch_bounds__(256) void dec_flagged(const int* __restrict__ flag_ws,
                                                   const int* __restrict__ idx_ws,
                                                   const float* __restrict__ val_ws,
                                                   const unsigned short* __restrict__ wdh,
                                                   const float* __restrict__ bpre,
                                                   const float* __restrict__ x,
                                                   float* __restrict__ x_hat,
                                                   float* __restrict__ recon)
{
    const int r = blockIdx.x;
    if (flag_ws[r] == 0) return;
    __shared__ int sidx[K_TOP];
    __shared__ float sval[K_TOP];
    const int tid = threadIdx.x;
    if (tid < K_TOP) {
        sidx[tid] = idx_ws[r*K_TOP + tid];
        sval[tid] = val_ws[r*K_TOP + tid];
    }
    __syncthreads();

    if (tid < D_IN / 4) {
        const int d0 = tid * 4;
        const float4 bp = *(const float4*)(bpre + d0);
        float a0 = bp.x, a1 = bp.y, a2 = bp.z, a3 = bp.w;
        #pragma unroll 8
        for (int j = 0; j < K_TOP; ++j) {
            const float vv = sval[j];
            const ushort4 w4 = *(const ushort4*)(wdh + (size_t)sidx[j] * D_IN + d0);
            a0 = fmaf(vv, bf2f(w4.x), a0);
            a1 = fmaf(vv, bf2f(w4.y), a1);
            a2 = fmaf(vv, bf2f(w4.z), a2);
            a3 = fmaf(vv, bf2f(w4.w), a3);
        }
        const size_t o = (size_t)r * D_IN + d0;
        const float4 xv = *(const float4*)(x + o);
        *(float4*)(x_hat + o) = make_float4(a0, a1, a2, a3);
        *(float4*)(recon + o) = make_float4(xv.x - a0, xv.y - a1, xv.z - a2, xv.w - a3);
    }
}

// ---------------------------------------------------------------------------
// Fallback GEMM with in-kernel split-2 (r5-verified) for small ws.
// ---------------------------------------------------------------------------
#define FBK 32
#define FLROW (FBK + 8)

__global__ __launch_bounds__(256) void enc_gemm_mfma(const float* __restrict__ x,
                                                     const float* __restrict__ W,
                                                     const float* __restrict__ bpre,
                                                     float* __restrict__ z_pre)
{
    __shared__ unsigned short Ah[GBM][FLROW], Al[GBM][FLROW];
    __shared__ unsigned short Bh[GBN][FLROW], Bl[GBN][FLROW];

    const int tid = threadIdx.x;
    const int bm = blockIdx.y * GBM;
    const int bn = blockIdx.x * GBN;
    const int lane = tid & 63;
    const int wv = tid >> 6;
    const int wr = (wv >> 1) * 64;
    const int wc = (wv & 1) * 64;
    const int fr = lane & 15;
    const int fg = lane >> 4;

    const int srow = tid >> 3;
    const int sk   = (tid & 7) * 4;

    f32x4 acc[4][4];
    #pragma unroll
    for (int i = 0; i < 4; ++i)
        #pragma unroll
        for (int j = 0; j < 4; ++j)
            #pragma unroll
            for (int e = 0; e < 4; ++e) acc[i][j][e] = 0.0f;

    for (int k0 = 0; k0 < D_IN; k0 += FBK) {
        float4 xa[4], wb[4];
        const float4 bp = *(const float4*)(bpre + k0 + sk);
        #pragma unroll
        for (int p = 0; p < 4; ++p) {
            xa[p] = *(const float4*)(x + (size_t)(bm + srow + 32*p) * D_IN + k0 + sk);
            wb[p] = *(const float4*)(W + (size_t)(bn + srow + 32*p) * D_IN + k0 + sk);
        }
        __syncthreads();
        #pragma unroll
        for (int p = 0; p < 4; ++p) {
            const float a0 = xa[p].x - bp.x, a1 = xa[p].y - bp.y,
                        a2 = xa[p].z - bp.z, a3 = xa[p].w - bp.w;
            const unsigned short h0 = bf16hi(a0), h1 = bf16hi(a1),
                                 h2 = bf16hi(a2), h3 = bf16hi(a3);
            *(ushort4*)&Ah[srow + 32*p][sk] = make_ushort4(h0, h1, h2, h3);
            *(ushort4*)&Al[srow + 32*p][sk] = make_ushort4(
                bf16hi(a0 - bf2f(h0)), bf16hi(a1 - bf2f(h1)),
                bf16hi(a2 - bf2f(h2)), bf16hi(a3 - bf2f(h3)));
            const float b0 = wb[p].x, b1 = wb[p].y, b2 = wb[p].z, b3 = wb[p].w;
            const unsigned short g0 = bf16hi(b0), g1 = bf16hi(b1),
                                 g2 = bf16hi(b2), g3 = bf16hi(b3);
            *(ushort4*)&Bh[srow + 32*p][sk] = make_ushort4(g0, g1, g2, g3);
            *(ushort4*)&Bl[srow + 32*p][sk] = make_ushort4(
                bf16hi(b0 - bf2f(g0)), bf16hi(b1 - bf2f(g1)),
                bf16hi(b2 - bf2f(g2)), bf16hi(b3 - bf2f(g3)));
        }
        __syncthreads();

        short8 ah[4], al[4], bh[4], bl[4];
        #pragma unroll
        for (int t = 0; t < 4; ++t) {
            ah[t] = *(const short8*)&Ah[wr + t*16 + fr][fg * 8];
            al[t] = *(const short8*)&Al[wr + t*16 + fr][fg * 8];
            bh[t] = *(const short8*)&Bh[wc + t*16 + fr][fg * 8];
            bl[t] = *(const short8*)&Bl[wc + t*16 + fr][fg * 8];
        }
        #pragma unroll
        for (int mt = 0; mt < 4; ++mt)
            #pragma unroll
            for (int nt = 0; nt < 4; ++nt) {
                acc[mt][nt] = __builtin_amdgcn_mfma_f32_16x16x32_bf16(ah[mt], bh[nt], acc[mt][nt], 0, 0, 0);
                acc[mt][nt] = __builtin_amdgcn_mfma_f32_16x16x32_bf16(ah[mt], bl[nt], acc[mt][nt], 0, 0, 0);
                acc[mt][nt] = __builtin_amdgcn_mfma_f32_16x16x32_bf16(al[mt], bh[nt], acc[mt][nt], 0, 0, 0);
            }
    }

    #pragma unroll
    for (int mt = 0; mt < 4; ++mt)
        #pragma unroll
        for (int j = 0; j < 4; ++j) {
            const int r = bm + wr + mt*16 + fg*4 + j;
            float* dst = z_pre + (size_t)r * NLAT + bn + wc;
            #pragma unroll
            for (int nt = 0; nt < 4; ++nt)
                dst[nt*16 + fr] = acc[mt][nt][j];
        }
}

__global__ __launch_bounds__(256) void dec_scan_kernel(const float* __restrict__ z,
                                                       const float* __restrict__ W_dec,
                                                       const float* __restrict__ bpre,
                                                       const float* __restrict__ x,
                                                       float* __restrict__ x_hat,
                                                       float* __restrict__ recon)
{
    __shared__ int sidx[K_TOP];
    __shared__ float sval[K_TOP];
    __shared__ int wcnt[4];
    __shared__ int base;
    const int r = blockIdx.x;
    const int tid = threadIdx.x;
    const int lane = tid & 63, w = tid >> 6;
    if (tid == 0) base = 0;
    __syncthreads();
    const float* zrow = z + (size_t)r * NLAT;
    for (int c = 0; c < NLAT; c += 256) {
        const float vv = zrow[c + tid];
        const bool nz = (vv != 0.0f);
        const unsigned long long m = __ballot(nz);
        if (lane == 0) wcnt[w] = __popcll(m);
        __syncthreads();
        int b = base;
        for (int j = 0; j < w; ++j) b += wcnt[j];
        const int pos = b + __popcll(m & ((1ull << lane) - 1ull));
        if (nz && pos < K_TOP) { sidx[pos] = c + tid; sval[pos] = vv; }
        __syncthreads();
        if (tid == 0) { int s = 0; for (int j = 0; j < 4; ++j) s += wcnt[j]; base += s; }
        __syncthreads();
    }
    const int n = base > K_TOP ? K_TOP : base;

    float a0 = bpre[tid], a1 = bpre[tid + 256], a2 = bpre[tid + 512];
    for (int j = 0; j < n; ++j) {
        const float vv = sval[j];
        const float* wr_ = W_dec + (size_t)sidx[j] * D_IN;
        a0 = fmaf(vv, wr_[tid],       a0);
        a1 = fmaf(vv, wr_[tid + 256], a1);
        a2 = fmaf(vv, wr_[tid + 512], a2);
    }
    const size_t o = (size_t)r * D_IN + tid;
    x_hat[o]       = a0;
    x_hat[o + 256] = a1;
    x_hat[o + 512] = a2;
    recon[o]       = x[o]       - a0;
    recon[o + 256] = x[o + 256] - a1;
    recon[o + 512] = x[o + 512] - a2;
}

// ---------------------------------------------------------------------------
extern "C" void kernel_launch(void* const* d_in, const int* in_sizes, int n_in,
                              void* d_out, int out_size, void* d_ws, size_t ws_size,
                              hipStream_t stream)
{
    const float* x     = (const float*)d_in[0];
    const float* W_enc = (const float*)d_in[1];
    const float* W_dec = (const float*)d_in[2];
    const float* bpre  = (const float*)d_in[3];

    float* out   = (float*)d_out;
    float* x_hat = out;
    float* z     = x_hat + (size_t)BATCH * D_IN;
    float* z_pre = z     + (size_t)BATCH * NLAT;
    float* recon = z_pre + (size_t)BATCH * NLAT;

    // ws layout
    char* p = (char*)d_ws;
    int*    flag_ws   = (int*)p;           p += (size_t)BATCH * 4;
    int*    idx_ws    = (int*)p;           p += (size_t)BATCH * K_TOP * 4;
    float*  val_ws    = (float*)p;         p += (size_t)BATCH * K_TOP * 4;
    p = (char*)(((size_t)p + 15) & ~(size_t)15);
    int*    cnt_blk   = (int*)p;           p += (size_t)NBLKN * BATCH * 4;
    int2*   slot_iv   = (int2*)p;          p += (size_t)BATCH * NBLKN * SLOTS * 8;
    unsigned short* xh  = (unsigned short*)p;    p += (size_t)BATCH * D_IN * 2;
    unsigned short* wh  = (unsigned short*)p;    p += (size_t)NLAT * D_IN * 2;
    unsigned short* wdh = (unsigned short*)p;    p += (size_t)NLAT * D_IN * 2;
    const size_t ws_full = (size_t)(p - (char*)d_ws);
    const bool have_full = (d_ws != nullptr) && (ws_size >= ws_full);

    if (have_full) {
        conv_all<<<XCHUNKS + 2 * WCHUNKS, 256, 0, stream>>>(
            (const float4*)x, bpre, (const float4*)W_enc, (const float4*)W_dec,
            (ushort4*)xh, (ushort4*)wh, (ushort4*)wdh);

        enc_gemm_fused<<<NWG, 256, 0, stream>>>(xh, wh, z_pre, z, cnt_blk, slot_iv);

        select_kernel<<<BATCH, 256, 0, stream>>>(cnt_blk, slot_iv, x, W_enc, bpre, wdh,
                                                 z, x_hat, recon, idx_ws, val_ws, flag_ws);
        topk_fallback<<<BATCH, 1024, 0, stream>>>(z_pre, z, x, W_enc, bpre,
                                                  idx_ws, val_ws, flag_ws);
        dec_flagged<<<BATCH, 256, 0, stream>>>(flag_ws, idx_ws, val_ws, wdh, bpre,
                                               x, x_hat, recon);
    } else {
        dim3 g1(NLAT / GBN, BATCH / GBM);
        enc_gemm_mfma<<<g1, 256, 0, stream>>>(x, W_enc, bpre, z_pre);
        topk_fallback<<<BATCH, 1024, 0, stream>>>(z_pre, z, x, W_enc, bpre,
                                                  nullptr, nullptr, nullptr);
        dec_scan_kernel<<<BATCH, 256, 0, stream>>>(z, W_dec, bpre, x, x_hat, recon);
    }
}